// Round 6
// baseline (1415.533 us; speedup 1.0000x reference)
//
#include <hip/hip_runtime.h>
#include <hip/hip_bf16.h>

#define Nn 20000
#define EREL 60000
#define ETOT 180000
#define NG 64
#define FD 384
#define EPS 1e-5f

typedef unsigned short u16;
typedef __attribute__((ext_vector_type(8))) short s8v;     // 8 bf16 (4 VGPR) MFMA A/B frag
typedef __attribute__((ext_vector_type(4))) float f4v;     // MFMA C/D frag

static inline int cdiv(int a, int b) { return (a + b - 1) / b; }

__device__ inline u16 f2b(float f) {
    __hip_bfloat16 h = __float2bfloat16(f);
    union { __hip_bfloat16 b; u16 u; } c; c.b = h; return c.u;
}
__device__ inline float b2f(u16 u) {
    union { __hip_bfloat16 b; u16 u; } c; c.u = u; return __bfloat162float(c.b);
}

// ---------------- split fp32 -> bf16 hi/lo (vectorized by float4) ----------------
__global__ __launch_bounds__(256) void split_k(const float* __restrict__ x,
    u16* __restrict__ hi, u16* __restrict__ lo, int n4)
{
    int i = blockIdx.x * 256 + threadIdx.x;
    if (i >= n4) return;
    float4 v = ((const float4*)x)[i];
    ushort4 h, l;
    h.x = f2b(v.x); l.x = f2b(v.x - b2f(h.x));
    h.y = f2b(v.y); l.y = f2b(v.y - b2f(h.y));
    h.z = f2b(v.z); l.z = f2b(v.z - b2f(h.z));
    h.w = f2b(v.w); l.w = f2b(v.w - b2f(h.w));
    ((ushort4*)hi)[i] = h;
    ((ushort4*)lo)[i] = l;
}

// transpose + split: W[b][K][N] -> T[b][N][K] hi/lo
__global__ void tsplit_k(const float* __restrict__ W, u16* __restrict__ hi,
                         u16* __restrict__ lo, int K, int N, int total)
{
    int idx = blockIdx.x * 256 + threadIdx.x;
    if (idx >= total) return;
    int kn = K * N;
    int b = idx / kn, rem = idx - b * kn;
    int k = rem / N, n = rem - k * N;
    float v = W[idx];
    u16 h = f2b(v), l = f2b(v - b2f(h));
    int o = b * kn + n * K + k;
    hi[o] = h; lo[o] = l;
}

// ---------------- split-bf16 MFMA GEMM ----------------
// C[M,N] = A[M,K] @ B[N,K]^T, A,B bf16 (hi,lo) pairs row-major ld=K. 128x128 tile,
// 4 waves of 64x64, 16x16x32 MFMA. TERMS=3: hi*bh + lo*bh + hi*bl (~fp32).
// TERMS=2: hi*bh + lo*bh (full-A x hi-B; B-lo never read) — for outputs that get
// rounded to bf16 anyway. blockIdx.z batches B/C. OB16: round C to bf16 at store.
template<bool BIAS, bool RELU, bool STATS, bool OB16, int TERMS>
__global__ __launch_bounds__(256) void mgemm_k(
    const u16* __restrict__ Ahi, const u16* __restrict__ Alo,
    const u16* __restrict__ Bhi, const u16* __restrict__ Blo,
    const float* __restrict__ bias, void* __restrict__ Cv,
    int M, int K, int ldc, int bstride, float* __restrict__ stats)
{
    __shared__ u16 lds[4 * 128 * 32];   // Ahi | Alo | Bhi | (Blo) tiles, [128][32] each
    __shared__ float red[256];
    const int t = threadIdx.x;
    const int brow = blockIdx.x * 128, bcol = blockIdx.y * 128;
    const int z = blockIdx.z;
    Bhi += (size_t)z * bstride;
    Blo += (size_t)z * bstride;
    float* Cf = OB16 ? nullptr : (float*)Cv + (size_t)z * M * ldc;
    u16*   Ch = OB16 ? (u16*)Cv + (size_t)z * M * ldc : nullptr;

    const int NSRC = (TERMS == 3) ? 8 : 6;
    const int r0 = t >> 2, sl = t & 3;
    const int rA0 = min(brow + r0, M - 1);
    const int rA1 = min(brow + r0 + 64, M - 1);
    const u16* gsrc[8];
    gsrc[0] = Ahi + (size_t)rA0 * K + sl * 8;
    gsrc[1] = Ahi + (size_t)rA1 * K + sl * 8;
    gsrc[2] = Alo + (size_t)rA0 * K + sl * 8;
    gsrc[3] = Alo + (size_t)rA1 * K + sl * 8;
    gsrc[4] = Bhi + (size_t)(bcol + r0) * K + sl * 8;
    gsrc[5] = Bhi + (size_t)(bcol + r0 + 64) * K + sl * 8;
    gsrc[6] = Blo + (size_t)(bcol + r0) * K + sl * 8;
    gsrc[7] = Blo + (size_t)(bcol + r0 + 64) * K + sl * 8;
    const int swz = (sl ^ (r0 & 3)) << 3;
    int ldst[8];
    #pragma unroll
    for (int i = 0; i < 8; i++) {
        int tile = i >> 1, row = r0 + 64 * (i & 1);
        ldst[i] = tile * 4096 + row * 32 + swz;
    }

    const int l = t & 63, w = t >> 6;
    const int wr = (w >> 1) * 64, wc = (w & 1) * 64;
    const int lr = l & 15, kq = l >> 4;

    f4v acc[4][4] = {};
    const int NK = K >> 5;

    s8v stg[8];
    #pragma unroll
    for (int i = 0; i < 8; i++) if (i < NSRC) stg[i] = *(const s8v*)gsrc[i];

    for (int kc = 0; kc < NK; kc++) {
        if (kc) __syncthreads();
        #pragma unroll
        for (int i = 0; i < 8; i++) if (i < NSRC) *(s8v*)(lds + ldst[i]) = stg[i];
        __syncthreads();
        if (kc + 1 < NK) {
            const int ko = (kc + 1) * 32;
            #pragma unroll
            for (int i = 0; i < 8; i++) if (i < NSRC) stg[i] = *(const s8v*)(gsrc[i] + ko);
        }
        #define LDR(T, row) (*(const s8v*)(lds + (T) * 4096 + (row) * 32 + ((kq ^ ((row) & 3)) << 3)))
        s8v bh[4], bl[4];
        #pragma unroll
        for (int tn = 0; tn < 4; tn++) {
            int rb = wc + tn * 16 + lr;
            bh[tn] = LDR(2, rb);
            if (TERMS == 3) bl[tn] = LDR(3, rb);
        }
        #pragma unroll
        for (int tm = 0; tm < 4; tm++) {
            int ra = wr + tm * 16 + lr;
            s8v ah = LDR(0, ra);
            s8v al = LDR(1, ra);
            #pragma unroll
            for (int tn = 0; tn < 4; tn++) {
                acc[tm][tn] = __builtin_amdgcn_mfma_f32_16x16x32_bf16(ah, bh[tn], acc[tm][tn], 0, 0, 0);
                acc[tm][tn] = __builtin_amdgcn_mfma_f32_16x16x32_bf16(al, bh[tn], acc[tm][tn], 0, 0, 0);
                if (TERMS == 3)
                    acc[tm][tn] = __builtin_amdgcn_mfma_f32_16x16x32_bf16(ah, bl[tn], acc[tm][tn], 0, 0, 0);
            }
        }
        #undef LDR
    }

    float s1 = 0.f, s2 = 0.f;
    #pragma unroll
    for (int tm = 0; tm < 4; tm++) {
        #pragma unroll
        for (int rg = 0; rg < 4; rg++) {
            int row = brow + wr + tm * 16 + kq * 4 + rg;
            if (row < M) {
                #pragma unroll
                for (int tn = 0; tn < 4; tn++) {
                    int col = bcol + wc + tn * 16 + lr;
                    float v = acc[tm][tn][rg];
                    if (BIAS) v += bias[col];
                    if (RELU) v = fmaxf(v, 0.f);
                    if (OB16) Ch[(size_t)row * ldc + col] = f2b(v);
                    else      Cf[(size_t)row * ldc + col] = v;
                    if (STATS) { s1 += v; s2 += v * v; }
                }
            }
        }
    }
    if (STATS) {
        __syncthreads();
        red[t] = s1; __syncthreads();
        for (int o = 128; o; o >>= 1) { if (t < o) red[t] += red[t + o]; __syncthreads(); }
        if (t == 0) atomicAdd(&stats[0], red[0]);
        __syncthreads();
        red[t] = s2; __syncthreads();
        for (int o = 128; o; o >>= 1) { if (t < o) red[t] += red[t + o]; __syncthreads(); }
        if (t == 0) atomicAdd(&stats[1], red[0]);
    }
}

// ---------------- fp32 tiled GEMM (tiny-K shapes: geo K=6, pri K=33, cls2) ----------------
template<bool BIAS, bool RELU, bool STATS>
__global__ __launch_bounds__(256) void sgemm_k(
    const float* __restrict__ A, const float* __restrict__ B,
    const float* __restrict__ bias, float* __restrict__ C,
    int M, int K, int N, int ldc, float* __restrict__ stats)
{
    const int BK = 16;
    const int r = blockIdx.z;
    B += (size_t)r * K * N;
    C += (size_t)r * M * ldc;
    __shared__ float As[16][65];
    __shared__ float Bs[16][64];
    int tid = threadIdx.x;
    int tx = tid & 15, ty = tid >> 4;
    int brow = blockIdx.x * 64, bcol = blockIdx.y * 64;
    float acc[4][4] = {};
    for (int k0 = 0; k0 < K; k0 += BK) {
        #pragma unroll
        for (int i = 0; i < 4; i++) {
            int e = tid + 256 * i;
            int ar = e >> 4, ak = e & 15;
            int gr = brow + ar, gk = k0 + ak;
            As[ak][ar] = (gr < M && gk < K) ? A[(size_t)gr * K + gk] : 0.f;
            int bk = e >> 6, bn = e & 63;
            int gbk = k0 + bk, gbn = bcol + bn;
            Bs[bk][bn] = (gbk < K && gbn < N) ? B[(size_t)gbk * N + gbn] : 0.f;
        }
        __syncthreads();
        #pragma unroll
        for (int k = 0; k < BK; k++) {
            float ra[4], rb[4];
            #pragma unroll
            for (int i = 0; i < 4; i++) ra[i] = As[k][ty * 4 + i];
            #pragma unroll
            for (int j = 0; j < 4; j++) rb[j] = Bs[k][tx * 4 + j];
            #pragma unroll
            for (int i = 0; i < 4; i++)
                #pragma unroll
                for (int j = 0; j < 4; j++)
                    acc[i][j] = fmaf(ra[i], rb[j], acc[i][j]);
        }
        __syncthreads();
    }
    float s1 = 0.f, s2 = 0.f;
    #pragma unroll
    for (int i = 0; i < 4; i++) {
        int row = brow + ty * 4 + i;
        #pragma unroll
        for (int j = 0; j < 4; j++) {
            int col = bcol + tx * 4 + j;
            if (row < M && col < N) {
                float v = acc[i][j];
                if (BIAS) v += bias[col];
                if (RELU) v = v > 0.f ? v : 0.f;
                C[(size_t)row * ldc + col] = v;
                if (STATS) { s1 += v; s2 += v * v; }
            }
        }
    }
    if (STATS) {
        __shared__ float red[256];
        __syncthreads();
        red[tid] = s1; __syncthreads();
        for (int o = 128; o; o >>= 1) { if (tid < o) red[tid] += red[tid + o]; __syncthreads(); }
        if (tid == 0) atomicAdd(&stats[0], red[0]);
        __syncthreads();
        red[tid] = s2; __syncthreads();
        for (int o = 128; o; o >>= 1) { if (tid < o) red[tid] += red[tid + o]; __syncthreads(); }
        if (tid == 0) atomicAdd(&stats[1], red[0]);
    }
}

// scalar-LN of a 128-col block of H (pre-offset) from RAW sums, fused bf16 hi/lo split.
__global__ __launch_bounds__(256) void enc_norm_k(float* __restrict__ H, const float* __restrict__ w,
                           const float* __restrict__ b, const float* __restrict__ stats,
                           float cntinv, u16* __restrict__ hi, u16* __restrict__ lo)
{
    int i = blockIdx.x * 256 + threadIdx.x;   // float4 index within the 128-col block
    if (i >= Nn * 32) return;
    int n = i >> 5, c4 = i & 31;
    float m = stats[0] * cntinv;
    float var = stats[1] * cntinv - m * m;
    float s = 1.f / (sqrtf(fmaxf(var, 0.f)) + EPS);
    float4 wv = ((const float4*)w)[c4];
    float4 bv = ((const float4*)b)[c4];
    float4* p = (float4*)(H + (size_t)n * FD) + c4;
    float4 v = *p;
    v.x = (v.x - m) * s * wv.x + bv.x;
    v.y = (v.y - m) * s * wv.y + bv.y;
    v.z = (v.z - m) * s * wv.z + bv.z;
    v.w = (v.w - m) * s * wv.w + bv.w;
    *p = v;
    ushort4 hh, ll;
    hh.x = f2b(v.x); ll.x = f2b(v.x - b2f(hh.x));
    hh.y = f2b(v.y); ll.y = f2b(v.y - b2f(hh.y));
    hh.z = f2b(v.z); ll.z = f2b(v.z - b2f(hh.z));
    hh.w = f2b(v.w); ll.w = f2b(v.w - b2f(hh.w));
    ((ushort4*)(hi + (size_t)n * FD))[c4] = hh;
    ((ushort4*)(lo + (size_t)n * FD))[c4] = ll;
}

// qi[r,n,h] = xr[r,n,:] . q[:,h] ; kj likewise. One wave per (r,n) row. XR is bf16.
__global__ __launch_bounds__(256) void proj_qk_k(const u16* __restrict__ xr,
    const float* __restrict__ q, const float* __restrict__ kk,
    float* __restrict__ qi, float* __restrict__ kj)
{
    int row = blockIdx.x * 4 + (threadIdx.x >> 6);
    int lane = threadIdx.x & 63;
    if (row >= 3 * Nn) return;
    const u16* xrow = xr + (size_t)row * FD;
    float pq[8] = {}, pk[8] = {};
    #pragma unroll
    for (int j = 0; j < 6; j++) {
        int c = lane + 64 * j;
        float x = b2f(xrow[c]);
        #pragma unroll
        for (int h = 0; h < 8; h++) {
            pq[h] = fmaf(x, q[c * 8 + h], pq[h]);
            pk[h] = fmaf(x, kk[c * 8 + h], pk[h]);
        }
    }
    #pragma unroll
    for (int o = 32; o; o >>= 1) {
        #pragma unroll
        for (int h = 0; h < 8; h++) {
            pq[h] += __shfl_down(pq[h], o);
            pk[h] += __shfl_down(pk[h], o);
        }
    }
    if (lane == 0) {
        #pragma unroll
        for (int h = 0; h < 8; h++) {
            qi[(size_t)row * 8 + h] = pq[h];
            kj[(size_t)row * 8 + h] = pk[h];
        }
    }
}

// per-edge unnormalized attention weights: ew[e][h] = exp(leaky(qi[et,dst,h]+kj[et,src,h]))
__global__ __launch_bounds__(256) void ew_k(const float* __restrict__ qi,
    const float* __restrict__ kj, const int* __restrict__ eidx,
    const int* __restrict__ dste, float* __restrict__ ew)
{
    int e = blockIdx.x * 256 + threadIdx.x;
    if (e >= ETOT) return;
    int p = eidx[e];
    int src = p & 0xFFFFFF, et = p >> 24;
    int dst = dste[e];
    const float4* q4 = (const float4*)(qi + ((size_t)et * Nn + dst) * 8);
    const float4* k4 = (const float4*)(kj + ((size_t)et * Nn + src) * 8);
    float4 out[2];
    #pragma unroll
    for (int half = 0; half < 2; half++) {
        float4 qv = q4[half], kv = k4[half];
        float a0 = qv.x + kv.x, a1 = qv.y + kv.y, a2 = qv.z + kv.z, a3 = qv.w + kv.w;
        a0 = (a0 > 0.f) ? a0 : 0.2f * a0;
        a1 = (a1 > 0.f) ? a1 : 0.2f * a1;
        a2 = (a2 > 0.f) ? a2 : 0.2f * a2;
        a3 = (a3 > 0.f) ? a3 : 0.2f * a3;
        out[half] = make_float4(__expf(a0), __expf(a1), __expf(a2), __expf(a3));
    }
    float4* ew4 = (float4*)(ew + (size_t)e * 8);
    ew4[0] = out[0];
    ew4[1] = out[1];
}

__global__ void edge_count_k(const int* __restrict__ e0, const int* __restrict__ e1,
                             const int* __restrict__ e2, int* __restrict__ cnt)
{
    int e = blockIdx.x * 256 + threadIdx.x;
    if (e >= ETOT) return;
    int r = e / EREL, i = e - r * EREL;
    const int* ei = (r == 0) ? e0 : (r == 1) ? e1 : e2;
    atomicAdd(&cnt[ei[EREL + i]], 1);
}

__global__ void edge_fill_k(const int* __restrict__ e0, const int* __restrict__ e1,
                            const int* __restrict__ e2, int* __restrict__ cursor,
                            int* __restrict__ eidx, int* __restrict__ dste)
{
    int e = blockIdx.x * 256 + threadIdx.x;
    if (e >= ETOT) return;
    int r = e / EREL, i = e - r * EREL;
    const int* ei = (r == 0) ? e0 : (r == 1) ? e1 : e2;
    int src = ei[i], dst = ei[EREL + i];
    int pos = atomicAdd(&cursor[dst], 1);
    eidx[pos] = src | (r << 24);
    dste[pos] = dst;
}

__global__ __launch_bounds__(1024) void scan_k(const int* __restrict__ cnt,
                                               int* __restrict__ rowptr, int* __restrict__ cursor)
{
    __shared__ int lds[1024];
    __shared__ int carry;
    int t = threadIdx.x;
    if (t == 0) carry = 0;
    __syncthreads();
    for (int base = 0; base < Nn; base += 1024) {
        int i = base + t;
        int v = (i < Nn) ? cnt[i] : 0;
        lds[t] = v; __syncthreads();
        for (int o = 1; o < 1024; o <<= 1) {
            int x = (t >= o) ? lds[t - o] : 0;
            __syncthreads();
            lds[t] += x;
            __syncthreads();
        }
        int c = carry;
        if (i < Nn) { int ex = c + lds[t] - v; rowptr[i] = ex; cursor[i] = ex; }
        __syncthreads();
        if (t == 1023) carry = c + lds[1023];
        __syncthreads();
    }
    if (t == 0) rowptr[Nn] = carry;
}

__global__ void gcount_k(const int* __restrict__ batch, int* __restrict__ gcnt)
{
    int n = blockIdx.x * 256 + threadIdx.x;
    if (n >= Nn) return;
    atomicAdd(&gcnt[batch[n]], 1);
}

// RGAT aggregation from precomputed EW. 2 waves per node (edges split), combine via LDS.
// Fused elu/residual/per-graph-stats. Block = 256 thr = 4 waves = 2 nodes. Nn % 2 == 0.
__global__ __launch_bounds__(256) void aggr_k(const u16* __restrict__ xr,
    const float* __restrict__ ew, const int* __restrict__ rowptr, const int* __restrict__ eidx,
    const float* __restrict__ bias, const float* __restrict__ hin,
    const int* __restrict__ batch, float* __restrict__ out,
    float* __restrict__ gsum, float* __restrict__ gsq)
{
    __shared__ float ls[NG], lq[NG];
    __shared__ float pacc[2][6][64];
    __shared__ float pden[2][8];
    int t = threadIdx.x;
    if (t < NG) { ls[t] = 0.f; lq[t] = 0.f; }
    int w = t >> 6, lane = t & 63;
    int ns = w & 1, half = w >> 1;
    int node = blockIdx.x * 2 + ns;
    int e0 = rowptr[node], e1 = rowptr[node + 1];
    int deg = e1 - e0;
    int mid = e0 + ((deg + 1) >> 1);
    int a0 = half ? mid : e0;
    int a1 = half ? e1 : mid;
    int hdv[6];
    #pragma unroll
    for (int j = 0; j < 6; j++) hdv[j] = (lane + 64 * j) / 48;

    // den over my half: 8 edges per iteration, coalesced 256B
    float den = 0.f;
    for (int ee = a0 + (lane >> 3); ee < a1; ee += 8)
        den += ew[(size_t)ee * 8 + (lane & 7)];
    den += __shfl_xor(den, 8);
    den += __shfl_xor(den, 16);
    den += __shfl_xor(den, 32);   // every lane: sum for head (lane&7)

    // unnormalized weighted gather over my half
    float acc[6] = {};
    for (int e = a0; e < a1; e++) {
        int p = eidx[e];
        int srcn = p & 0xFFFFFF, et = p >> 24;
        float ev = (lane < 8) ? ew[(size_t)e * 8 + lane] : 0.f;
        const u16* row = xr + ((size_t)et * Nn + srcn) * FD;
        #pragma unroll
        for (int j = 0; j < 6; j++) {
            float a = __shfl(ev, hdv[j]);
            acc[j] = fmaf(a, b2f(row[lane + 64 * j]), acc[j]);
        }
    }

    if (half) {
        #pragma unroll
        for (int j = 0; j < 6; j++) pacc[ns][j][lane] = acc[j];
        if (lane < 8) pden[ns][lane] = den;
    }
    __syncthreads();
    if (!half) {
        float s1 = 0.f, s2 = 0.f;
        #pragma unroll
        for (int j = 0; j < 6; j++) {
            int hd = hdv[j];
            float dh = __shfl(den, hd) + pden[ns][hd];
            float rcp = 1.f / (dh + 1e-16f);
            int c = lane + 64 * j;
            float v = (acc[j] + pacc[ns][j][lane]) * rcp + bias[c];
            v = (v > 0.f) ? v : expm1f(v);
            v += hin[(size_t)node * FD + c];
            out[(size_t)node * FD + c] = v;
            s1 += v; s2 += v * v;
        }
        #pragma unroll
        for (int o = 32; o; o >>= 1) { s1 += __shfl_down(s1, o); s2 += __shfl_down(s2, o); }
        int g = batch[node];   // wave-uniform
        if (lane == 0) { atomicAdd(&ls[g], s1); atomicAdd(&lq[g], s2); }
    }
    __syncthreads();
    if (t < NG && (ls[t] != 0.f || lq[t] != 0.f)) {
        atomicAdd(&gsum[t], ls[t]);
        atomicAdd(&gsq[t], lq[t]);
    }
}

// graph-LN (stats finalized inline from raw sums) + fused bf16 hi/lo split
__global__ __launch_bounds__(256) void gnorm_split_k(float* __restrict__ y,
    const int* __restrict__ batch, const float* __restrict__ gsum, const float* __restrict__ gsq,
    const int* __restrict__ gcnt, const float* __restrict__ w, const float* __restrict__ b,
    u16* __restrict__ hi, u16* __restrict__ lo)
{
    int i = blockIdx.x * 256 + threadIdx.x;   // float4 index
    if (i >= Nn * (FD / 4)) return;
    int n = i / 96, c4 = i - n * 96;
    int g = batch[n];
    float norm = fmaxf((float)gcnt[g], 1.f) * (float)FD;
    float m = gsum[g] / norm;
    float var = gsq[g] / norm - m * m;
    float rstd = rsqrtf(var + EPS);
    float4 wv = ((const float4*)w)[c4];
    float4 bv = ((const float4*)b)[c4];
    float4 v = ((const float4*)y)[i];
    v.x = (v.x - m) * rstd * wv.x + bv.x;
    v.y = (v.y - m) * rstd * wv.y + bv.y;
    v.z = (v.z - m) * rstd * wv.z + bv.z;
    v.w = (v.w - m) * rstd * wv.w + bv.w;
    ((float4*)y)[i] = v;
    ushort4 hh, ll;
    hh.x = f2b(v.x); ll.x = f2b(v.x - b2f(hh.x));
    hh.y = f2b(v.y); ll.y = f2b(v.y - b2f(hh.y));
    hh.z = f2b(v.z); ll.z = f2b(v.z - b2f(hh.z));
    hh.w = f2b(v.w); ll.w = f2b(v.w - b2f(hh.w));
    ((ushort4*)hi)[i] = hh;
    ((ushort4*)lo)[i] = ll;
}

__global__ void softmax_prior_k(const float* __restrict__ logits, float* __restrict__ prior)
{
    int n = blockIdx.x * 8 + (threadIdx.x >> 5);
    int l = threadIdx.x & 31;
    if (n >= Nn) return;
    float v = logits[n * 32 + l];
    float m = v;
    #pragma unroll
    for (int o = 16; o; o >>= 1) m = fmaxf(m, __shfl_xor(m, o, 32));
    float e = __expf(v - m);
    float s = e;
    #pragma unroll
    for (int o = 16; o; o >>= 1) s += __shfl_xor(s, o, 32);
    prior[(size_t)n * 33 + l] = e / s;
    if (l == 0) prior[(size_t)n * 33 + 32] = 1.f / s;
}

extern "C" void kernel_launch(void* const* d_in, const int* in_sizes, int n_in,
                              void* d_out, int out_size, void* d_ws, size_t ws_size,
                              hipStream_t stream)
{
    const float* x_visual = (const float*)d_in[0];
    const float* x_geom   = (const float*)d_in[1];
    const float* x_prior  = (const float*)d_in[2];
    const int* ei0   = (const int*)d_in[3];
    const int* ei1   = (const int*)d_in[4];
    const int* ei2   = (const int*)d_in[5];
    const int* batch = (const int*)d_in[6];
    const float* vis_W = (const float*)d_in[7];  const float* vis_b = (const float*)d_in[8];
    const float* vis_lnw = (const float*)d_in[9]; const float* vis_lnb = (const float*)d_in[10];
    const float* geo_W = (const float*)d_in[11]; const float* geo_b = (const float*)d_in[12];
    const float* geo_lnw = (const float*)d_in[13]; const float* geo_lnb = (const float*)d_in[14];
    const float* pri_W = (const float*)d_in[15]; const float* pri_b = (const float*)d_in[16];
    const float* pri_lnw = (const float*)d_in[17]; const float* pri_lnb = (const float*)d_in[18];
    const float* rgat_W[2]    = { (const float*)d_in[19], (const float*)d_in[25] };
    const float* rgat_q[2]    = { (const float*)d_in[20], (const float*)d_in[26] };
    const float* rgat_kk[2]   = { (const float*)d_in[21], (const float*)d_in[27] };
    const float* rgat_bias[2] = { (const float*)d_in[22], (const float*)d_in[28] };
    const float* ln_w[2]      = { (const float*)d_in[23], (const float*)d_in[29] };
    const float* ln_b[2]      = { (const float*)d_in[24], (const float*)d_in[30] };
    const float* cls_W1 = (const float*)d_in[31]; const float* cls_b1 = (const float*)d_in[32];
    const float* cls_W2 = (const float*)d_in[33]; const float* cls_b2 = (const float*)d_in[34];
    float* OUT = (float*)d_out;

    // ---------------- workspace layout ----------------
    float* ws = (float*)d_ws;
    float* XRreg = ws;                         // 3*Nn*FD floats reserved (92.2 MB region)
    u16*   XR16  = (u16*)XRreg;                // XR stored bf16: first 46 MB of the region
    float* HCAT  = XRreg + (size_t)3 * Nn * FD;
    float* HA    = HCAT + (size_t)Nn * FD;
    float* HB    = HA + (size_t)Nn * FD;
    float* PRIOR = HB + (size_t)Nn * FD;       // Nn*33
    float* QI    = PRIOR + (size_t)Nn * 33;
    float* KJ    = QI + (size_t)3 * Nn * 8;
    u16* HS0_HI  = (u16*)(KJ + (size_t)3 * Nn * 8);   // HCAT split
    u16* HS0_LO  = HS0_HI + (size_t)Nn * FD;
    u16* HS1_HI  = HS0_LO + (size_t)Nn * FD;          // HA split
    u16* HS1_LO  = HS1_HI + (size_t)Nn * FD;
    u16* RW_HI   = HS1_LO + (size_t)Nn * FD;   // 2*3*384*384
    u16* RW_LO   = RW_HI + (size_t)2 * 3 * 384 * 384;
    u16* VW_HI   = RW_LO + (size_t)2 * 3 * 384 * 384; // 128*1024
    u16* VW_LO   = VW_HI + (size_t)128 * 1024;
    u16* CW_HI   = VW_LO + (size_t)128 * 1024;        // 128*384
    u16* CW_LO   = CW_HI + (size_t)128 * 384;
    float* STATS = (float*)(CW_LO + (size_t)128 * 384); // 2
    float* GSUM  = STATS + 2;                  // 64
    float* GSQ   = GSUM + 64;
    int* CNT    = (int*)(GSQ + 64);
    int* ROWPTR = CNT + Nn;
    int* CURSOR = ROWPTR + Nn + 1;
    int* EIDX   = CURSOR + Nn;
    int* GCNT   = EIDX + ETOT;
    int* DSTE   = GCNT + 64;                   // ETOT
    float* EW   = (float*)(DSTE + ETOT);       // ETOT*8 floats (5.76 MB)
    // aliases into the XR region (temporally dead sub-ranges):
    u16* VA_HI = (u16*)XRreg;                  // x_visual split [0,82MB): dead after vis gemm
    u16* VA_LO = VA_HI + (size_t)Nn * 1024;
    float* CLSH = XRreg;                       // classifier hidden [0,10.3MB): after last aggr
    u16* HS2_HI = (u16*)(XRreg + (size_t)12 * 1000 * 1000); // HB split [48MB,78.7MB): after last aggr
    u16* HS2_LO = HS2_HI + (size_t)Nn * FD;

    // ---------------- CSR build (reused by all 4 RGAT calls) ----------------
    hipMemsetAsync(CNT, 0, Nn * sizeof(int), stream);
    edge_count_k<<<cdiv(ETOT, 256), 256, 0, stream>>>(ei0, ei1, ei2, CNT);
    scan_k<<<1, 1024, 0, stream>>>(CNT, ROWPTR, CURSOR);
    edge_fill_k<<<cdiv(ETOT, 256), 256, 0, stream>>>(ei0, ei1, ei2, CURSOR, EIDX, DSTE);
    hipMemsetAsync(GCNT, 0, 64 * sizeof(int), stream);
    gcount_k<<<cdiv(Nn, 256), 256, 0, stream>>>(batch, GCNT);

    // ---------------- weight + x_visual conversions ----------------
    tsplit_k<<<cdiv(3 * 384 * 384, 256), 256, 0, stream>>>(rgat_W[0], RW_HI, RW_LO, 384, 384, 3 * 384 * 384);
    tsplit_k<<<cdiv(3 * 384 * 384, 256), 256, 0, stream>>>(rgat_W[1], RW_HI + 3 * 384 * 384, RW_LO + 3 * 384 * 384, 384, 384, 3 * 384 * 384);
    tsplit_k<<<cdiv(1024 * 128, 256), 256, 0, stream>>>(vis_W, VW_HI, VW_LO, 1024, 128, 1024 * 128);
    tsplit_k<<<cdiv(384 * 128, 256), 256, 0, stream>>>(cls_W1, CW_HI, CW_LO, 384, 128, 384 * 128);
    split_k<<<cdiv(Nn * 1024 / 4, 256), 256, 0, stream>>>(x_visual, VA_HI, VA_LO, Nn * 1024 / 4);

    const int MB = cdiv(Nn, 128);   // 157

    // ---------------- vis encoder (MFMA) -> HCAT[:,0:128) ----------------
    hipMemsetAsync(STATS, 0, 2 * sizeof(float), stream);
    mgemm_k<true, true, true, false, 3><<<dim3(MB, 1, 1), 256, 0, stream>>>(
        VA_HI, VA_LO, VW_HI, VW_LO, vis_b, HCAT, Nn, 1024, FD, 0, STATS);
    enc_norm_k<<<cdiv(Nn * 32, 256), 256, 0, stream>>>(HCAT, vis_lnw, vis_lnb, STATS, 1.f / ((float)Nn * 128.f), HS0_HI, HS0_LO);

    // ---------------- geo encoder (fp32, K=6) -> HCAT[:,128:256) ----------------
    dim3 genc(cdiv(Nn, 64), 2, 1);
    hipMemsetAsync(STATS, 0, 2 * sizeof(float), stream);
    sgemm_k<true, true, true><<<genc, 256, 0, stream>>>(x_geom, geo_W, geo_b, HCAT + 128, Nn, 6, 128, FD, STATS);
    enc_norm_k<<<cdiv(Nn * 32, 256), 256, 0, stream>>>(HCAT + 128, geo_lnw, geo_lnb, STATS, 1.f / ((float)Nn * 128.f), HS0_HI + 128, HS0_LO + 128);

    for (int t = 0; t < 2; t++) {
        // prior encoder (fp32, K=33) -> HCAT[:,256:384)
        const float* pin = t ? PRIOR : x_prior;
        hipMemsetAsync(STATS, 0, 2 * sizeof(float), stream);
        sgemm_k<true, true, true><<<genc, 256, 0, stream>>>(pin, pri_W, pri_b, HCAT + 256, Nn, 33, 128, FD, STATS);
        enc_norm_k<<<cdiv(Nn * 32, 256), 256, 0, stream>>>(HCAT + 256, pri_lnw, pri_lnb, STATS, 1.f / ((float)Nn * 128.f), HS0_HI + 256, HS0_LO + 256);

        float* hin = HCAT;
        for (int L = 0; L < 2; L++) {
            float* hout = L ? HB : HA;
            const u16* ahi = L ? HS1_HI : HS0_HI;
            const u16* alo = L ? HS1_LO : HS0_LO;
            u16* shi = L ? HS2_HI : HS1_HI;
            u16* slo = L ? HS2_LO : HS1_LO;
            mgemm_k<false, false, false, true, 2><<<dim3(MB, 3, 3), 256, 0, stream>>>(
                ahi, alo, RW_HI + (size_t)L * 3 * 384 * 384, RW_LO + (size_t)L * 3 * 384 * 384,
                nullptr, XR16, Nn, 384, FD, 384 * 384, nullptr);
            proj_qk_k<<<cdiv(3 * Nn, 4), 256, 0, stream>>>(XR16, rgat_q[L], rgat_kk[L], QI, KJ);
            ew_k<<<cdiv(ETOT, 256), 256, 0, stream>>>(QI, KJ, EIDX, DSTE, EW);
            hipMemsetAsync(GSUM, 0, 128 * sizeof(float), stream);  // GSUM+GSQ contiguous
            aggr_k<<<Nn / 2, 256, 0, stream>>>(XR16, EW, ROWPTR, EIDX, rgat_bias[L],
                                               hin, batch, hout, GSUM, GSQ);
            gnorm_split_k<<<cdiv(Nn * 96, 256), 256, 0, stream>>>(hout, batch, GSUM, GSQ, GCNT, ln_w[L], ln_b[L], shi, slo);
            hin = hout;
        }

        // classifier: cls1 (MFMA, reads HS2 split) -> CLSH, cls2 (fp32) -> OUT
        mgemm_k<true, true, false, false, 3><<<dim3(MB, 1, 1), 256, 0, stream>>>(
            HS2_HI, HS2_LO, CW_HI, CW_LO, cls_b1, CLSH, Nn, 384, 128, 0, nullptr);
        sgemm_k<true, false, false><<<dim3(cdiv(Nn, 64), 1, 1), 256, 0, stream>>>(
            CLSH, cls_W2, cls_b2, OUT, Nn, 128, 32, 32, nullptr);

        if (t == 0)
            softmax_prior_k<<<cdiv(Nn, 8), 256, 0, stream>>>(OUT, PRIOR);
    }
}

// Round 7
// 1248.007 us; speedup vs baseline: 1.1342x; 1.1342x over previous
//
#include <hip/hip_runtime.h>
#include <hip/hip_bf16.h>

#define Nn 20000
#define EREL 60000
#define ETOT 180000
#define NG 64
#define FD 384
#define EPS 1e-5f

typedef unsigned short u16;
typedef unsigned int u32;
typedef __attribute__((ext_vector_type(8))) short s8v;     // 8 bf16 (4 VGPR) MFMA A/B frag
typedef __attribute__((ext_vector_type(4))) float f4v;     // MFMA C/D frag

static inline int cdiv(int a, int b) { return (a + b - 1) / b; }

__device__ inline u16 f2b(float f) {
    __hip_bfloat16 h = __float2bfloat16(f);
    union { __hip_bfloat16 b; u16 u; } c; c.b = h; return c.u;
}
__device__ inline float b2f(u16 u) {
    union { __hip_bfloat16 b; u16 u; } c; c.u = u; return __bfloat162float(c.b);
}

// ---------------- split fp32 -> bf16 hi/lo (vectorized by float4) ----------------
__global__ __launch_bounds__(256) void split_k(const float* __restrict__ x,
    u16* __restrict__ hi, u16* __restrict__ lo, int n4)
{
    int i = blockIdx.x * 256 + threadIdx.x;
    if (i >= n4) return;
    float4 v = ((const float4*)x)[i];
    ushort4 h, l;
    h.x = f2b(v.x); l.x = f2b(v.x - b2f(h.x));
    h.y = f2b(v.y); l.y = f2b(v.y - b2f(h.y));
    h.z = f2b(v.z); l.z = f2b(v.z - b2f(h.z));
    h.w = f2b(v.w); l.w = f2b(v.w - b2f(h.w));
    ((ushort4*)hi)[i] = h;
    ((ushort4*)lo)[i] = l;
}

// transpose + split: W[b][K][N] -> T[b][N][K] hi/lo
__global__ void tsplit_k(const float* __restrict__ W, u16* __restrict__ hi,
                         u16* __restrict__ lo, int K, int N, int total)
{
    int idx = blockIdx.x * 256 + threadIdx.x;
    if (idx >= total) return;
    int kn = K * N;
    int b = idx / kn, rem = idx - b * kn;
    int k = rem / N, n = rem - k * N;
    float v = W[idx];
    u16 h = f2b(v), l = f2b(v - b2f(h));
    int o = b * kn + n * K + k;
    hi[o] = h; lo[o] = l;
}

// ---------------- split-bf16 MFMA GEMM ----------------
// C[M,N] = A[M,K] @ B[N,K]^T, A,B bf16 (hi,lo) pairs row-major ld=K. 128x128 tile,
// 4 waves of 64x64, 16x16x32 MFMA. TERMS=3: hi*bh + lo*bh + hi*bl (~fp32).
// TERMS=2: hi*bh + lo*bh (B-lo never read) — for outputs rounded to bf16 anyway.
template<bool BIAS, bool RELU, bool STATS, bool OB16, int TERMS>
__global__ __launch_bounds__(256) void mgemm_k(
    const u16* __restrict__ Ahi, const u16* __restrict__ Alo,
    const u16* __restrict__ Bhi, const u16* __restrict__ Blo,
    const float* __restrict__ bias, void* __restrict__ Cv,
    int M, int K, int ldc, int bstride, float* __restrict__ stats)
{
    __shared__ u16 lds[4 * 128 * 32];   // Ahi | Alo | Bhi | (Blo) tiles, [128][32] each
    __shared__ float red[256];
    const int t = threadIdx.x;
    const int brow = blockIdx.x * 128, bcol = blockIdx.y * 128;
    const int z = blockIdx.z;
    Bhi += (size_t)z * bstride;
    Blo += (size_t)z * bstride;
    float* Cf = OB16 ? nullptr : (float*)Cv + (size_t)z * M * ldc;
    u16*   Ch = OB16 ? (u16*)Cv + (size_t)z * M * ldc : nullptr;

    const int NSRC = (TERMS == 3) ? 8 : 6;
    const int r0 = t >> 2, sl = t & 3;
    const int rA0 = min(brow + r0, M - 1);
    const int rA1 = min(brow + r0 + 64, M - 1);
    const u16* gsrc[8];
    gsrc[0] = Ahi + (size_t)rA0 * K + sl * 8;
    gsrc[1] = Ahi + (size_t)rA1 * K + sl * 8;
    gsrc[2] = Alo + (size_t)rA0 * K + sl * 8;
    gsrc[3] = Alo + (size_t)rA1 * K + sl * 8;
    gsrc[4] = Bhi + (size_t)(bcol + r0) * K + sl * 8;
    gsrc[5] = Bhi + (size_t)(bcol + r0 + 64) * K + sl * 8;
    gsrc[6] = Blo + (size_t)(bcol + r0) * K + sl * 8;
    gsrc[7] = Blo + (size_t)(bcol + r0 + 64) * K + sl * 8;
    const int swz = (sl ^ (r0 & 3)) << 3;
    int ldst[8];
    #pragma unroll
    for (int i = 0; i < 8; i++) {
        int tile = i >> 1, row = r0 + 64 * (i & 1);
        ldst[i] = tile * 4096 + row * 32 + swz;
    }

    const int l = t & 63, w = t >> 6;
    const int wr = (w >> 1) * 64, wc = (w & 1) * 64;
    const int lr = l & 15, kq = l >> 4;

    f4v acc[4][4] = {};
    const int NK = K >> 5;

    s8v stg[8];
    #pragma unroll
    for (int i = 0; i < 8; i++) if (i < NSRC) stg[i] = *(const s8v*)gsrc[i];

    for (int kc = 0; kc < NK; kc++) {
        if (kc) __syncthreads();
        #pragma unroll
        for (int i = 0; i < 8; i++) if (i < NSRC) *(s8v*)(lds + ldst[i]) = stg[i];
        __syncthreads();
        if (kc + 1 < NK) {
            const int ko = (kc + 1) * 32;
            #pragma unroll
            for (int i = 0; i < 8; i++) if (i < NSRC) stg[i] = *(const s8v*)(gsrc[i] + ko);
        }
        #define LDR(T, row) (*(const s8v*)(lds + (T) * 4096 + (row) * 32 + ((kq ^ ((row) & 3)) << 3)))
        s8v bh[4], bl[4];
        #pragma unroll
        for (int tn = 0; tn < 4; tn++) {
            int rb = wc + tn * 16 + lr;
            bh[tn] = LDR(2, rb);
            if (TERMS == 3) bl[tn] = LDR(3, rb);
        }
        #pragma unroll
        for (int tm = 0; tm < 4; tm++) {
            int ra = wr + tm * 16 + lr;
            s8v ah = LDR(0, ra);
            s8v al = LDR(1, ra);
            #pragma unroll
            for (int tn = 0; tn < 4; tn++) {
                acc[tm][tn] = __builtin_amdgcn_mfma_f32_16x16x32_bf16(ah, bh[tn], acc[tm][tn], 0, 0, 0);
                acc[tm][tn] = __builtin_amdgcn_mfma_f32_16x16x32_bf16(al, bh[tn], acc[tm][tn], 0, 0, 0);
                if (TERMS == 3)
                    acc[tm][tn] = __builtin_amdgcn_mfma_f32_16x16x32_bf16(ah, bl[tn], acc[tm][tn], 0, 0, 0);
            }
        }
        #undef LDR
    }

    float s1 = 0.f, s2 = 0.f;
    #pragma unroll
    for (int tm = 0; tm < 4; tm++) {
        #pragma unroll
        for (int rg = 0; rg < 4; rg++) {
            int row = brow + wr + tm * 16 + kq * 4 + rg;
            if (row < M) {
                #pragma unroll
                for (int tn = 0; tn < 4; tn++) {
                    int col = bcol + wc + tn * 16 + lr;
                    float v = acc[tm][tn][rg];
                    if (BIAS) v += bias[col];
                    if (RELU) v = fmaxf(v, 0.f);
                    if (OB16) Ch[(size_t)row * ldc + col] = f2b(v);
                    else      Cf[(size_t)row * ldc + col] = v;
                    if (STATS) { s1 += v; s2 += v * v; }
                }
            }
        }
    }
    if (STATS) {
        __syncthreads();
        red[t] = s1; __syncthreads();
        for (int o = 128; o; o >>= 1) { if (t < o) red[t] += red[t + o]; __syncthreads(); }
        if (t == 0) atomicAdd(&stats[0], red[0]);
        __syncthreads();
        red[t] = s2; __syncthreads();
        for (int o = 128; o; o >>= 1) { if (t < o) red[t] += red[t + o]; __syncthreads(); }
        if (t == 0) atomicAdd(&stats[1], red[0]);
    }
}

// ---------------- fp32 tiled GEMM (tiny-K shapes: geo K=6, pri K=33, cls2) ----------------
template<bool BIAS, bool RELU, bool STATS>
__global__ __launch_bounds__(256) void sgemm_k(
    const float* __restrict__ A, const float* __restrict__ B,
    const float* __restrict__ bias, float* __restrict__ C,
    int M, int K, int N, int ldc, float* __restrict__ stats)
{
    const int BK = 16;
    const int r = blockIdx.z;
    B += (size_t)r * K * N;
    C += (size_t)r * M * ldc;
    __shared__ float As[16][65];
    __shared__ float Bs[16][64];
    int tid = threadIdx.x;
    int tx = tid & 15, ty = tid >> 4;
    int brow = blockIdx.x * 64, bcol = blockIdx.y * 64;
    float acc[4][4] = {};
    for (int k0 = 0; k0 < K; k0 += BK) {
        #pragma unroll
        for (int i = 0; i < 4; i++) {
            int e = tid + 256 * i;
            int ar = e >> 4, ak = e & 15;
            int gr = brow + ar, gk = k0 + ak;
            As[ak][ar] = (gr < M && gk < K) ? A[(size_t)gr * K + gk] : 0.f;
            int bk = e >> 6, bn = e & 63;
            int gbk = k0 + bk, gbn = bcol + bn;
            Bs[bk][bn] = (gbk < K && gbn < N) ? B[(size_t)gbk * N + gbn] : 0.f;
        }
        __syncthreads();
        #pragma unroll
        for (int k = 0; k < BK; k++) {
            float ra[4], rb[4];
            #pragma unroll
            for (int i = 0; i < 4; i++) ra[i] = As[k][ty * 4 + i];
            #pragma unroll
            for (int j = 0; j < 4; j++) rb[j] = Bs[k][tx * 4 + j];
            #pragma unroll
            for (int i = 0; i < 4; i++)
                #pragma unroll
                for (int j = 0; j < 4; j++)
                    acc[i][j] = fmaf(ra[i], rb[j], acc[i][j]);
        }
        __syncthreads();
    }
    float s1 = 0.f, s2 = 0.f;
    #pragma unroll
    for (int i = 0; i < 4; i++) {
        int row = brow + ty * 4 + i;
        #pragma unroll
        for (int j = 0; j < 4; j++) {
            int col = bcol + tx * 4 + j;
            if (row < M && col < N) {
                float v = acc[i][j];
                if (BIAS) v += bias[col];
                if (RELU) v = v > 0.f ? v : 0.f;
                C[(size_t)row * ldc + col] = v;
                if (STATS) { s1 += v; s2 += v * v; }
            }
        }
    }
    if (STATS) {
        __shared__ float red[256];
        __syncthreads();
        red[tid] = s1; __syncthreads();
        for (int o = 128; o; o >>= 1) { if (tid < o) red[tid] += red[tid + o]; __syncthreads(); }
        if (tid == 0) atomicAdd(&stats[0], red[0]);
        __syncthreads();
        red[tid] = s2; __syncthreads();
        for (int o = 128; o; o >>= 1) { if (tid < o) red[tid] += red[tid + o]; __syncthreads(); }
        if (tid == 0) atomicAdd(&stats[1], red[0]);
    }
}

// scalar-LN of a 128-col block of H (pre-offset) from RAW sums, fused bf16 hi/lo split.
__global__ __launch_bounds__(256) void enc_norm_k(float* __restrict__ H, const float* __restrict__ w,
                           const float* __restrict__ b, const float* __restrict__ stats,
                           float cntinv, u16* __restrict__ hi, u16* __restrict__ lo)
{
    int i = blockIdx.x * 256 + threadIdx.x;   // float4 index within the 128-col block
    if (i >= Nn * 32) return;
    int n = i >> 5, c4 = i & 31;
    float m = stats[0] * cntinv;
    float var = stats[1] * cntinv - m * m;
    float s = 1.f / (sqrtf(fmaxf(var, 0.f)) + EPS);
    float4 wv = ((const float4*)w)[c4];
    float4 bv = ((const float4*)b)[c4];
    float4* p = (float4*)(H + (size_t)n * FD) + c4;
    float4 v = *p;
    v.x = (v.x - m) * s * wv.x + bv.x;
    v.y = (v.y - m) * s * wv.y + bv.y;
    v.z = (v.z - m) * s * wv.z + bv.z;
    v.w = (v.w - m) * s * wv.w + bv.w;
    *p = v;
    ushort4 hh, ll;
    hh.x = f2b(v.x); ll.x = f2b(v.x - b2f(hh.x));
    hh.y = f2b(v.y); ll.y = f2b(v.y - b2f(hh.y));
    hh.z = f2b(v.z); ll.z = f2b(v.z - b2f(hh.z));
    hh.w = f2b(v.w); ll.w = f2b(v.w - b2f(hh.w));
    ((ushort4*)(hi + (size_t)n * FD))[c4] = hh;
    ((ushort4*)(lo + (size_t)n * FD))[c4] = ll;
}

// qi[r,n,h] = xr[r,n,:] . q[:,h] ; kj likewise. One wave per (r,n) row. XR is bf16.
__global__ __launch_bounds__(256) void proj_qk_k(const u16* __restrict__ xr,
    const float* __restrict__ q, const float* __restrict__ kk,
    float* __restrict__ qi, float* __restrict__ kj)
{
    int row = blockIdx.x * 4 + (threadIdx.x >> 6);
    int lane = threadIdx.x & 63;
    if (row >= 3 * Nn) return;
    const u16* xrow = xr + (size_t)row * FD;
    float pq[8] = {}, pk[8] = {};
    #pragma unroll
    for (int j = 0; j < 6; j++) {
        int c = lane + 64 * j;
        float x = b2f(xrow[c]);
        #pragma unroll
        for (int h = 0; h < 8; h++) {
            pq[h] = fmaf(x, q[c * 8 + h], pq[h]);
            pk[h] = fmaf(x, kk[c * 8 + h], pk[h]);
        }
    }
    #pragma unroll
    for (int o = 32; o; o >>= 1) {
        #pragma unroll
        for (int h = 0; h < 8; h++) {
            pq[h] += __shfl_down(pq[h], o);
            pk[h] += __shfl_down(pk[h], o);
        }
    }
    if (lane == 0) {
        #pragma unroll
        for (int h = 0; h < 8; h++) {
            qi[(size_t)row * 8 + h] = pq[h];
            kj[(size_t)row * 8 + h] = pk[h];
        }
    }
}

// per-edge unnormalized attention weights: ew[e][h] = exp(leaky(qi[et,dst,h]+kj[et,src,h]))
__global__ __launch_bounds__(256) void ew_k(const float* __restrict__ qi,
    const float* __restrict__ kj, const int* __restrict__ eidx,
    const int* __restrict__ dste, float* __restrict__ ew)
{
    int e = blockIdx.x * 256 + threadIdx.x;
    if (e >= ETOT) return;
    int p = eidx[e];
    int src = p & 0xFFFFFF, et = p >> 24;
    int dst = dste[e];
    const float4* q4 = (const float4*)(qi + ((size_t)et * Nn + dst) * 8);
    const float4* k4 = (const float4*)(kj + ((size_t)et * Nn + src) * 8);
    float4 out[2];
    #pragma unroll
    for (int half = 0; half < 2; half++) {
        float4 qv = q4[half], kv = k4[half];
        float a0 = qv.x + kv.x, a1 = qv.y + kv.y, a2 = qv.z + kv.z, a3 = qv.w + kv.w;
        a0 = (a0 > 0.f) ? a0 : 0.2f * a0;
        a1 = (a1 > 0.f) ? a1 : 0.2f * a1;
        a2 = (a2 > 0.f) ? a2 : 0.2f * a2;
        a3 = (a3 > 0.f) ? a3 : 0.2f * a3;
        out[half] = make_float4(__expf(a0), __expf(a1), __expf(a2), __expf(a3));
    }
    float4* ew4 = (float4*)(ew + (size_t)e * 8);
    ew4[0] = out[0];
    ew4[1] = out[1];
}

__global__ void edge_count_k(const int* __restrict__ e0, const int* __restrict__ e1,
                             const int* __restrict__ e2, int* __restrict__ cnt)
{
    int e = blockIdx.x * 256 + threadIdx.x;
    if (e >= ETOT) return;
    int r = e / EREL, i = e - r * EREL;
    const int* ei = (r == 0) ? e0 : (r == 1) ? e1 : e2;
    atomicAdd(&cnt[ei[EREL + i]], 1);
}

__global__ void edge_fill_k(const int* __restrict__ e0, const int* __restrict__ e1,
                            const int* __restrict__ e2, int* __restrict__ cursor,
                            int* __restrict__ eidx, int* __restrict__ dste)
{
    int e = blockIdx.x * 256 + threadIdx.x;
    if (e >= ETOT) return;
    int r = e / EREL, i = e - r * EREL;
    const int* ei = (r == 0) ? e0 : (r == 1) ? e1 : e2;
    int src = ei[i], dst = ei[EREL + i];
    int pos = atomicAdd(&cursor[dst], 1);
    eidx[pos] = src | (r << 24);
    dste[pos] = dst;
}

__global__ __launch_bounds__(1024) void scan_k(const int* __restrict__ cnt,
                                               int* __restrict__ rowptr, int* __restrict__ cursor)
{
    __shared__ int lds[1024];
    __shared__ int carry;
    int t = threadIdx.x;
    if (t == 0) carry = 0;
    __syncthreads();
    for (int base = 0; base < Nn; base += 1024) {
        int i = base + t;
        int v = (i < Nn) ? cnt[i] : 0;
        lds[t] = v; __syncthreads();
        for (int o = 1; o < 1024; o <<= 1) {
            int x = (t >= o) ? lds[t - o] : 0;
            __syncthreads();
            lds[t] += x;
            __syncthreads();
        }
        int c = carry;
        if (i < Nn) { int ex = c + lds[t] - v; rowptr[i] = ex; cursor[i] = ex; }
        __syncthreads();
        if (t == 1023) carry = c + lds[1023];
        __syncthreads();
    }
    if (t == 0) rowptr[Nn] = carry;
}

__global__ void gcount_k(const int* __restrict__ batch, int* __restrict__ gcnt)
{
    int n = blockIdx.x * 256 + threadIdx.x;
    if (n >= Nn) return;
    atomicAdd(&gcnt[batch[n]], 1);
}

// RGAT aggregation from precomputed EW. One wave per dst node, SINGLE pass over edges
// (den and unnormalized acc accumulated together; normalize in epilogue).
// Rows gathered as dwords (2 bf16/lane/chunk, bit-shift convert). Fused elu/residual/stats.
__global__ __launch_bounds__(256) void aggr_k(const u16* __restrict__ xr,
    const float* __restrict__ ew, const int* __restrict__ rowptr, const int* __restrict__ eidx,
    const float* __restrict__ bias, const float* __restrict__ hin,
    const int* __restrict__ batch, float* __restrict__ out,
    float* __restrict__ gsum, float* __restrict__ gsq)
{
    __shared__ float ls[NG], lq[NG];
    int t = threadIdx.x;
    if (t < NG) { ls[t] = 0.f; lq[t] = 0.f; }
    __syncthreads();
    int node = blockIdx.x * 4 + (t >> 6);
    int lane = t & 63;
    int e0 = rowptr[node], e1 = rowptr[node + 1];
    int hd[3];
    #pragma unroll
    for (int j = 0; j < 3; j++) hd[j] = (lane * 2 + 128 * j) / 48;  // c,c+1 same head (c even)
    float den = 0.f;                 // lane h < 8 accumulates head h
    float accx[3] = {}, accy[3] = {};
    for (int e = e0; e < e1; e++) {
        int p = eidx[e];
        int srcn = p & 0xFFFFFF, et = p >> 24;
        float ev = (lane < 8) ? ew[(size_t)e * 8 + lane] : 0.f;
        den += ev;
        const u32* row = (const u32*)(xr + ((size_t)et * Nn + srcn) * FD);
        #pragma unroll
        for (int j = 0; j < 3; j++) {
            float a = __shfl(ev, hd[j]);
            u32 u = row[lane + 64 * j];
            accx[j] = fmaf(a, __uint_as_float(u << 16), accx[j]);
            accy[j] = fmaf(a, __uint_as_float(u & 0xffff0000u), accy[j]);
        }
    }
    float s1 = 0.f, s2 = 0.f;
    #pragma unroll
    for (int j = 0; j < 3; j++) {
        float dh = __shfl(den, hd[j]);
        float rcp = 1.f / (dh + 1e-16f);
        int c = lane * 2 + 128 * j;
        float2 bv = *(const float2*)(bias + c);
        float2 hv = *(const float2*)(hin + (size_t)node * FD + c);
        float vx = accx[j] * rcp + bv.x;
        float vy = accy[j] * rcp + bv.y;
        vx = (vx > 0.f) ? vx : expm1f(vx);
        vy = (vy > 0.f) ? vy : expm1f(vy);
        vx += hv.x; vy += hv.y;
        *(float2*)(out + (size_t)node * FD + c) = make_float2(vx, vy);
        s1 += vx + vy; s2 += vx * vx + vy * vy;
    }
    #pragma unroll
    for (int o = 32; o; o >>= 1) { s1 += __shfl_down(s1, o); s2 += __shfl_down(s2, o); }
    int g = batch[node];   // wave-uniform
    if (lane == 0) { atomicAdd(&ls[g], s1); atomicAdd(&lq[g], s2); }
    __syncthreads();
    if (t < NG && (ls[t] != 0.f || lq[t] != 0.f)) {
        atomicAdd(&gsum[t], ls[t]);
        atomicAdd(&gsq[t], lq[t]);
    }
}

// graph-LN (stats finalized inline from raw sums) + fused bf16 hi/lo split
__global__ __launch_bounds__(256) void gnorm_split_k(float* __restrict__ y,
    const int* __restrict__ batch, const float* __restrict__ gsum, const float* __restrict__ gsq,
    const int* __restrict__ gcnt, const float* __restrict__ w, const float* __restrict__ b,
    u16* __restrict__ hi, u16* __restrict__ lo)
{
    int i = blockIdx.x * 256 + threadIdx.x;   // float4 index
    if (i >= Nn * (FD / 4)) return;
    int n = i / 96, c4 = i - n * 96;
    int g = batch[n];
    float norm = fmaxf((float)gcnt[g], 1.f) * (float)FD;
    float m = gsum[g] / norm;
    float var = gsq[g] / norm - m * m;
    float rstd = rsqrtf(var + EPS);
    float4 wv = ((const float4*)w)[c4];
    float4 bv = ((const float4*)b)[c4];
    float4 v = ((const float4*)y)[i];
    v.x = (v.x - m) * rstd * wv.x + bv.x;
    v.y = (v.y - m) * rstd * wv.y + bv.y;
    v.z = (v.z - m) * rstd * wv.z + bv.z;
    v.w = (v.w - m) * rstd * wv.w + bv.w;
    ((float4*)y)[i] = v;
    ushort4 hh, ll;
    hh.x = f2b(v.x); ll.x = f2b(v.x - b2f(hh.x));
    hh.y = f2b(v.y); ll.y = f2b(v.y - b2f(hh.y));
    hh.z = f2b(v.z); ll.z = f2b(v.z - b2f(hh.z));
    hh.w = f2b(v.w); ll.w = f2b(v.w - b2f(hh.w));
    ((ushort4*)hi)[i] = hh;
    ((ushort4*)lo)[i] = ll;
}

__global__ void softmax_prior_k(const float* __restrict__ logits, float* __restrict__ prior)
{
    int n = blockIdx.x * 8 + (threadIdx.x >> 5);
    int l = threadIdx.x & 31;
    if (n >= Nn) return;
    float v = logits[n * 32 + l];
    float m = v;
    #pragma unroll
    for (int o = 16; o; o >>= 1) m = fmaxf(m, __shfl_xor(m, o, 32));
    float e = __expf(v - m);
    float s = e;
    #pragma unroll
    for (int o = 16; o; o >>= 1) s += __shfl_xor(s, o, 32);
    prior[(size_t)n * 33 + l] = e / s;
    if (l == 0) prior[(size_t)n * 33 + 32] = 1.f / s;
}

extern "C" void kernel_launch(void* const* d_in, const int* in_sizes, int n_in,
                              void* d_out, int out_size, void* d_ws, size_t ws_size,
                              hipStream_t stream)
{
    const float* x_visual = (const float*)d_in[0];
    const float* x_geom   = (const float*)d_in[1];
    const float* x_prior  = (const float*)d_in[2];
    const int* ei0   = (const int*)d_in[3];
    const int* ei1   = (const int*)d_in[4];
    const int* ei2   = (const int*)d_in[5];
    const int* batch = (const int*)d_in[6];
    const float* vis_W = (const float*)d_in[7];  const float* vis_b = (const float*)d_in[8];
    const float* vis_lnw = (const float*)d_in[9]; const float* vis_lnb = (const float*)d_in[10];
    const float* geo_W = (const float*)d_in[11]; const float* geo_b = (const float*)d_in[12];
    const float* geo_lnw = (const float*)d_in[13]; const float* geo_lnb = (const float*)d_in[14];
    const float* pri_W = (const float*)d_in[15]; const float* pri_b = (const float*)d_in[16];
    const float* pri_lnw = (const float*)d_in[17]; const float* pri_lnb = (const float*)d_in[18];
    const float* rgat_W[2]    = { (const float*)d_in[19], (const float*)d_in[25] };
    const float* rgat_q[2]    = { (const float*)d_in[20], (const float*)d_in[26] };
    const float* rgat_kk[2]   = { (const float*)d_in[21], (const float*)d_in[27] };
    const float* rgat_bias[2] = { (const float*)d_in[22], (const float*)d_in[28] };
    const float* ln_w[2]      = { (const float*)d_in[23], (const float*)d_in[29] };
    const float* ln_b[2]      = { (const float*)d_in[24], (const float*)d_in[30] };
    const float* cls_W1 = (const float*)d_in[31]; const float* cls_b1 = (const float*)d_in[32];
    const float* cls_W2 = (const float*)d_in[33]; const float* cls_b2 = (const float*)d_in[34];
    float* OUT = (float*)d_out;

    // ---------------- workspace layout ----------------
    float* ws = (float*)d_ws;
    float* XRreg = ws;                         // 3*Nn*FD floats reserved (92.2 MB region)
    u16*   XR16  = (u16*)XRreg;                // XR stored bf16: first 46 MB of the region
    float* HCAT  = XRreg + (size_t)3 * Nn * FD;
    float* HA    = HCAT + (size_t)Nn * FD;
    float* HB    = HA + (size_t)Nn * FD;
    float* PRIOR = HB + (size_t)Nn * FD;       // Nn*33
    float* QI    = PRIOR + (size_t)Nn * 33;
    float* KJ    = QI + (size_t)3 * Nn * 8;
    u16* HS0_HI  = (u16*)(KJ + (size_t)3 * Nn * 8);   // HCAT split
    u16* HS0_LO  = HS0_HI + (size_t)Nn * FD;
    u16* HS1_HI  = HS0_LO + (size_t)Nn * FD;          // HA split
    u16* HS1_LO  = HS1_HI + (size_t)Nn * FD;
    u16* RW_HI   = HS1_LO + (size_t)Nn * FD;   // 2*3*384*384
    u16* RW_LO   = RW_HI + (size_t)2 * 3 * 384 * 384;
    u16* VW_HI   = RW_LO + (size_t)2 * 3 * 384 * 384; // 128*1024
    u16* VW_LO   = VW_HI + (size_t)128 * 1024;
    u16* CW_HI   = VW_LO + (size_t)128 * 1024;        // 128*384
    u16* CW_LO   = CW_HI + (size_t)128 * 384;
    float* STATS = (float*)(CW_LO + (size_t)128 * 384); // 2
    float* GSUM  = STATS + 2;                  // 64
    float* GSQ   = GSUM + 64;
    int* CNT    = (int*)(GSQ + 64);
    int* ROWPTR = CNT + Nn;
    int* CURSOR = ROWPTR + Nn + 1;
    int* EIDX   = CURSOR + Nn;
    int* GCNT   = EIDX + ETOT;
    int* DSTE   = GCNT + 64;                   // ETOT
    float* EW   = (float*)(DSTE + ETOT);       // ETOT*8 floats (5.76 MB)
    // aliases into the XR region (temporally dead sub-ranges):
    u16* VA_HI = (u16*)XRreg;                  // x_visual split [0,82MB): dead after vis gemm
    u16* VA_LO = VA_HI + (size_t)Nn * 1024;
    float* CLSH = XRreg;                       // classifier hidden [0,10.3MB): after last aggr
    u16* HS2_HI = (u16*)(XRreg + (size_t)12 * 1000 * 1000); // HB split [48MB,78.7MB): after last aggr
    u16* HS2_LO = HS2_HI + (size_t)Nn * FD;

    // ---------------- CSR build (reused by all 4 RGAT calls) ----------------
    hipMemsetAsync(CNT, 0, Nn * sizeof(int), stream);
    edge_count_k<<<cdiv(ETOT, 256), 256, 0, stream>>>(ei0, ei1, ei2, CNT);
    scan_k<<<1, 1024, 0, stream>>>(CNT, ROWPTR, CURSOR);
    edge_fill_k<<<cdiv(ETOT, 256), 256, 0, stream>>>(ei0, ei1, ei2, CURSOR, EIDX, DSTE);
    hipMemsetAsync(GCNT, 0, 64 * sizeof(int), stream);
    gcount_k<<<cdiv(Nn, 256), 256, 0, stream>>>(batch, GCNT);

    // ---------------- weight + x_visual conversions ----------------
    tsplit_k<<<cdiv(3 * 384 * 384, 256), 256, 0, stream>>>(rgat_W[0], RW_HI, RW_LO, 384, 384, 3 * 384 * 384);
    tsplit_k<<<cdiv(3 * 384 * 384, 256), 256, 0, stream>>>(rgat_W[1], RW_HI + 3 * 384 * 384, RW_LO + 3 * 384 * 384, 384, 384, 3 * 384 * 384);
    tsplit_k<<<cdiv(1024 * 128, 256), 256, 0, stream>>>(vis_W, VW_HI, VW_LO, 1024, 128, 1024 * 128);
    tsplit_k<<<cdiv(384 * 128, 256), 256, 0, stream>>>(cls_W1, CW_HI, CW_LO, 384, 128, 384 * 128);
    split_k<<<cdiv(Nn * 1024 / 4, 256), 256, 0, stream>>>(x_visual, VA_HI, VA_LO, Nn * 1024 / 4);

    const int MB = cdiv(Nn, 128);   // 157

    // ---------------- vis encoder (MFMA) -> HCAT[:,0:128) ----------------
    hipMemsetAsync(STATS, 0, 2 * sizeof(float), stream);
    mgemm_k<true, true, true, false, 3><<<dim3(MB, 1, 1), 256, 0, stream>>>(
        VA_HI, VA_LO, VW_HI, VW_LO, vis_b, HCAT, Nn, 1024, FD, 0, STATS);
    enc_norm_k<<<cdiv(Nn * 32, 256), 256, 0, stream>>>(HCAT, vis_lnw, vis_lnb, STATS, 1.f / ((float)Nn * 128.f), HS0_HI, HS0_LO);

    // ---------------- geo encoder (fp32, K=6) -> HCAT[:,128:256) ----------------
    dim3 genc(cdiv(Nn, 64), 2, 1);
    hipMemsetAsync(STATS, 0, 2 * sizeof(float), stream);
    sgemm_k<true, true, true><<<genc, 256, 0, stream>>>(x_geom, geo_W, geo_b, HCAT + 128, Nn, 6, 128, FD, STATS);
    enc_norm_k<<<cdiv(Nn * 32, 256), 256, 0, stream>>>(HCAT + 128, geo_lnw, geo_lnb, STATS, 1.f / ((float)Nn * 128.f), HS0_HI + 128, HS0_LO + 128);

    for (int t = 0; t < 2; t++) {
        // prior encoder (fp32, K=33) -> HCAT[:,256:384)
        const float* pin = t ? PRIOR : x_prior;
        hipMemsetAsync(STATS, 0, 2 * sizeof(float), stream);
        sgemm_k<true, true, true><<<genc, 256, 0, stream>>>(pin, pri_W, pri_b, HCAT + 256, Nn, 33, 128, FD, STATS);
        enc_norm_k<<<cdiv(Nn * 32, 256), 256, 0, stream>>>(HCAT + 256, pri_lnw, pri_lnb, STATS, 1.f / ((float)Nn * 128.f), HS0_HI + 256, HS0_LO + 256);

        float* hin = HCAT;
        for (int L = 0; L < 2; L++) {
            float* hout = L ? HB : HA;
            const u16* ahi = L ? HS1_HI : HS0_HI;
            const u16* alo = L ? HS1_LO : HS0_LO;
            u16* shi = L ? HS2_HI : HS1_HI;
            u16* slo = L ? HS2_LO : HS1_LO;
            mgemm_k<false, false, false, true, 2><<<dim3(MB, 3, 3), 256, 0, stream>>>(
                ahi, alo, RW_HI + (size_t)L * 3 * 384 * 384, RW_LO + (size_t)L * 3 * 384 * 384,
                nullptr, XR16, Nn, 384, FD, 384 * 384, nullptr);
            proj_qk_k<<<cdiv(3 * Nn, 4), 256, 0, stream>>>(XR16, rgat_q[L], rgat_kk[L], QI, KJ);
            ew_k<<<cdiv(ETOT, 256), 256, 0, stream>>>(QI, KJ, EIDX, DSTE, EW);
            hipMemsetAsync(GSUM, 0, 128 * sizeof(float), stream);  // GSUM+GSQ contiguous
            aggr_k<<<cdiv(Nn, 4), 256, 0, stream>>>(XR16, EW, ROWPTR, EIDX, rgat_bias[L],
                                                    hin, batch, hout, GSUM, GSQ);
            gnorm_split_k<<<cdiv(Nn * 96, 256), 256, 0, stream>>>(hout, batch, GSUM, GSQ, GCNT, ln_w[L], ln_b[L], shi, slo);
            hin = hout;
        }

        // classifier: cls1 (MFMA, reads HS2 split) -> CLSH, cls2 (fp32) -> OUT
        mgemm_k<true, true, false, false, 3><<<dim3(MB, 1, 1), 256, 0, stream>>>(
            HS2_HI, HS2_LO, CW_HI, CW_LO, cls_b1, CLSH, Nn, 384, 128, 0, nullptr);
        sgemm_k<true, false, false><<<dim3(cdiv(Nn, 64), 1, 1), 256, 0, stream>>>(
            CLSH, cls_W2, cls_b2, OUT, Nn, 128, 32, 32, nullptr);

        if (t == 0)
            softmax_prior_k<<<cdiv(Nn, 8), 256, 0, stream>>>(OUT, PRIOR);
    }
}

// Round 8
// 987.055 us; speedup vs baseline: 1.4341x; 1.2644x over previous
//
#include <hip/hip_runtime.h>
#include <hip/hip_bf16.h>

#define Nn 20000
#define EREL 60000
#define ETOT 180000
#define NG 64
#define FD 384
#define EPS 1e-5f

typedef unsigned short u16;
typedef unsigned int u32;
typedef __attribute__((ext_vector_type(8))) short s8v;     // 8 bf16 (4 VGPR) MFMA A/B frag
typedef __attribute__((ext_vector_type(4))) float f4v;     // MFMA C/D frag

static inline int cdiv(int a, int b) { return (a + b - 1) / b; }

__device__ inline u16 f2b(float f) {
    __hip_bfloat16 h = __float2bfloat16(f);
    union { __hip_bfloat16 b; u16 u; } c; c.b = h; return c.u;
}
__device__ inline float b2f(u16 u) {
    union { __hip_bfloat16 b; u16 u; } c; c.u = u; return __bfloat162float(c.b);
}

// ---------------- split fp32 -> bf16 hi/lo (vectorized by float4) ----------------
__global__ __launch_bounds__(256) void split_k(const float* __restrict__ x,
    u16* __restrict__ hi, u16* __restrict__ lo, int n4)
{
    int i = blockIdx.x * 256 + threadIdx.x;
    if (i >= n4) return;
    float4 v = ((const float4*)x)[i];
    ushort4 h, l;
    h.x = f2b(v.x); l.x = f2b(v.x - b2f(h.x));
    h.y = f2b(v.y); l.y = f2b(v.y - b2f(h.y));
    h.z = f2b(v.z); l.z = f2b(v.z - b2f(h.z));
    h.w = f2b(v.w); l.w = f2b(v.w - b2f(h.w));
    ((ushort4*)hi)[i] = h;
    ((ushort4*)lo)[i] = l;
}

// transpose + split: W[b][K][N] -> T[b][N][K] hi/lo
__global__ void tsplit_k(const float* __restrict__ W, u16* __restrict__ hi,
                         u16* __restrict__ lo, int K, int N, int total)
{
    int idx = blockIdx.x * 256 + threadIdx.x;
    if (idx >= total) return;
    int kn = K * N;
    int b = idx / kn, rem = idx - b * kn;
    int k = rem / N, n = rem - k * N;
    float v = W[idx];
    u16 h = f2b(v), l = f2b(v - b2f(h));
    int o = b * kn + n * K + k;
    hi[o] = h; lo[o] = l;
}

// pack q (384x8) and k (384x8) into QKW[16][384] hi/lo: col<8 = q head, col>=8 = k head
__global__ void prep_qkw_k(const float* __restrict__ q, const float* __restrict__ kk,
                           u16* __restrict__ hi, u16* __restrict__ lo)
{
    int idx = blockIdx.x * 256 + threadIdx.x;
    if (idx >= 16 * 384) return;
    int col = idx / 384, k = idx - col * 384;
    float v = (col < 8) ? q[k * 8 + col] : kk[k * 8 + col - 8];
    u16 h = f2b(v), l = f2b(v - b2f(h));
    hi[idx] = h; lo[idx] = l;
}

// ---------------- split-bf16 MFMA GEMM ----------------
// C[M,N] = A[M,K] @ B[N,K]^T, A,B bf16 (hi,lo) pairs row-major ld=K. 128x128 tile,
// 4 waves of 64x64, 16x16x32 MFMA. TERMS=3: hi*bh + lo*bh + hi*bl (~fp32).
// TERMS=2: hi*bh + lo*bh (B-lo never read) — for outputs rounded to bf16 anyway.
template<bool BIAS, bool RELU, bool STATS, bool OB16, int TERMS>
__global__ __launch_bounds__(256) void mgemm_k(
    const u16* __restrict__ Ahi, const u16* __restrict__ Alo,
    const u16* __restrict__ Bhi, const u16* __restrict__ Blo,
    const float* __restrict__ bias, void* __restrict__ Cv,
    int M, int K, int ldc, int bstride, float* __restrict__ stats)
{
    __shared__ u16 lds[4 * 128 * 32];   // Ahi | Alo | Bhi | (Blo) tiles, [128][32] each
    __shared__ float red[256];
    const int t = threadIdx.x;
    const int brow = blockIdx.x * 128, bcol = blockIdx.y * 128;
    const int z = blockIdx.z;
    Bhi += (size_t)z * bstride;
    Blo += (size_t)z * bstride;
    float* Cf = OB16 ? nullptr : (float*)Cv + (size_t)z * M * ldc;
    u16*   Ch = OB16 ? (u16*)Cv + (size_t)z * M * ldc : nullptr;

    const int NSRC = (TERMS == 3) ? 8 : 6;
    const int r0 = t >> 2, sl = t & 3;
    const int rA0 = min(brow + r0, M - 1);
    const int rA1 = min(brow + r0 + 64, M - 1);
    const u16* gsrc[8];
    gsrc[0] = Ahi + (size_t)rA0 * K + sl * 8;
    gsrc[1] = Ahi + (size_t)rA1 * K + sl * 8;
    gsrc[2] = Alo + (size_t)rA0 * K + sl * 8;
    gsrc[3] = Alo + (size_t)rA1 * K + sl * 8;
    gsrc[4] = Bhi + (size_t)(bcol + r0) * K + sl * 8;
    gsrc[5] = Bhi + (size_t)(bcol + r0 + 64) * K + sl * 8;
    gsrc[6] = Blo + (size_t)(bcol + r0) * K + sl * 8;
    gsrc[7] = Blo + (size_t)(bcol + r0 + 64) * K + sl * 8;
    const int swz = (sl ^ (r0 & 3)) << 3;
    int ldst[8];
    #pragma unroll
    for (int i = 0; i < 8; i++) {
        int tile = i >> 1, row = r0 + 64 * (i & 1);
        ldst[i] = tile * 4096 + row * 32 + swz;
    }

    const int l = t & 63, w = t >> 6;
    const int wr = (w >> 1) * 64, wc = (w & 1) * 64;
    const int lr = l & 15, kq = l >> 4;

    f4v acc[4][4] = {};
    const int NK = K >> 5;

    s8v stg[8];
    #pragma unroll
    for (int i = 0; i < 8; i++) if (i < NSRC) stg[i] = *(const s8v*)gsrc[i];

    for (int kc = 0; kc < NK; kc++) {
        if (kc) __syncthreads();
        #pragma unroll
        for (int i = 0; i < 8; i++) if (i < NSRC) *(s8v*)(lds + ldst[i]) = stg[i];
        __syncthreads();
        if (kc + 1 < NK) {
            const int ko = (kc + 1) * 32;
            #pragma unroll
            for (int i = 0; i < 8; i++) if (i < NSRC) stg[i] = *(const s8v*)(gsrc[i] + ko);
        }
        #define LDR(T, row) (*(const s8v*)(lds + (T) * 4096 + (row) * 32 + ((kq ^ ((row) & 3)) << 3)))
        s8v bh[4], bl[4];
        #pragma unroll
        for (int tn = 0; tn < 4; tn++) {
            int rb = wc + tn * 16 + lr;
            bh[tn] = LDR(2, rb);
            if (TERMS == 3) bl[tn] = LDR(3, rb);
        }
        #pragma unroll
        for (int tm = 0; tm < 4; tm++) {
            int ra = wr + tm * 16 + lr;
            s8v ah = LDR(0, ra);
            s8v al = LDR(1, ra);
            #pragma unroll
            for (int tn = 0; tn < 4; tn++) {
                acc[tm][tn] = __builtin_amdgcn_mfma_f32_16x16x32_bf16(ah, bh[tn], acc[tm][tn], 0, 0, 0);
                acc[tm][tn] = __builtin_amdgcn_mfma_f32_16x16x32_bf16(al, bh[tn], acc[tm][tn], 0, 0, 0);
                if (TERMS == 3)
                    acc[tm][tn] = __builtin_amdgcn_mfma_f32_16x16x32_bf16(ah, bl[tn], acc[tm][tn], 0, 0, 0);
            }
        }
        #undef LDR
    }

    float s1 = 0.f, s2 = 0.f;
    #pragma unroll
    for (int tm = 0; tm < 4; tm++) {
        #pragma unroll
        for (int rg = 0; rg < 4; rg++) {
            int row = brow + wr + tm * 16 + kq * 4 + rg;
            if (row < M) {
                #pragma unroll
                for (int tn = 0; tn < 4; tn++) {
                    int col = bcol + wc + tn * 16 + lr;
                    float v = acc[tm][tn][rg];
                    if (BIAS) v += bias[col];
                    if (RELU) v = fmaxf(v, 0.f);
                    if (OB16) Ch[(size_t)row * ldc + col] = f2b(v);
                    else      Cf[(size_t)row * ldc + col] = v;
                    if (STATS) { s1 += v; s2 += v * v; }
                }
            }
        }
    }
    if (STATS) {
        __syncthreads();
        red[t] = s1; __syncthreads();
        for (int o = 128; o; o >>= 1) { if (t < o) red[t] += red[t + o]; __syncthreads(); }
        if (t == 0) atomicAdd(&stats[0], red[0]);
        __syncthreads();
        red[t] = s2; __syncthreads();
        for (int o = 128; o; o >>= 1) { if (t < o) red[t] += red[t + o]; __syncthreads(); }
        if (t == 0) atomicAdd(&stats[1], red[0]);
    }
}

// ---------------- proj GEMM: QIK[3Nn,16] = XR[3Nn,384] @ QKW[16,384]^T ----------------
// A = bf16 XR (exact). B = fp32 weights as hi/lo (2 MFMA terms). 128 rows/block,
// 4 waves x 2 fragments. B (24KB, stride 392 u16 vs bank conflicts) loaded to LDS once.
__global__ __launch_bounds__(256) void proj_k(const u16* __restrict__ xr,
    const u16* __restrict__ qkw_hi, const u16* __restrict__ qkw_lo,
    float* __restrict__ qik)
{
    const int M3 = 3 * Nn;
    __shared__ u16 a_lds[128 * 32];
    __shared__ u16 b_lds[2][16 * 392];
    int t = threadIdx.x;
    int brow = blockIdx.x * 128;

    // B: 16 cols x 384 k, hi+lo, once
    for (int i = t; i < 768; i += 256) {
        int col = i / 48, c8 = (i - col * 48) * 8;
        *(s8v*)&b_lds[0][col * 392 + c8] = *(const s8v*)(qkw_hi + col * 384 + c8);
        *(s8v*)&b_lds[1][col * 392 + c8] = *(const s8v*)(qkw_lo + col * 384 + c8);
    }

    // A staging: thread t loads 2 x 16B chunks of row (t>>1)
    int ar = t >> 1;
    int sl0 = (t & 1) * 2;
    int grow = min(brow + ar, M3 - 1);
    const u16* asrc = xr + (size_t)grow * 384;
    int adst0 = ar * 32 + ((sl0 ^ (ar & 3)) << 3);
    int adst1 = ar * 32 + (((sl0 + 1) ^ (ar & 3)) << 3);

    int l = t & 63, w = t >> 6;
    int lr = l & 15, kq = l >> 4;
    f4v acc0 = {}, acc1 = {};

    s8v stg0 = *(const s8v*)(asrc + sl0 * 8);
    s8v stg1 = *(const s8v*)(asrc + sl0 * 8 + 8);
    for (int kc = 0; kc < 12; kc++) {
        if (kc) __syncthreads();
        *(s8v*)&a_lds[adst0] = stg0;
        *(s8v*)&a_lds[adst1] = stg1;
        __syncthreads();
        if (kc + 1 < 12) {
            int ko = (kc + 1) * 32 + sl0 * 8;
            stg0 = *(const s8v*)(asrc + ko);
            stg1 = *(const s8v*)(asrc + ko + 8);
        }
        s8v bh = *(const s8v*)&b_lds[0][lr * 392 + kc * 32 + kq * 8];
        s8v bl = *(const s8v*)&b_lds[1][lr * 392 + kc * 32 + kq * 8];
        int r0 = w * 32 + lr;
        s8v a0 = *(const s8v*)&a_lds[r0 * 32 + ((kq ^ (r0 & 3)) << 3)];
        int r1 = r0 + 16;
        s8v a1 = *(const s8v*)&a_lds[r1 * 32 + ((kq ^ (r1 & 3)) << 3)];
        acc0 = __builtin_amdgcn_mfma_f32_16x16x32_bf16(a0, bh, acc0, 0, 0, 0);
        acc0 = __builtin_amdgcn_mfma_f32_16x16x32_bf16(a0, bl, acc0, 0, 0, 0);
        acc1 = __builtin_amdgcn_mfma_f32_16x16x32_bf16(a1, bh, acc1, 0, 0, 0);
        acc1 = __builtin_amdgcn_mfma_f32_16x16x32_bf16(a1, bl, acc1, 0, 0, 0);
    }
    #pragma unroll
    for (int rg = 0; rg < 4; rg++) {
        int row0 = brow + w * 32 + kq * 4 + rg;
        if (row0 < M3) qik[(size_t)row0 * 16 + lr] = acc0[rg];
        int row1 = row0 + 16;
        if (row1 < M3) qik[(size_t)row1 * 16 + lr] = acc1[rg];
    }
}

// ---------------- fp32 tiled GEMM (tiny-K shapes: geo K=6, pri K=33, cls2) ----------------
template<bool BIAS, bool RELU, bool STATS>
__global__ __launch_bounds__(256) void sgemm_k(
    const float* __restrict__ A, const float* __restrict__ B,
    const float* __restrict__ bias, float* __restrict__ C,
    int M, int K, int N, int ldc, float* __restrict__ stats)
{
    const int BK = 16;
    const int r = blockIdx.z;
    B += (size_t)r * K * N;
    C += (size_t)r * M * ldc;
    __shared__ float As[16][65];
    __shared__ float Bs[16][64];
    int tid = threadIdx.x;
    int tx = tid & 15, ty = tid >> 4;
    int brow = blockIdx.x * 64, bcol = blockIdx.y * 64;
    float acc[4][4] = {};
    for (int k0 = 0; k0 < K; k0 += BK) {
        #pragma unroll
        for (int i = 0; i < 4; i++) {
            int e = tid + 256 * i;
            int ar = e >> 4, ak = e & 15;
            int gr = brow + ar, gk = k0 + ak;
            As[ak][ar] = (gr < M && gk < K) ? A[(size_t)gr * K + gk] : 0.f;
            int bk = e >> 6, bn = e & 63;
            int gbk = k0 + bk, gbn = bcol + bn;
            Bs[bk][bn] = (gbk < K && gbn < N) ? B[(size_t)gbk * N + gbn] : 0.f;
        }
        __syncthreads();
        #pragma unroll
        for (int k = 0; k < BK; k++) {
            float ra[4], rb[4];
            #pragma unroll
            for (int i = 0; i < 4; i++) ra[i] = As[k][ty * 4 + i];
            #pragma unroll
            for (int j = 0; j < 4; j++) rb[j] = Bs[k][tx * 4 + j];
            #pragma unroll
            for (int i = 0; i < 4; i++)
                #pragma unroll
                for (int j = 0; j < 4; j++)
                    acc[i][j] = fmaf(ra[i], rb[j], acc[i][j]);
        }
        __syncthreads();
    }
    float s1 = 0.f, s2 = 0.f;
    #pragma unroll
    for (int i = 0; i < 4; i++) {
        int row = brow + ty * 4 + i;
        #pragma unroll
        for (int j = 0; j < 4; j++) {
            int col = bcol + tx * 4 + j;
            if (row < M && col < N) {
                float v = acc[i][j];
                if (BIAS) v += bias[col];
                if (RELU) v = v > 0.f ? v : 0.f;
                C[(size_t)row * ldc + col] = v;
                if (STATS) { s1 += v; s2 += v * v; }
            }
        }
    }
    if (STATS) {
        __shared__ float red[256];
        __syncthreads();
        red[tid] = s1; __syncthreads();
        for (int o = 128; o; o >>= 1) { if (tid < o) red[tid] += red[tid + o]; __syncthreads(); }
        if (tid == 0) atomicAdd(&stats[0], red[0]);
        __syncthreads();
        red[tid] = s2; __syncthreads();
        for (int o = 128; o; o >>= 1) { if (tid < o) red[tid] += red[tid + o]; __syncthreads(); }
        if (tid == 0) atomicAdd(&stats[1], red[0]);
    }
}

// scalar-LN of a 128-col block of H (pre-offset) from RAW sums, fused bf16 hi/lo split.
__global__ __launch_bounds__(256) void enc_norm_k(float* __restrict__ H, const float* __restrict__ w,
                           const float* __restrict__ b, const float* __restrict__ stats,
                           float cntinv, u16* __restrict__ hi, u16* __restrict__ lo)
{
    int i = blockIdx.x * 256 + threadIdx.x;   // float4 index within the 128-col block
    if (i >= Nn * 32) return;
    int n = i >> 5, c4 = i & 31;
    float m = stats[0] * cntinv;
    float var = stats[1] * cntinv - m * m;
    float s = 1.f / (sqrtf(fmaxf(var, 0.f)) + EPS);
    float4 wv = ((const float4*)w)[c4];
    float4 bv = ((const float4*)b)[c4];
    float4* p = (float4*)(H + (size_t)n * FD) + c4;
    float4 v = *p;
    v.x = (v.x - m) * s * wv.x + bv.x;
    v.y = (v.y - m) * s * wv.y + bv.y;
    v.z = (v.z - m) * s * wv.z + bv.z;
    v.w = (v.w - m) * s * wv.w + bv.w;
    *p = v;
    ushort4 hh, ll;
    hh.x = f2b(v.x); ll.x = f2b(v.x - b2f(hh.x));
    hh.y = f2b(v.y); ll.y = f2b(v.y - b2f(hh.y));
    hh.z = f2b(v.z); ll.z = f2b(v.z - b2f(hh.z));
    hh.w = f2b(v.w); ll.w = f2b(v.w - b2f(hh.w));
    ((ushort4*)(hi + (size_t)n * FD))[c4] = hh;
    ((ushort4*)(lo + (size_t)n * FD))[c4] = ll;
}

// per-edge unnormalized attention weights from fused QIK[row][16] (q: 0-7, k: 8-15)
__global__ __launch_bounds__(256) void ew_k(const float* __restrict__ qik,
    const int* __restrict__ eidx, const int* __restrict__ dste, float* __restrict__ ew)
{
    int e = blockIdx.x * 256 + threadIdx.x;
    if (e >= ETOT) return;
    int p = eidx[e];
    int src = p & 0xFFFFFF, et = p >> 24;
    int dst = dste[e];
    const float4* q4 = (const float4*)(qik + ((size_t)et * Nn + dst) * 16);
    const float4* k4 = (const float4*)(qik + ((size_t)et * Nn + src) * 16 + 8);
    float4 out[2];
    #pragma unroll
    for (int half = 0; half < 2; half++) {
        float4 qv = q4[half], kv = k4[half];
        float a0 = qv.x + kv.x, a1 = qv.y + kv.y, a2 = qv.z + kv.z, a3 = qv.w + kv.w;
        a0 = (a0 > 0.f) ? a0 : 0.2f * a0;
        a1 = (a1 > 0.f) ? a1 : 0.2f * a1;
        a2 = (a2 > 0.f) ? a2 : 0.2f * a2;
        a3 = (a3 > 0.f) ? a3 : 0.2f * a3;
        out[half] = make_float4(__expf(a0), __expf(a1), __expf(a2), __expf(a3));
    }
    float4* ew4 = (float4*)(ew + (size_t)e * 8);
    ew4[0] = out[0];
    ew4[1] = out[1];
}

__global__ void edge_count_k(const int* __restrict__ e0, const int* __restrict__ e1,
                             const int* __restrict__ e2, int* __restrict__ cnt)
{
    int e = blockIdx.x * 256 + threadIdx.x;
    if (e >= ETOT) return;
    int r = e / EREL, i = e - r * EREL;
    const int* ei = (r == 0) ? e0 : (r == 1) ? e1 : e2;
    atomicAdd(&cnt[ei[EREL + i]], 1);
}

__global__ void edge_fill_k(const int* __restrict__ e0, const int* __restrict__ e1,
                            const int* __restrict__ e2, int* __restrict__ cursor,
                            int* __restrict__ eidx, int* __restrict__ dste)
{
    int e = blockIdx.x * 256 + threadIdx.x;
    if (e >= ETOT) return;
    int r = e / EREL, i = e - r * EREL;
    const int* ei = (r == 0) ? e0 : (r == 1) ? e1 : e2;
    int src = ei[i], dst = ei[EREL + i];
    int pos = atomicAdd(&cursor[dst], 1);
    eidx[pos] = src | (r << 24);
    dste[pos] = dst;
}

__global__ __launch_bounds__(1024) void scan_k(const int* __restrict__ cnt,
                                               int* __restrict__ rowptr, int* __restrict__ cursor)
{
    __shared__ int lds[1024];
    __shared__ int carry;
    int t = threadIdx.x;
    if (t == 0) carry = 0;
    __syncthreads();
    for (int base = 0; base < Nn; base += 1024) {
        int i = base + t;
        int v = (i < Nn) ? cnt[i] : 0;
        lds[t] = v; __syncthreads();
        for (int o = 1; o < 1024; o <<= 1) {
            int x = (t >= o) ? lds[t - o] : 0;
            __syncthreads();
            lds[t] += x;
            __syncthreads();
        }
        int c = carry;
        if (i < Nn) { int ex = c + lds[t] - v; rowptr[i] = ex; cursor[i] = ex; }
        __syncthreads();
        if (t == 1023) carry = c + lds[1023];
        __syncthreads();
    }
    if (t == 0) rowptr[Nn] = carry;
}

// per-graph node counts via LDS histogram: 1 global atomic per (block, graph)
__global__ __launch_bounds__(256) void gcount_k(const int* __restrict__ batch, int* __restrict__ gcnt)
{
    __shared__ int bins[NG];
    int t = threadIdx.x;
    if (t < NG) bins[t] = 0;
    __syncthreads();
    int n = blockIdx.x * 256 + t;
    if (n < Nn) atomicAdd(&bins[batch[n]], 1);
    __syncthreads();
    if (t < NG && bins[t]) atomicAdd(&gcnt[t], bins[t]);
}

// RGAT aggregation from precomputed EW. One wave per dst node, SINGLE pass over edges
// (den and unnormalized acc accumulated together; normalize in epilogue).
// Rows gathered as dwords (2 bf16/lane/chunk, bit-shift convert). Fused elu/residual/stats.
__global__ __launch_bounds__(256) void aggr_k(const u16* __restrict__ xr,
    const float* __restrict__ ew, const int* __restrict__ rowptr, const int* __restrict__ eidx,
    const float* __restrict__ bias, const float* __restrict__ hin,
    const int* __restrict__ batch, float* __restrict__ out,
    float* __restrict__ gsum, float* __restrict__ gsq)
{
    __shared__ float ls[NG], lq[NG];
    int t = threadIdx.x;
    if (t < NG) { ls[t] = 0.f; lq[t] = 0.f; }
    __syncthreads();
    int node = blockIdx.x * 4 + (t >> 6);
    int lane = t & 63;
    int e0 = rowptr[node], e1 = rowptr[node + 1];
    int hd[3];
    #pragma unroll
    for (int j = 0; j < 3; j++) hd[j] = (lane * 2 + 128 * j) / 48;  // c,c+1 same head (c even)
    float den = 0.f;                 // lane h < 8 accumulates head h
    float accx[3] = {}, accy[3] = {};
    for (int e = e0; e < e1; e++) {
        int p = eidx[e];
        int srcn = p & 0xFFFFFF, et = p >> 24;
        float ev = (lane < 8) ? ew[(size_t)e * 8 + lane] : 0.f;
        den += ev;
        const u32* row = (const u32*)(xr + ((size_t)et * Nn + srcn) * FD);
        #pragma unroll
        for (int j = 0; j < 3; j++) {
            float a = __shfl(ev, hd[j]);
            u32 u = row[lane + 64 * j];
            accx[j] = fmaf(a, __uint_as_float(u << 16), accx[j]);
            accy[j] = fmaf(a, __uint_as_float(u & 0xffff0000u), accy[j]);
        }
    }
    float s1 = 0.f, s2 = 0.f;
    #pragma unroll
    for (int j = 0; j < 3; j++) {
        float dh = __shfl(den, hd[j]);
        float rcp = 1.f / (dh + 1e-16f);
        int c = lane * 2 + 128 * j;
        float2 bv = *(const float2*)(bias + c);
        float2 hv = *(const float2*)(hin + (size_t)node * FD + c);
        float vx = accx[j] * rcp + bv.x;
        float vy = accy[j] * rcp + bv.y;
        vx = (vx > 0.f) ? vx : expm1f(vx);
        vy = (vy > 0.f) ? vy : expm1f(vy);
        vx += hv.x; vy += hv.y;
        *(float2*)(out + (size_t)node * FD + c) = make_float2(vx, vy);
        s1 += vx + vy; s2 += vx * vx + vy * vy;
    }
    #pragma unroll
    for (int o = 32; o; o >>= 1) { s1 += __shfl_down(s1, o); s2 += __shfl_down(s2, o); }
    int g = batch[node];   // wave-uniform
    if (lane == 0) { atomicAdd(&ls[g], s1); atomicAdd(&lq[g], s2); }
    __syncthreads();
    if (t < NG && (ls[t] != 0.f || lq[t] != 0.f)) {
        atomicAdd(&gsum[t], ls[t]);
        atomicAdd(&gsq[t], lq[t]);
    }
}

// graph-LN (stats finalized inline from raw sums) + fused bf16 hi/lo split
__global__ __launch_bounds__(256) void gnorm_split_k(float* __restrict__ y,
    const int* __restrict__ batch, const float* __restrict__ gsum, const float* __restrict__ gsq,
    const int* __restrict__ gcnt, const float* __restrict__ w, const float* __restrict__ b,
    u16* __restrict__ hi, u16* __restrict__ lo)
{
    int i = blockIdx.x * 256 + threadIdx.x;   // float4 index
    if (i >= Nn * (FD / 4)) return;
    int n = i / 96, c4 = i - n * 96;
    int g = batch[n];
    float norm = fmaxf((float)gcnt[g], 1.f) * (float)FD;
    float m = gsum[g] / norm;
    float var = gsq[g] / norm - m * m;
    float rstd = rsqrtf(var + EPS);
    float4 wv = ((const float4*)w)[c4];
    float4 bv = ((const float4*)b)[c4];
    float4 v = ((const float4*)y)[i];
    v.x = (v.x - m) * rstd * wv.x + bv.x;
    v.y = (v.y - m) * rstd * wv.y + bv.y;
    v.z = (v.z - m) * rstd * wv.z + bv.z;
    v.w = (v.w - m) * rstd * wv.w + bv.w;
    ((float4*)y)[i] = v;
    ushort4 hh, ll;
    hh.x = f2b(v.x); ll.x = f2b(v.x - b2f(hh.x));
    hh.y = f2b(v.y); ll.y = f2b(v.y - b2f(hh.y));
    hh.z = f2b(v.z); ll.z = f2b(v.z - b2f(hh.z));
    hh.w = f2b(v.w); ll.w = f2b(v.w - b2f(hh.w));
    ((ushort4*)hi)[i] = hh;
    ((ushort4*)lo)[i] = ll;
}

__global__ void softmax_prior_k(const float* __restrict__ logits, float* __restrict__ prior)
{
    int n = blockIdx.x * 8 + (threadIdx.x >> 5);
    int l = threadIdx.x & 31;
    if (n >= Nn) return;
    float v = logits[n * 32 + l];
    float m = v;
    #pragma unroll
    for (int o = 16; o; o >>= 1) m = fmaxf(m, __shfl_xor(m, o, 32));
    float e = __expf(v - m);
    float s = e;
    #pragma unroll
    for (int o = 16; o; o >>= 1) s += __shfl_xor(s, o, 32);
    prior[(size_t)n * 33 + l] = e / s;
    if (l == 0) prior[(size_t)n * 33 + 32] = 1.f / s;
}

extern "C" void kernel_launch(void* const* d_in, const int* in_sizes, int n_in,
                              void* d_out, int out_size, void* d_ws, size_t ws_size,
                              hipStream_t stream)
{
    const float* x_visual = (const float*)d_in[0];
    const float* x_geom   = (const float*)d_in[1];
    const float* x_prior  = (const float*)d_in[2];
    const int* ei0   = (const int*)d_in[3];
    const int* ei1   = (const int*)d_in[4];
    const int* ei2   = (const int*)d_in[5];
    const int* batch = (const int*)d_in[6];
    const float* vis_W = (const float*)d_in[7];  const float* vis_b = (const float*)d_in[8];
    const float* vis_lnw = (const float*)d_in[9]; const float* vis_lnb = (const float*)d_in[10];
    const float* geo_W = (const float*)d_in[11]; const float* geo_b = (const float*)d_in[12];
    const float* geo_lnw = (const float*)d_in[13]; const float* geo_lnb = (const float*)d_in[14];
    const float* pri_W = (const float*)d_in[15]; const float* pri_b = (const float*)d_in[16];
    const float* pri_lnw = (const float*)d_in[17]; const float* pri_lnb = (const float*)d_in[18];
    const float* rgat_W[2]    = { (const float*)d_in[19], (const float*)d_in[25] };
    const float* rgat_q[2]    = { (const float*)d_in[20], (const float*)d_in[26] };
    const float* rgat_kk[2]   = { (const float*)d_in[21], (const float*)d_in[27] };
    const float* rgat_bias[2] = { (const float*)d_in[22], (const float*)d_in[28] };
    const float* ln_w[2]      = { (const float*)d_in[23], (const float*)d_in[29] };
    const float* ln_b[2]      = { (const float*)d_in[24], (const float*)d_in[30] };
    const float* cls_W1 = (const float*)d_in[31]; const float* cls_b1 = (const float*)d_in[32];
    const float* cls_W2 = (const float*)d_in[33]; const float* cls_b2 = (const float*)d_in[34];
    float* OUT = (float*)d_out;

    // ---------------- workspace layout ----------------
    float* ws = (float*)d_ws;
    float* XRreg = ws;                         // 3*Nn*FD floats reserved (92.2 MB region)
    u16*   XR16  = (u16*)XRreg;                // XR stored bf16: first 46 MB of the region
    float* HCAT  = XRreg + (size_t)3 * Nn * FD;
    float* HA    = HCAT + (size_t)Nn * FD;
    float* HB    = HA + (size_t)Nn * FD;
    float* PRIOR = HB + (size_t)Nn * FD;       // Nn*33
    float* QIK   = PRIOR + (size_t)Nn * 33;    // 3*Nn*16 (q heads 0-7, k heads 8-15)
    u16* HS0_HI  = (u16*)(QIK + (size_t)3 * Nn * 16);  // HCAT split
    u16* HS0_LO  = HS0_HI + (size_t)Nn * FD;
    u16* HS1_HI  = HS0_LO + (size_t)Nn * FD;          // HA split
    u16* HS1_LO  = HS1_HI + (size_t)Nn * FD;
    u16* RW_HI   = HS1_LO + (size_t)Nn * FD;   // 2*3*384*384
    u16* RW_LO   = RW_HI + (size_t)2 * 3 * 384 * 384;
    u16* VW_HI   = RW_LO + (size_t)2 * 3 * 384 * 384; // 128*1024
    u16* VW_LO   = VW_HI + (size_t)128 * 1024;
    u16* CW_HI   = VW_LO + (size_t)128 * 1024;        // 128*384
    u16* CW_LO   = CW_HI + (size_t)128 * 384;
    u16* QKW_HI  = CW_LO + (size_t)128 * 384;         // 2 layers * 16*384
    u16* QKW_LO  = QKW_HI + (size_t)2 * 16 * 384;
    float* STATS = (float*)(QKW_LO + (size_t)2 * 16 * 384); // 2
    float* GSUM  = STATS + 2;                  // 64
    float* GSQ   = GSUM + 64;
    int* CNT    = (int*)(GSQ + 64);
    int* ROWPTR = CNT + Nn;
    int* CURSOR = ROWPTR + Nn + 1;
    int* EIDX   = CURSOR + Nn;
    int* GCNT   = EIDX + ETOT;
    int* DSTE   = GCNT + 64;                   // ETOT
    float* EW   = (float*)(DSTE + ETOT);       // ETOT*8 floats (5.76 MB)
    // aliases into the XR region (temporally dead sub-ranges):
    u16* VA_HI = (u16*)XRreg;                  // x_visual split [0,82MB): dead after vis gemm
    u16* VA_LO = VA_HI + (size_t)Nn * 1024;
    float* CLSH = XRreg;                       // classifier hidden [0,10.3MB): after last aggr
    u16* HS2_HI = (u16*)(XRreg + (size_t)12 * 1000 * 1000); // HB split [48MB,78.7MB): after last aggr
    u16* HS2_LO = HS2_HI + (size_t)Nn * FD;

    // ---------------- CSR build (reused by all 4 RGAT calls) ----------------
    hipMemsetAsync(CNT, 0, Nn * sizeof(int), stream);
    edge_count_k<<<cdiv(ETOT, 256), 256, 0, stream>>>(ei0, ei1, ei2, CNT);
    scan_k<<<1, 1024, 0, stream>>>(CNT, ROWPTR, CURSOR);
    edge_fill_k<<<cdiv(ETOT, 256), 256, 0, stream>>>(ei0, ei1, ei2, CURSOR, EIDX, DSTE);
    hipMemsetAsync(GCNT, 0, 64 * sizeof(int), stream);
    gcount_k<<<cdiv(Nn, 256), 256, 0, stream>>>(batch, GCNT);

    // ---------------- weight + x_visual conversions ----------------
    tsplit_k<<<cdiv(3 * 384 * 384, 256), 256, 0, stream>>>(rgat_W[0], RW_HI, RW_LO, 384, 384, 3 * 384 * 384);
    tsplit_k<<<cdiv(3 * 384 * 384, 256), 256, 0, stream>>>(rgat_W[1], RW_HI + 3 * 384 * 384, RW_LO + 3 * 384 * 384, 384, 384, 3 * 384 * 384);
    tsplit_k<<<cdiv(1024 * 128, 256), 256, 0, stream>>>(vis_W, VW_HI, VW_LO, 1024, 128, 1024 * 128);
    tsplit_k<<<cdiv(384 * 128, 256), 256, 0, stream>>>(cls_W1, CW_HI, CW_LO, 384, 128, 384 * 128);
    prep_qkw_k<<<cdiv(16 * 384, 256), 256, 0, stream>>>(rgat_q[0], rgat_kk[0], QKW_HI, QKW_LO);
    prep_qkw_k<<<cdiv(16 * 384, 256), 256, 0, stream>>>(rgat_q[1], rgat_kk[1], QKW_HI + 16 * 384, QKW_LO + 16 * 384);
    split_k<<<cdiv(Nn * 1024 / 4, 256), 256, 0, stream>>>(x_visual, VA_HI, VA_LO, Nn * 1024 / 4);

    const int MB = cdiv(Nn, 128);   // 157

    // ---------------- vis encoder (MFMA) -> HCAT[:,0:128) ----------------
    hipMemsetAsync(STATS, 0, 2 * sizeof(float), stream);
    mgemm_k<true, true, true, false, 3><<<dim3(MB, 1, 1), 256, 0, stream>>>(
        VA_HI, VA_LO, VW_HI, VW_LO, vis_b, HCAT, Nn, 1024, FD, 0, STATS);
    enc_norm_k<<<cdiv(Nn * 32, 256), 256, 0, stream>>>(HCAT, vis_lnw, vis_lnb, STATS, 1.f / ((float)Nn * 128.f), HS0_HI, HS0_LO);

    // ---------------- geo encoder (fp32, K=6) -> HCAT[:,128:256) ----------------
    dim3 genc(cdiv(Nn, 64), 2, 1);
    hipMemsetAsync(STATS, 0, 2 * sizeof(float), stream);
    sgemm_k<true, true, true><<<genc, 256, 0, stream>>>(x_geom, geo_W, geo_b, HCAT + 128, Nn, 6, 128, FD, STATS);
    enc_norm_k<<<cdiv(Nn * 32, 256), 256, 0, stream>>>(HCAT + 128, geo_lnw, geo_lnb, STATS, 1.f / ((float)Nn * 128.f), HS0_HI + 128, HS0_LO + 128);

    for (int t = 0; t < 2; t++) {
        // prior encoder (fp32, K=33) -> HCAT[:,256:384)
        const float* pin = t ? PRIOR : x_prior;
        hipMemsetAsync(STATS, 0, 2 * sizeof(float), stream);
        sgemm_k<true, true, true><<<genc, 256, 0, stream>>>(pin, pri_W, pri_b, HCAT + 256, Nn, 33, 128, FD, STATS);
        enc_norm_k<<<cdiv(Nn * 32, 256), 256, 0, stream>>>(HCAT + 256, pri_lnw, pri_lnb, STATS, 1.f / ((float)Nn * 128.f), HS0_HI + 256, HS0_LO + 256);

        float* hin = HCAT;
        for (int L = 0; L < 2; L++) {
            float* hout = L ? HB : HA;
            const u16* ahi = L ? HS1_HI : HS0_HI;
            const u16* alo = L ? HS1_LO : HS0_LO;
            u16* shi = L ? HS2_HI : HS1_HI;
            u16* slo = L ? HS2_LO : HS1_LO;
            mgemm_k<false, false, false, true, 2><<<dim3(MB, 3, 3), 256, 0, stream>>>(
                ahi, alo, RW_HI + (size_t)L * 3 * 384 * 384, RW_LO + (size_t)L * 3 * 384 * 384,
                nullptr, XR16, Nn, 384, FD, 384 * 384, nullptr);
            proj_k<<<cdiv(3 * Nn, 128), 256, 0, stream>>>(XR16,
                QKW_HI + (size_t)L * 16 * 384, QKW_LO + (size_t)L * 16 * 384, QIK);
            ew_k<<<cdiv(ETOT, 256), 256, 0, stream>>>(QIK, EIDX, DSTE, EW);
            hipMemsetAsync(GSUM, 0, 128 * sizeof(float), stream);  // GSUM+GSQ contiguous
            aggr_k<<<cdiv(Nn, 4), 256, 0, stream>>>(XR16, EW, ROWPTR, EIDX, rgat_bias[L],
                                                    hin, batch, hout, GSUM, GSQ);
            gnorm_split_k<<<cdiv(Nn * 96, 256), 256, 0, stream>>>(hout, batch, GSUM, GSQ, GCNT, ln_w[L], ln_b[L], shi, slo);
            hin = hout;
        }

        // classifier: cls1 (MFMA, reads HS2 split) -> CLSH, cls2 (fp32) -> OUT
        mgemm_k<true, true, false, false, 3><<<dim3(MB, 1, 1), 256, 0, stream>>>(
            HS2_HI, HS2_LO, CW_HI, CW_LO, cls_b1, CLSH, Nn, 384, 128, 0, nullptr);
        sgemm_k<true, false, false><<<dim3(cdiv(Nn, 64), 1, 1), 256, 0, stream>>>(
            CLSH, cls_W2, cls_b2, OUT, Nn, 128, 32, 32, nullptr);

        if (t == 0)
            softmax_prior_k<<<cdiv(Nn, 8), 256, 0, stream>>>(OUT, PRIOR);
    }
}

// Round 9
// 920.064 us; speedup vs baseline: 1.5385x; 1.0728x over previous
//
#include <hip/hip_runtime.h>
#include <hip/hip_bf16.h>

#define Nn 20000
#define EREL 60000
#define ETOT 180000
#define NG 64
#define FD 384
#define EPS 1e-5f

typedef unsigned short u16;
typedef unsigned int u32;
typedef __attribute__((ext_vector_type(8))) short s8v;     // 8 bf16 (4 VGPR) MFMA A/B frag
typedef __attribute__((ext_vector_type(4))) float f4v;     // MFMA C/D frag

static inline int cdiv(int a, int b) { return (a + b - 1) / b; }

__device__ inline u16 f2b(float f) {
    __hip_bfloat16 h = __float2bfloat16(f);
    union { __hip_bfloat16 b; u16 u; } c; c.b = h; return c.u;
}
__device__ inline float b2f(u16 u) {
    union { __hip_bfloat16 b; u16 u; } c; c.u = u; return __bfloat162float(c.b);
}

// ---------------- split fp32 -> bf16 hi/lo (vectorized by float4) ----------------
__global__ __launch_bounds__(256) void split_k(const float* __restrict__ x,
    u16* __restrict__ hi, u16* __restrict__ lo, int n4)
{
    int i = blockIdx.x * 256 + threadIdx.x;
    if (i >= n4) return;
    float4 v = ((const float4*)x)[i];
    ushort4 h, l;
    h.x = f2b(v.x); l.x = f2b(v.x - b2f(h.x));
    h.y = f2b(v.y); l.y = f2b(v.y - b2f(h.y));
    h.z = f2b(v.z); l.z = f2b(v.z - b2f(h.z));
    h.w = f2b(v.w); l.w = f2b(v.w - b2f(h.w));
    ((ushort4*)hi)[i] = h;
    ((ushort4*)lo)[i] = l;
}

// transpose + split: W[b][K][N] -> T[b][N][K] hi/lo
__global__ void tsplit_k(const float* __restrict__ W, u16* __restrict__ hi,
                         u16* __restrict__ lo, int K, int N, int total)
{
    int idx = blockIdx.x * 256 + threadIdx.x;
    if (idx >= total) return;
    int kn = K * N;
    int b = idx / kn, rem = idx - b * kn;
    int k = rem / N, n = rem - k * N;
    float v = W[idx];
    u16 h = f2b(v), l = f2b(v - b2f(h));
    int o = b * kn + n * K + k;
    hi[o] = h; lo[o] = l;
}

// pack q (384x8) and k (384x8) into QKW[16][384] hi/lo: col<8 = q head, col>=8 = k head
__global__ void prep_qkw_k(const float* __restrict__ q, const float* __restrict__ kk,
                           u16* __restrict__ hi, u16* __restrict__ lo)
{
    int idx = blockIdx.x * 256 + threadIdx.x;
    if (idx >= 16 * 384) return;
    int col = idx / 384, k = idx - col * 384;
    float v = (col < 8) ? q[k * 8 + col] : kk[k * 8 + col - 8];
    u16 h = f2b(v), l = f2b(v - b2f(h));
    hi[idx] = h; lo[idx] = l;
}

// ---------------- split-bf16 MFMA GEMM ----------------
// C[M,N] = A[M,K] @ B[N,K]^T, A,B bf16 (hi,lo) pairs row-major ld=K. 128x128 tile,
// 4 waves of 64x64, 16x16x32 MFMA. TERMS=3: hi*bh + lo*bh + hi*bl (~fp32).
// TERMS=2: hi*bh + lo*bh (B-lo never read) — for outputs rounded to bf16 anyway.
// SWZ: XCD-aware linear grid for the 9-(col,rel) XR shape — blocks sharing an A
// row-strip get dispatch indices congruent mod 8 -> same XCD L2 -> A fetched once.
template<bool BIAS, bool RELU, bool STATS, bool OB16, int TERMS, bool SWZ>
__global__ __launch_bounds__(256) void mgemm_k(
    const u16* __restrict__ Ahi, const u16* __restrict__ Alo,
    const u16* __restrict__ Bhi, const u16* __restrict__ Blo,
    const float* __restrict__ bias, void* __restrict__ Cv,
    int M, int K, int ldc, int bstride, float* __restrict__ stats)
{
    __shared__ u16 lds[4 * 128 * 32];   // Ahi | Alo | Bhi | (Blo) tiles, [128][32] each
    __shared__ float red[256];
    const int t = threadIdx.x;
    int brow, bcol, z;
    if (SWZ) {
        // linear grid of 160*9 blocks; row = xcd + 8*(s/9), (col,rel) = s%9
        int d = blockIdx.x;
        int xcd = d & 7, s = d >> 3;
        int row = xcd + 8 * (s / 9);
        int c = s % 9;
        brow = row * 128;
        if (brow >= M) return;
        bcol = (c % 3) * 128;
        z = c / 3;
    } else {
        brow = blockIdx.x * 128; bcol = blockIdx.y * 128; z = blockIdx.z;
    }
    Bhi += (size_t)z * bstride;
    Blo += (size_t)z * bstride;
    float* Cf = OB16 ? nullptr : (float*)Cv + (size_t)z * M * ldc;
    u16*   Ch = OB16 ? (u16*)Cv + (size_t)z * M * ldc : nullptr;

    const int NSRC = (TERMS == 3) ? 8 : 6;
    const int r0 = t >> 2, sl = t & 3;
    const int rA0 = min(brow + r0, M - 1);
    const int rA1 = min(brow + r0 + 64, M - 1);
    const u16* gsrc[8];
    gsrc[0] = Ahi + (size_t)rA0 * K + sl * 8;
    gsrc[1] = Ahi + (size_t)rA1 * K + sl * 8;
    gsrc[2] = Alo + (size_t)rA0 * K + sl * 8;
    gsrc[3] = Alo + (size_t)rA1 * K + sl * 8;
    gsrc[4] = Bhi + (size_t)(bcol + r0) * K + sl * 8;
    gsrc[5] = Bhi + (size_t)(bcol + r0 + 64) * K + sl * 8;
    gsrc[6] = Blo + (size_t)(bcol + r0) * K + sl * 8;
    gsrc[7] = Blo + (size_t)(bcol + r0 + 64) * K + sl * 8;
    const int swz = (sl ^ (r0 & 3)) << 3;
    int ldst[8];
    #pragma unroll
    for (int i = 0; i < 8; i++) {
        int tile = i >> 1, row = r0 + 64 * (i & 1);
        ldst[i] = tile * 4096 + row * 32 + swz;
    }

    const int l = t & 63, w = t >> 6;
    const int wr = (w >> 1) * 64, wc = (w & 1) * 64;
    const int lr = l & 15, kq = l >> 4;

    f4v acc[4][4] = {};
    const int NK = K >> 5;

    s8v stg[8];
    #pragma unroll
    for (int i = 0; i < 8; i++) if (i < NSRC) stg[i] = *(const s8v*)gsrc[i];

    for (int kc = 0; kc < NK; kc++) {
        if (kc) __syncthreads();
        #pragma unroll
        for (int i = 0; i < 8; i++) if (i < NSRC) *(s8v*)(lds + ldst[i]) = stg[i];
        __syncthreads();
        if (kc + 1 < NK) {
            const int ko = (kc + 1) * 32;
            #pragma unroll
            for (int i = 0; i < 8; i++) if (i < NSRC) stg[i] = *(const s8v*)(gsrc[i] + ko);
        }
        #define LDR(T, row) (*(const s8v*)(lds + (T) * 4096 + (row) * 32 + ((kq ^ ((row) & 3)) << 3)))
        s8v bh[4], bl[4];
        #pragma unroll
        for (int tn = 0; tn < 4; tn++) {
            int rb = wc + tn * 16 + lr;
            bh[tn] = LDR(2, rb);
            if (TERMS == 3) bl[tn] = LDR(3, rb);
        }
        #pragma unroll
        for (int tm = 0; tm < 4; tm++) {
            int ra = wr + tm * 16 + lr;
            s8v ah = LDR(0, ra);
            s8v al = LDR(1, ra);
            #pragma unroll
            for (int tn = 0; tn < 4; tn++) {
                acc[tm][tn] = __builtin_amdgcn_mfma_f32_16x16x32_bf16(ah, bh[tn], acc[tm][tn], 0, 0, 0);
                acc[tm][tn] = __builtin_amdgcn_mfma_f32_16x16x32_bf16(al, bh[tn], acc[tm][tn], 0, 0, 0);
                if (TERMS == 3)
                    acc[tm][tn] = __builtin_amdgcn_mfma_f32_16x16x32_bf16(ah, bl[tn], acc[tm][tn], 0, 0, 0);
            }
        }
        #undef LDR
    }

    float s1 = 0.f, s2 = 0.f;
    #pragma unroll
    for (int tm = 0; tm < 4; tm++) {
        #pragma unroll
        for (int rg = 0; rg < 4; rg++) {
            int row = brow + wr + tm * 16 + kq * 4 + rg;
            if (row < M) {
                #pragma unroll
                for (int tn = 0; tn < 4; tn++) {
                    int col = bcol + wc + tn * 16 + lr;
                    float v = acc[tm][tn][rg];
                    if (BIAS) v += bias[col];
                    if (RELU) v = fmaxf(v, 0.f);
                    if (OB16) Ch[(size_t)row * ldc + col] = f2b(v);
                    else      Cf[(size_t)row * ldc + col] = v;
                    if (STATS) { s1 += v; s2 += v * v; }
                }
            }
        }
    }
    if (STATS) {
        __syncthreads();
        red[t] = s1; __syncthreads();
        for (int o = 128; o; o >>= 1) { if (t < o) red[t] += red[t + o]; __syncthreads(); }
        if (t == 0) atomicAdd(&stats[0], red[0]);
        __syncthreads();
        red[t] = s2; __syncthreads();
        for (int o = 128; o; o >>= 1) { if (t < o) red[t] += red[t + o]; __syncthreads(); }
        if (t == 0) atomicAdd(&stats[1], red[0]);
    }
}

// ---------------- proj GEMM: QIK[3Nn,16] = XR[3Nn,384] @ QKW[16,384]^T ----------------
__global__ __launch_bounds__(256) void proj_k(const u16* __restrict__ xr,
    const u16* __restrict__ qkw_hi, const u16* __restrict__ qkw_lo,
    float* __restrict__ qik)
{
    const int M3 = 3 * Nn;
    __shared__ u16 a_lds[128 * 32];
    __shared__ u16 b_lds[2][16 * 392];
    int t = threadIdx.x;
    int brow = blockIdx.x * 128;

    for (int i = t; i < 768; i += 256) {
        int col = i / 48, c8 = (i - col * 48) * 8;
        *(s8v*)&b_lds[0][col * 392 + c8] = *(const s8v*)(qkw_hi + col * 384 + c8);
        *(s8v*)&b_lds[1][col * 392 + c8] = *(const s8v*)(qkw_lo + col * 384 + c8);
    }

    int ar = t >> 1;
    int sl0 = (t & 1) * 2;
    int grow = min(brow + ar, M3 - 1);
    const u16* asrc = xr + (size_t)grow * 384;
    int adst0 = ar * 32 + ((sl0 ^ (ar & 3)) << 3);
    int adst1 = ar * 32 + (((sl0 + 1) ^ (ar & 3)) << 3);

    int l = t & 63, w = t >> 6;
    int lr = l & 15, kq = l >> 4;
    f4v acc0 = {}, acc1 = {};

    s8v stg0 = *(const s8v*)(asrc + sl0 * 8);
    s8v stg1 = *(const s8v*)(asrc + sl0 * 8 + 8);
    for (int kc = 0; kc < 12; kc++) {
        if (kc) __syncthreads();
        *(s8v*)&a_lds[adst0] = stg0;
        *(s8v*)&a_lds[adst1] = stg1;
        __syncthreads();
        if (kc + 1 < 12) {
            int ko = (kc + 1) * 32 + sl0 * 8;
            stg0 = *(const s8v*)(asrc + ko);
            stg1 = *(const s8v*)(asrc + ko + 8);
        }
        s8v bh = *(const s8v*)&b_lds[0][lr * 392 + kc * 32 + kq * 8];
        s8v bl = *(const s8v*)&b_lds[1][lr * 392 + kc * 32 + kq * 8];
        int r0 = w * 32 + lr;
        s8v a0 = *(const s8v*)&a_lds[r0 * 32 + ((kq ^ (r0 & 3)) << 3)];
        int r1 = r0 + 16;
        s8v a1 = *(const s8v*)&a_lds[r1 * 32 + ((kq ^ (r1 & 3)) << 3)];
        acc0 = __builtin_amdgcn_mfma_f32_16x16x32_bf16(a0, bh, acc0, 0, 0, 0);
        acc0 = __builtin_amdgcn_mfma_f32_16x16x32_bf16(a0, bl, acc0, 0, 0, 0);
        acc1 = __builtin_amdgcn_mfma_f32_16x16x32_bf16(a1, bh, acc1, 0, 0, 0);
        acc1 = __builtin_amdgcn_mfma_f32_16x16x32_bf16(a1, bl, acc1, 0, 0, 0);
    }
    #pragma unroll
    for (int rg = 0; rg < 4; rg++) {
        int row0 = brow + w * 32 + kq * 4 + rg;
        if (row0 < M3) qik[(size_t)row0 * 16 + lr] = acc0[rg];
        int row1 = row0 + 16;
        if (row1 < M3) qik[(size_t)row1 * 16 + lr] = acc1[rg];
    }
}

// ---------------- fp32 tiled GEMM (tiny-K shapes: geo K=6, pri K=33, cls2) ----------------
template<bool BIAS, bool RELU, bool STATS>
__global__ __launch_bounds__(256) void sgemm_k(
    const float* __restrict__ A, const float* __restrict__ B,
    const float* __restrict__ bias, float* __restrict__ C,
    int M, int K, int N, int ldc, float* __restrict__ stats)
{
    const int BK = 16;
    const int r = blockIdx.z;
    B += (size_t)r * K * N;
    C += (size_t)r * M * ldc;
    __shared__ float As[16][65];
    __shared__ float Bs[16][64];
    int tid = threadIdx.x;
    int tx = tid & 15, ty = tid >> 4;
    int brow = blockIdx.x * 64, bcol = blockIdx.y * 64;
    float acc[4][4] = {};
    for (int k0 = 0; k0 < K; k0 += BK) {
        #pragma unroll
        for (int i = 0; i < 4; i++) {
            int e = tid + 256 * i;
            int ar = e >> 4, ak = e & 15;
            int gr = brow + ar, gk = k0 + ak;
            As[ak][ar] = (gr < M && gk < K) ? A[(size_t)gr * K + gk] : 0.f;
            int bk = e >> 6, bn = e & 63;
            int gbk = k0 + bk, gbn = bcol + bn;
            Bs[bk][bn] = (gbk < K && gbn < N) ? B[(size_t)gbk * N + gbn] : 0.f;
        }
        __syncthreads();
        #pragma unroll
        for (int k = 0; k < BK; k++) {
            float ra[4], rb[4];
            #pragma unroll
            for (int i = 0; i < 4; i++) ra[i] = As[k][ty * 4 + i];
            #pragma unroll
            for (int j = 0; j < 4; j++) rb[j] = Bs[k][tx * 4 + j];
            #pragma unroll
            for (int i = 0; i < 4; i++)
                #pragma unroll
                for (int j = 0; j < 4; j++)
                    acc[i][j] = fmaf(ra[i], rb[j], acc[i][j]);
        }
        __syncthreads();
    }
    float s1 = 0.f, s2 = 0.f;
    #pragma unroll
    for (int i = 0; i < 4; i++) {
        int row = brow + ty * 4 + i;
        #pragma unroll
        for (int j = 0; j < 4; j++) {
            int col = bcol + tx * 4 + j;
            if (row < M && col < N) {
                float v = acc[i][j];
                if (BIAS) v += bias[col];
                if (RELU) v = v > 0.f ? v : 0.f;
                C[(size_t)row * ldc + col] = v;
                if (STATS) { s1 += v; s2 += v * v; }
            }
        }
    }
    if (STATS) {
        __shared__ float red[256];
        __syncthreads();
        red[tid] = s1; __syncthreads();
        for (int o = 128; o; o >>= 1) { if (tid < o) red[tid] += red[tid + o]; __syncthreads(); }
        if (tid == 0) atomicAdd(&stats[0], red[0]);
        __syncthreads();
        red[tid] = s2; __syncthreads();
        for (int o = 128; o; o >>= 1) { if (tid < o) red[tid] += red[tid + o]; __syncthreads(); }
        if (tid == 0) atomicAdd(&stats[1], red[0]);
    }
}

// scalar-LN of a 128-col block of H (pre-offset) from RAW sums, fused bf16 hi/lo split.
__global__ __launch_bounds__(256) void enc_norm_k(float* __restrict__ H, const float* __restrict__ w,
                           const float* __restrict__ b, const float* __restrict__ stats,
                           float cntinv, u16* __restrict__ hi, u16* __restrict__ lo)
{
    int i = blockIdx.x * 256 + threadIdx.x;   // float4 index within the 128-col block
    if (i >= Nn * 32) return;
    int n = i >> 5, c4 = i & 31;
    float m = stats[0] * cntinv;
    float var = stats[1] * cntinv - m * m;
    float s = 1.f / (sqrtf(fmaxf(var, 0.f)) + EPS);
    float4 wv = ((const float4*)w)[c4];
    float4 bv = ((const float4*)b)[c4];
    float4* p = (float4*)(H + (size_t)n * FD) + c4;
    float4 v = *p;
    v.x = (v.x - m) * s * wv.x + bv.x;
    v.y = (v.y - m) * s * wv.y + bv.y;
    v.z = (v.z - m) * s * wv.z + bv.z;
    v.w = (v.w - m) * s * wv.w + bv.w;
    *p = v;
    ushort4 hh, ll;
    hh.x = f2b(v.x); ll.x = f2b(v.x - b2f(hh.x));
    hh.y = f2b(v.y); ll.y = f2b(v.y - b2f(hh.y));
    hh.z = f2b(v.z); ll.z = f2b(v.z - b2f(hh.z));
    hh.w = f2b(v.w); ll.w = f2b(v.w - b2f(hh.w));
    ((ushort4*)(hi + (size_t)n * FD))[c4] = hh;
    ((ushort4*)(lo + (size_t)n * FD))[c4] = ll;
}

// per-edge unnormalized attention weights from fused QIK[row][16] (q: 0-7, k: 8-15)
__global__ __launch_bounds__(256) void ew_k(const float* __restrict__ qik,
    const int* __restrict__ eidx, const int* __restrict__ dste, float* __restrict__ ew)
{
    int e = blockIdx.x * 256 + threadIdx.x;
    if (e >= ETOT) return;
    int p = eidx[e];
    int src = p & 0xFFFFFF, et = p >> 24;
    int dst = dste[e];
    const float4* q4 = (const float4*)(qik + ((size_t)et * Nn + dst) * 16);
    const float4* k4 = (const float4*)(qik + ((size_t)et * Nn + src) * 16 + 8);
    float4 out[2];
    #pragma unroll
    for (int half = 0; half < 2; half++) {
        float4 qv = q4[half], kv = k4[half];
        float a0 = qv.x + kv.x, a1 = qv.y + kv.y, a2 = qv.z + kv.z, a3 = qv.w + kv.w;
        a0 = (a0 > 0.f) ? a0 : 0.2f * a0;
        a1 = (a1 > 0.f) ? a1 : 0.2f * a1;
        a2 = (a2 > 0.f) ? a2 : 0.2f * a2;
        a3 = (a3 > 0.f) ? a3 : 0.2f * a3;
        out[half] = make_float4(__expf(a0), __expf(a1), __expf(a2), __expf(a3));
    }
    float4* ew4 = (float4*)(ew + (size_t)e * 8);
    ew4[0] = out[0];
    ew4[1] = out[1];
}

__global__ void edge_count_k(const int* __restrict__ e0, const int* __restrict__ e1,
                             const int* __restrict__ e2, int* __restrict__ cnt)
{
    int e = blockIdx.x * 256 + threadIdx.x;
    if (e >= ETOT) return;
    int r = e / EREL, i = e - r * EREL;
    const int* ei = (r == 0) ? e0 : (r == 1) ? e1 : e2;
    atomicAdd(&cnt[ei[EREL + i]], 1);
}

__global__ void edge_fill_k(const int* __restrict__ e0, const int* __restrict__ e1,
                            const int* __restrict__ e2, int* __restrict__ cursor,
                            int* __restrict__ eidx, int* __restrict__ dste)
{
    int e = blockIdx.x * 256 + threadIdx.x;
    if (e >= ETOT) return;
    int r = e / EREL, i = e - r * EREL;
    const int* ei = (r == 0) ? e0 : (r == 1) ? e1 : e2;
    int src = ei[i], dst = ei[EREL + i];
    int pos = atomicAdd(&cursor[dst], 1);
    eidx[pos] = src | (r << 24);
    dste[pos] = dst;
}

__global__ __launch_bounds__(1024) void scan_k(const int* __restrict__ cnt,
                                               int* __restrict__ rowptr, int* __restrict__ cursor)
{
    __shared__ int lds[1024];
    __shared__ int carry;
    int t = threadIdx.x;
    if (t == 0) carry = 0;
    __syncthreads();
    for (int base = 0; base < Nn; base += 1024) {
        int i = base + t;
        int v = (i < Nn) ? cnt[i] : 0;
        lds[t] = v; __syncthreads();
        for (int o = 1; o < 1024; o <<= 1) {
            int x = (t >= o) ? lds[t - o] : 0;
            __syncthreads();
            lds[t] += x;
            __syncthreads();
        }
        int c = carry;
        if (i < Nn) { int ex = c + lds[t] - v; rowptr[i] = ex; cursor[i] = ex; }
        __syncthreads();
        if (t == 1023) carry = c + lds[1023];
        __syncthreads();
    }
    if (t == 0) rowptr[Nn] = carry;
}

// per-graph node counts via LDS histogram: 1 global atomic per (block, graph)
__global__ __launch_bounds__(256) void gcount_k(const int* __restrict__ batch, int* __restrict__ gcnt)
{
    __shared__ int bins[NG];
    int t = threadIdx.x;
    if (t < NG) bins[t] = 0;
    __syncthreads();
    int n = blockIdx.x * 256 + t;
    if (n < Nn) atomicAdd(&bins[batch[n]], 1);
    __syncthreads();
    if (t < NG && bins[t]) atomicAdd(&gcnt[t], bins[t]);
}

// RGAT aggregation from precomputed EW. One wave per dst node, SINGLE pass over edges.
// Rows gathered as dwords (2 bf16/lane/chunk, bit-shift convert). Fused elu/residual/stats.
__global__ __launch_bounds__(256) void aggr_k(const u16* __restrict__ xr,
    const float* __restrict__ ew, const int* __restrict__ rowptr, const int* __restrict__ eidx,
    const float* __restrict__ bias, const float* __restrict__ hin,
    const int* __restrict__ batch, float* __restrict__ out,
    float* __restrict__ gsum, float* __restrict__ gsq)
{
    __shared__ float ls[NG], lq[NG];
    int t = threadIdx.x;
    if (t < NG) { ls[t] = 0.f; lq[t] = 0.f; }
    __syncthreads();
    int node = blockIdx.x * 4 + (t >> 6);
    int lane = t & 63;
    int e0 = rowptr[node], e1 = rowptr[node + 1];
    int hd[3];
    #pragma unroll
    for (int j = 0; j < 3; j++) hd[j] = (lane * 2 + 128 * j) / 48;  // c,c+1 same head (c even)
    float den = 0.f;                 // lane h < 8 accumulates head h
    float accx[3] = {}, accy[3] = {};
    for (int e = e0; e < e1; e++) {
        int p = eidx[e];
        int srcn = p & 0xFFFFFF, et = p >> 24;
        float ev = (lane < 8) ? ew[(size_t)e * 8 + lane] : 0.f;
        den += ev;
        const u32* row = (const u32*)(xr + ((size_t)et * Nn + srcn) * FD);
        #pragma unroll
        for (int j = 0; j < 3; j++) {
            float a = __shfl(ev, hd[j]);
            u32 u = row[lane + 64 * j];
            accx[j] = fmaf(a, __uint_as_float(u << 16), accx[j]);
            accy[j] = fmaf(a, __uint_as_float(u & 0xffff0000u), accy[j]);
        }
    }
    float s1 = 0.f, s2 = 0.f;
    #pragma unroll
    for (int j = 0; j < 3; j++) {
        float dh = __shfl(den, hd[j]);
        float rcp = 1.f / (dh + 1e-16f);
        int c = lane * 2 + 128 * j;
        float2 bv = *(const float2*)(bias + c);
        float2 hv = *(const float2*)(hin + (size_t)node * FD + c);
        float vx = accx[j] * rcp + bv.x;
        float vy = accy[j] * rcp + bv.y;
        vx = (vx > 0.f) ? vx : expm1f(vx);
        vy = (vy > 0.f) ? vy : expm1f(vy);
        vx += hv.x; vy += hv.y;
        *(float2*)(out + (size_t)node * FD + c) = make_float2(vx, vy);
        s1 += vx + vy; s2 += vx * vx + vy * vy;
    }
    #pragma unroll
    for (int o = 32; o; o >>= 1) { s1 += __shfl_down(s1, o); s2 += __shfl_down(s2, o); }
    int g = batch[node];   // wave-uniform
    if (lane == 0) { atomicAdd(&ls[g], s1); atomicAdd(&lq[g], s2); }
    __syncthreads();
    if (t < NG && (ls[t] != 0.f || lq[t] != 0.f)) {
        atomicAdd(&gsum[t], ls[t]);
        atomicAdd(&gsq[t], lq[t]);
    }
}

// graph-LN (stats finalized inline from raw sums) + fused bf16 hi/lo split
__global__ __launch_bounds__(256) void gnorm_split_k(float* __restrict__ y,
    const int* __restrict__ batch, const float* __restrict__ gsum, const float* __restrict__ gsq,
    const int* __restrict__ gcnt, const float* __restrict__ w, const float* __restrict__ b,
    u16* __restrict__ hi, u16* __restrict__ lo)
{
    int i = blockIdx.x * 256 + threadIdx.x;   // float4 index
    if (i >= Nn * (FD / 4)) return;
    int n = i / 96, c4 = i - n * 96;
    int g = batch[n];
    float norm = fmaxf((float)gcnt[g], 1.f) * (float)FD;
    float m = gsum[g] / norm;
    float var = gsq[g] / norm - m * m;
    float rstd = rsqrtf(var + EPS);
    float4 wv = ((const float4*)w)[c4];
    float4 bv = ((const float4*)b)[c4];
    float4 v = ((const float4*)y)[i];
    v.x = (v.x - m) * rstd * wv.x + bv.x;
    v.y = (v.y - m) * rstd * wv.y + bv.y;
    v.z = (v.z - m) * rstd * wv.z + bv.z;
    v.w = (v.w - m) * rstd * wv.w + bv.w;
    ((float4*)y)[i] = v;
    ushort4 hh, ll;
    hh.x = f2b(v.x); ll.x = f2b(v.x - b2f(hh.x));
    hh.y = f2b(v.y); ll.y = f2b(v.y - b2f(hh.y));
    hh.z = f2b(v.z); ll.z = f2b(v.z - b2f(hh.z));
    hh.w = f2b(v.w); ll.w = f2b(v.w - b2f(hh.w));
    ((ushort4*)hi)[i] = hh;
    ((ushort4*)lo)[i] = ll;
}

__global__ void softmax_prior_k(const float* __restrict__ logits, float* __restrict__ prior)
{
    int n = blockIdx.x * 8 + (threadIdx.x >> 5);
    int l = threadIdx.x & 31;
    if (n >= Nn) return;
    float v = logits[n * 32 + l];
    float m = v;
    #pragma unroll
    for (int o = 16; o; o >>= 1) m = fmaxf(m, __shfl_xor(m, o, 32));
    float e = __expf(v - m);
    float s = e;
    #pragma unroll
    for (int o = 16; o; o >>= 1) s += __shfl_xor(s, o, 32);
    prior[(size_t)n * 33 + l] = e / s;
    if (l == 0) prior[(size_t)n * 33 + 32] = 1.f / s;
}

extern "C" void kernel_launch(void* const* d_in, const int* in_sizes, int n_in,
                              void* d_out, int out_size, void* d_ws, size_t ws_size,
                              hipStream_t stream)
{
    const float* x_visual = (const float*)d_in[0];
    const float* x_geom   = (const float*)d_in[1];
    const float* x_prior  = (const float*)d_in[2];
    const int* ei0   = (const int*)d_in[3];
    const int* ei1   = (const int*)d_in[4];
    const int* ei2   = (const int*)d_in[5];
    const int* batch = (const int*)d_in[6];
    const float* vis_W = (const float*)d_in[7];  const float* vis_b = (const float*)d_in[8];
    const float* vis_lnw = (const float*)d_in[9]; const float* vis_lnb = (const float*)d_in[10];
    const float* geo_W = (const float*)d_in[11]; const float* geo_b = (const float*)d_in[12];
    const float* geo_lnw = (const float*)d_in[13]; const float* geo_lnb = (const float*)d_in[14];
    const float* pri_W = (const float*)d_in[15]; const float* pri_b = (const float*)d_in[16];
    const float* pri_lnw = (const float*)d_in[17]; const float* pri_lnb = (const float*)d_in[18];
    const float* rgat_W[2]    = { (const float*)d_in[19], (const float*)d_in[25] };
    const float* rgat_q[2]    = { (const float*)d_in[20], (const float*)d_in[26] };
    const float* rgat_kk[2]   = { (const float*)d_in[21], (const float*)d_in[27] };
    const float* rgat_bias[2] = { (const float*)d_in[22], (const float*)d_in[28] };
    const float* ln_w[2]      = { (const float*)d_in[23], (const float*)d_in[29] };
    const float* ln_b[2]      = { (const float*)d_in[24], (const float*)d_in[30] };
    const float* cls_W1 = (const float*)d_in[31]; const float* cls_b1 = (const float*)d_in[32];
    const float* cls_W2 = (const float*)d_in[33]; const float* cls_b2 = (const float*)d_in[34];
    float* OUT = (float*)d_out;

    // ---------------- workspace layout ----------------
    float* ws = (float*)d_ws;
    float* XRreg = ws;                         // 3*Nn*FD floats reserved (92.2 MB region)
    u16*   XR16  = (u16*)XRreg;                // XR stored bf16: first 46 MB of the region
    float* HCAT  = XRreg + (size_t)3 * Nn * FD;
    float* HA    = HCAT + (size_t)Nn * FD;
    float* HB    = HA + (size_t)Nn * FD;
    float* PRIOR = HB + (size_t)Nn * FD;       // Nn*33
    float* QIK   = PRIOR + (size_t)Nn * 33;    // 3*Nn*16 (q heads 0-7, k heads 8-15)
    u16* HS0_HI  = (u16*)(QIK + (size_t)3 * Nn * 16);  // HCAT split
    u16* HS0_LO  = HS0_HI + (size_t)Nn * FD;
    u16* HS1_HI  = HS0_LO + (size_t)Nn * FD;          // HA split
    u16* HS1_LO  = HS1_HI + (size_t)Nn * FD;
    u16* RW_HI   = HS1_LO + (size_t)Nn * FD;   // 2*3*384*384
    u16* RW_LO   = RW_HI + (size_t)2 * 3 * 384 * 384;
    u16* VW_HI   = RW_LO + (size_t)2 * 3 * 384 * 384; // 128*1024
    u16* VW_LO   = VW_HI + (size_t)128 * 1024;
    u16* CW_HI   = VW_LO + (size_t)128 * 1024;        // 128*384
    u16* CW_LO   = CW_HI + (size_t)128 * 384;
    u16* QKW_HI  = CW_LO + (size_t)128 * 384;         // 2 layers * 16*384
    u16* QKW_LO  = QKW_HI + (size_t)2 * 16 * 384;
    float* STATS = (float*)(QKW_LO + (size_t)2 * 16 * 384); // 2
    float* GSUM  = STATS + 2;                  // 64
    float* GSQ   = GSUM + 64;
    int* CNT    = (int*)(GSQ + 64);
    int* ROWPTR = CNT + Nn;
    int* CURSOR = ROWPTR + Nn + 1;
    int* EIDX   = CURSOR + Nn;
    int* GCNT   = EIDX + ETOT;
    int* DSTE   = GCNT + 64;                   // ETOT
    float* EW   = (float*)(DSTE + ETOT);       // ETOT*8 floats (5.76 MB)
    // aliases into the XR region (temporally dead sub-ranges):
    u16* VA_HI = (u16*)XRreg;                  // x_visual split [0,82MB): dead after vis gemm
    u16* VA_LO = VA_HI + (size_t)Nn * 1024;
    float* CLSH = XRreg;                       // classifier hidden [0,10.3MB): after last aggr
    u16* HS2_HI = (u16*)(XRreg + (size_t)12 * 1000 * 1000); // HB split [48MB,78.7MB): after last aggr
    u16* HS2_LO = HS2_HI + (size_t)Nn * FD;

    // ---------------- CSR build (reused by all 4 RGAT calls) ----------------
    hipMemsetAsync(CNT, 0, Nn * sizeof(int), stream);
    edge_count_k<<<cdiv(ETOT, 256), 256, 0, stream>>>(ei0, ei1, ei2, CNT);
    scan_k<<<1, 1024, 0, stream>>>(CNT, ROWPTR, CURSOR);
    edge_fill_k<<<cdiv(ETOT, 256), 256, 0, stream>>>(ei0, ei1, ei2, CURSOR, EIDX, DSTE);
    hipMemsetAsync(GCNT, 0, 64 * sizeof(int), stream);
    gcount_k<<<cdiv(Nn, 256), 256, 0, stream>>>(batch, GCNT);

    // ---------------- weight + x_visual conversions ----------------
    tsplit_k<<<cdiv(3 * 384 * 384, 256), 256, 0, stream>>>(rgat_W[0], RW_HI, RW_LO, 384, 384, 3 * 384 * 384);
    tsplit_k<<<cdiv(3 * 384 * 384, 256), 256, 0, stream>>>(rgat_W[1], RW_HI + 3 * 384 * 384, RW_LO + 3 * 384 * 384, 384, 384, 3 * 384 * 384);
    tsplit_k<<<cdiv(1024 * 128, 256), 256, 0, stream>>>(vis_W, VW_HI, VW_LO, 1024, 128, 1024 * 128);
    tsplit_k<<<cdiv(384 * 128, 256), 256, 0, stream>>>(cls_W1, CW_HI, CW_LO, 384, 128, 384 * 128);
    prep_qkw_k<<<cdiv(16 * 384, 256), 256, 0, stream>>>(rgat_q[0], rgat_kk[0], QKW_HI, QKW_LO);
    prep_qkw_k<<<cdiv(16 * 384, 256), 256, 0, stream>>>(rgat_q[1], rgat_kk[1], QKW_HI + 16 * 384, QKW_LO + 16 * 384);
    split_k<<<cdiv(Nn * 1024 / 4, 256), 256, 0, stream>>>(x_visual, VA_HI, VA_LO, Nn * 1024 / 4);

    const int MB = cdiv(Nn, 128);   // 157
    const int XRBLK = 160 * 9;      // padded rows * (3 cols x 3 rels), XCD-swizzled

    // ---------------- vis encoder (MFMA) -> HCAT[:,0:128) ----------------
    hipMemsetAsync(STATS, 0, 2 * sizeof(float), stream);
    mgemm_k<true, true, true, false, 3, false><<<dim3(MB, 1, 1), 256, 0, stream>>>(
        VA_HI, VA_LO, VW_HI, VW_LO, vis_b, HCAT, Nn, 1024, FD, 0, STATS);
    enc_norm_k<<<cdiv(Nn * 32, 256), 256, 0, stream>>>(HCAT, vis_lnw, vis_lnb, STATS, 1.f / ((float)Nn * 128.f), HS0_HI, HS0_LO);

    // ---------------- geo encoder (fp32, K=6) -> HCAT[:,128:256) ----------------
    dim3 genc(cdiv(Nn, 64), 2, 1);
    hipMemsetAsync(STATS, 0, 2 * sizeof(float), stream);
    sgemm_k<true, true, true><<<genc, 256, 0, stream>>>(x_geom, geo_W, geo_b, HCAT + 128, Nn, 6, 128, FD, STATS);
    enc_norm_k<<<cdiv(Nn * 32, 256), 256, 0, stream>>>(HCAT + 128, geo_lnw, geo_lnb, STATS, 1.f / ((float)Nn * 128.f), HS0_HI + 128, HS0_LO + 128);

    for (int t = 0; t < 2; t++) {
        // prior encoder (fp32, K=33) -> HCAT[:,256:384)
        const float* pin = t ? PRIOR : x_prior;
        hipMemsetAsync(STATS, 0, 2 * sizeof(float), stream);
        sgemm_k<true, true, true><<<genc, 256, 0, stream>>>(pin, pri_W, pri_b, HCAT + 256, Nn, 33, 128, FD, STATS);
        enc_norm_k<<<cdiv(Nn * 32, 256), 256, 0, stream>>>(HCAT + 256, pri_lnw, pri_lnb, STATS, 1.f / ((float)Nn * 128.f), HS0_HI + 256, HS0_LO + 256);

        float* hin = HCAT;
        for (int L = 0; L < 2; L++) {
            float* hout = L ? HB : HA;
            const u16* ahi = L ? HS1_HI : HS0_HI;
            const u16* alo = L ? HS1_LO : HS0_LO;
            u16* shi = L ? HS2_HI : HS1_HI;
            u16* slo = L ? HS2_LO : HS1_LO;
            mgemm_k<false, false, false, true, 2, true><<<dim3(XRBLK, 1, 1), 256, 0, stream>>>(
                ahi, alo, RW_HI + (size_t)L * 3 * 384 * 384, RW_LO + (size_t)L * 3 * 384 * 384,
                nullptr, XR16, Nn, 384, FD, 384 * 384, nullptr);
            proj_k<<<cdiv(3 * Nn, 128), 256, 0, stream>>>(XR16,
                QKW_HI + (size_t)L * 16 * 384, QKW_LO + (size_t)L * 16 * 384, QIK);
            ew_k<<<cdiv(ETOT, 256), 256, 0, stream>>>(QIK, EIDX, DSTE, EW);
            hipMemsetAsync(GSUM, 0, 128 * sizeof(float), stream);  // GSUM+GSQ contiguous
            aggr_k<<<cdiv(Nn, 4), 256, 0, stream>>>(XR16, EW, ROWPTR, EIDX, rgat_bias[L],
                                                    hin, batch, hout, GSUM, GSQ);
            gnorm_split_k<<<cdiv(Nn * 96, 256), 256, 0, stream>>>(hout, batch, GSUM, GSQ, GCNT, ln_w[L], ln_b[L], shi, slo);
            hin = hout;
        }

        // classifier: cls1 (MFMA, reads HS2 split) -> CLSH, cls2 (fp32) -> OUT
        mgemm_k<true, true, false, false, 3, false><<<dim3(MB, 1, 1), 256, 0, stream>>>(
            HS2_HI, HS2_LO, CW_HI, CW_LO, cls_b1, CLSH, Nn, 384, 128, 0, nullptr);
        sgemm_k<true, false, false><<<dim3(cdiv(Nn, 64), 1, 1), 256, 0, stream>>>(
            CLSH, cls_W2, cls_b2, OUT, Nn, 128, 32, 32, nullptr);

        if (t == 0)
            softmax_prior_k<<<cdiv(Nn, 8), 256, 0, stream>>>(OUT, PRIOR);
    }
}

// Round 10
// 903.183 us; speedup vs baseline: 1.5673x; 1.0187x over previous
//
#include <hip/hip_runtime.h>
#include <hip/hip_bf16.h>

#define Nn 20000
#define EREL 60000
#define ETOT 180000
#define NG 64
#define FD 384
#define EPS 1e-5f

typedef unsigned short u16;
typedef unsigned int u32;
typedef __attribute__((ext_vector_type(8))) short s8v;     // 8 bf16 (4 VGPR) MFMA A/B frag
typedef __attribute__((ext_vector_type(4))) float f4v;     // MFMA C/D frag

static inline int cdiv(int a, int b) { return (a + b - 1) / b; }

__device__ inline u16 f2b(float f) {
    __hip_bfloat16 h = __float2bfloat16(f);
    union { __hip_bfloat16 b; u16 u; } c; c.b = h; return c.u;
}
__device__ inline float b2f(u16 u) {
    union { __hip_bfloat16 b; u16 u; } c; c.u = u; return __bfloat162float(c.b);
}

// ---------------- split fp32 -> bf16 hi/lo (vectorized by float4) ----------------
__global__ __launch_bounds__(256) void split_k(const float* __restrict__ x,
    u16* __restrict__ hi, u16* __restrict__ lo, int n4)
{
    int i = blockIdx.x * 256 + threadIdx.x;
    if (i >= n4) return;
    float4 v = ((const float4*)x)[i];
    ushort4 h, l;
    h.x = f2b(v.x); l.x = f2b(v.x - b2f(h.x));
    h.y = f2b(v.y); l.y = f2b(v.y - b2f(h.y));
    h.z = f2b(v.z); l.z = f2b(v.z - b2f(h.z));
    h.w = f2b(v.w); l.w = f2b(v.w - b2f(h.w));
    ((ushort4*)hi)[i] = h;
    ((ushort4*)lo)[i] = l;
}

// transpose + split: W[b][K][N] -> T[b][N][K] hi/lo
__global__ void tsplit_k(const float* __restrict__ W, u16* __restrict__ hi,
                         u16* __restrict__ lo, int K, int N, int total)
{
    int idx = blockIdx.x * 256 + threadIdx.x;
    if (idx >= total) return;
    int kn = K * N;
    int b = idx / kn, rem = idx - b * kn;
    int k = rem / N, n = rem - k * N;
    float v = W[idx];
    u16 h = f2b(v), l = f2b(v - b2f(h));
    int o = b * kn + n * K + k;
    hi[o] = h; lo[o] = l;
}

// pack q (384x8) and k (384x8) into QKW[16][384] hi/lo: col<8 = q head, col>=8 = k head
__global__ void prep_qkw_k(const float* __restrict__ q, const float* __restrict__ kk,
                           u16* __restrict__ hi, u16* __restrict__ lo)
{
    int idx = blockIdx.x * 256 + threadIdx.x;
    if (idx >= 16 * 384) return;
    int col = idx / 384, k = idx - col * 384;
    float v = (col < 8) ? q[k * 8 + col] : kk[k * 8 + col - 8];
    u16 h = f2b(v), l = f2b(v - b2f(h));
    hi[idx] = h; lo[idx] = l;
}

// ---------------- split-bf16 MFMA GEMM ----------------
// C[M,N] = A[M,K] @ B[N,K]^T, A,B bf16 (hi,lo) pairs row-major ld=K. 128x128 tile,
// 4 waves of 64x64, 16x16x32 MFMA. TERMS=3: hi*bh + lo*bh + hi*bl (~fp32).
// TERMS=2: hi*bh + lo*bh (B-lo never read). SWZ: XCD-aware grid for the XR shape.
template<bool BIAS, bool RELU, bool STATS, bool OB16, int TERMS, bool SWZ>
__global__ __launch_bounds__(256) void mgemm_k(
    const u16* __restrict__ Ahi, const u16* __restrict__ Alo,
    const u16* __restrict__ Bhi, const u16* __restrict__ Blo,
    const float* __restrict__ bias, void* __restrict__ Cv,
    int M, int K, int ldc, int bstride, float* __restrict__ stats)
{
    __shared__ u16 lds[4 * 128 * 32];   // Ahi | Alo | Bhi | (Blo) tiles, [128][32] each
    __shared__ float red[256];
    const int t = threadIdx.x;
    int brow, bcol, z;
    if (SWZ) {
        int d = blockIdx.x;
        int xcd = d & 7, s = d >> 3;
        int row = xcd + 8 * (s / 9);
        int c = s % 9;
        brow = row * 128;
        if (brow >= M) return;
        bcol = (c % 3) * 128;
        z = c / 3;
    } else {
        brow = blockIdx.x * 128; bcol = blockIdx.y * 128; z = blockIdx.z;
    }
    Bhi += (size_t)z * bstride;
    Blo += (size_t)z * bstride;
    float* Cf = OB16 ? nullptr : (float*)Cv + (size_t)z * M * ldc;
    u16*   Ch = OB16 ? (u16*)Cv + (size_t)z * M * ldc : nullptr;

    const int NSRC = (TERMS == 3) ? 8 : 6;
    const int r0 = t >> 2, sl = t & 3;
    const int rA0 = min(brow + r0, M - 1);
    const int rA1 = min(brow + r0 + 64, M - 1);
    const u16* gsrc[8];
    gsrc[0] = Ahi + (size_t)rA0 * K + sl * 8;
    gsrc[1] = Ahi + (size_t)rA1 * K + sl * 8;
    gsrc[2] = Alo + (size_t)rA0 * K + sl * 8;
    gsrc[3] = Alo + (size_t)rA1 * K + sl * 8;
    gsrc[4] = Bhi + (size_t)(bcol + r0) * K + sl * 8;
    gsrc[5] = Bhi + (size_t)(bcol + r0 + 64) * K + sl * 8;
    gsrc[6] = Blo + (size_t)(bcol + r0) * K + sl * 8;
    gsrc[7] = Blo + (size_t)(bcol + r0 + 64) * K + sl * 8;
    const int swz = (sl ^ (r0 & 3)) << 3;
    int ldst[8];
    #pragma unroll
    for (int i = 0; i < 8; i++) {
        int tile = i >> 1, row = r0 + 64 * (i & 1);
        ldst[i] = tile * 4096 + row * 32 + swz;
    }

    const int l = t & 63, w = t >> 6;
    const int wr = (w >> 1) * 64, wc = (w & 1) * 64;
    const int lr = l & 15, kq = l >> 4;

    f4v acc[4][4] = {};
    const int NK = K >> 5;

    s8v stg[8];
    #pragma unroll
    for (int i = 0; i < 8; i++) if (i < NSRC) stg[i] = *(const s8v*)gsrc[i];

    for (int kc = 0; kc < NK; kc++) {
        if (kc) __syncthreads();
        #pragma unroll
        for (int i = 0; i < 8; i++) if (i < NSRC) *(s8v*)(lds + ldst[i]) = stg[i];
        __syncthreads();
        if (kc + 1 < NK) {
            const int ko = (kc + 1) * 32;
            #pragma unroll
            for (int i = 0; i < 8; i++) if (i < NSRC) stg[i] = *(const s8v*)(gsrc[i] + ko);
        }
        #define LDR(T, row) (*(const s8v*)(lds + (T) * 4096 + (row) * 32 + ((kq ^ ((row) & 3)) << 3)))
        s8v bh[4], bl[4];
        #pragma unroll
        for (int tn = 0; tn < 4; tn++) {
            int rb = wc + tn * 16 + lr;
            bh[tn] = LDR(2, rb);
            if (TERMS == 3) bl[tn] = LDR(3, rb);
        }
        #pragma unroll
        for (int tm = 0; tm < 4; tm++) {
            int ra = wr + tm * 16 + lr;
            s8v ah = LDR(0, ra);
            s8v al = LDR(1, ra);
            #pragma unroll
            for (int tn = 0; tn < 4; tn++) {
                acc[tm][tn] = __builtin_amdgcn_mfma_f32_16x16x32_bf16(ah, bh[tn], acc[tm][tn], 0, 0, 0);
                acc[tm][tn] = __builtin_amdgcn_mfma_f32_16x16x32_bf16(al, bh[tn], acc[tm][tn], 0, 0, 0);
                if (TERMS == 3)
                    acc[tm][tn] = __builtin_amdgcn_mfma_f32_16x16x32_bf16(ah, bl[tn], acc[tm][tn], 0, 0, 0);
            }
        }
        #undef LDR
    }

    float s1 = 0.f, s2 = 0.f;
    #pragma unroll
    for (int tm = 0; tm < 4; tm++) {
        #pragma unroll
        for (int rg = 0; rg < 4; rg++) {
            int row = brow + wr + tm * 16 + kq * 4 + rg;
            if (row < M) {
                #pragma unroll
                for (int tn = 0; tn < 4; tn++) {
                    int col = bcol + wc + tn * 16 + lr;
                    float v = acc[tm][tn][rg];
                    if (BIAS) v += bias[col];
                    if (RELU) v = fmaxf(v, 0.f);
                    if (OB16) Ch[(size_t)row * ldc + col] = f2b(v);
                    else      Cf[(size_t)row * ldc + col] = v;
                    if (STATS) { s1 += v; s2 += v * v; }
                }
            }
        }
    }
    if (STATS) {
        __syncthreads();
        red[t] = s1; __syncthreads();
        for (int o = 128; o; o >>= 1) { if (t < o) red[t] += red[t + o]; __syncthreads(); }
        if (t == 0) atomicAdd(&stats[0], red[0]);
        __syncthreads();
        red[t] = s2; __syncthreads();
        for (int o = 128; o; o >>= 1) { if (t < o) red[t] += red[t + o]; __syncthreads(); }
        if (t == 0) atomicAdd(&stats[1], red[0]);
    }
}

// ---------------- proj GEMM: QIK[3Nn,16] = XR[3Nn,384] @ QKW[16,384]^T ----------------
__global__ __launch_bounds__(256) void proj_k(const u16* __restrict__ xr,
    const u16* __restrict__ qkw_hi, const u16* __restrict__ qkw_lo,
    float* __restrict__ qik)
{
    const int M3 = 3 * Nn;
    __shared__ u16 a_lds[128 * 32];
    __shared__ u16 b_lds[2][16 * 392];
    int t = threadIdx.x;
    int brow = blockIdx.x * 128;

    for (int i = t; i < 768; i += 256) {
        int col = i / 48, c8 = (i - col * 48) * 8;
        *(s8v*)&b_lds[0][col * 392 + c8] = *(const s8v*)(qkw_hi + col * 384 + c8);
        *(s8v*)&b_lds[1][col * 392 + c8] = *(const s8v*)(qkw_lo + col * 384 + c8);
    }

    int ar = t >> 1;
    int sl0 = (t & 1) * 2;
    int grow = min(brow + ar, M3 - 1);
    const u16* asrc = xr + (size_t)grow * 384;
    int adst0 = ar * 32 + ((sl0 ^ (ar & 3)) << 3);
    int adst1 = ar * 32 + (((sl0 + 1) ^ (ar & 3)) << 3);

    int l = t & 63, w = t >> 6;
    int lr = l & 15, kq = l >> 4;
    f4v acc0 = {}, acc1 = {};

    s8v stg0 = *(const s8v*)(asrc + sl0 * 8);
    s8v stg1 = *(const s8v*)(asrc + sl0 * 8 + 8);
    for (int kc = 0; kc < 12; kc++) {
        if (kc) __syncthreads();
        *(s8v*)&a_lds[adst0] = stg0;
        *(s8v*)&a_lds[adst1] = stg1;
        __syncthreads();
        if (kc + 1 < 12) {
            int ko = (kc + 1) * 32 + sl0 * 8;
            stg0 = *(const s8v*)(asrc + ko);
            stg1 = *(const s8v*)(asrc + ko + 8);
        }
        s8v bh = *(const s8v*)&b_lds[0][lr * 392 + kc * 32 + kq * 8];
        s8v bl = *(const s8v*)&b_lds[1][lr * 392 + kc * 32 + kq * 8];
        int r0 = w * 32 + lr;
        s8v a0 = *(const s8v*)&a_lds[r0 * 32 + ((kq ^ (r0 & 3)) << 3)];
        int r1 = r0 + 16;
        s8v a1 = *(const s8v*)&a_lds[r1 * 32 + ((kq ^ (r1 & 3)) << 3)];
        acc0 = __builtin_amdgcn_mfma_f32_16x16x32_bf16(a0, bh, acc0, 0, 0, 0);
        acc0 = __builtin_amdgcn_mfma_f32_16x16x32_bf16(a0, bl, acc0, 0, 0, 0);
        acc1 = __builtin_amdgcn_mfma_f32_16x16x32_bf16(a1, bh, acc1, 0, 0, 0);
        acc1 = __builtin_amdgcn_mfma_f32_16x16x32_bf16(a1, bl, acc1, 0, 0, 0);
    }
    #pragma unroll
    for (int rg = 0; rg < 4; rg++) {
        int row0 = brow + w * 32 + kq * 4 + rg;
        if (row0 < M3) qik[(size_t)row0 * 16 + lr] = acc0[rg];
        int row1 = row0 + 16;
        if (row1 < M3) qik[(size_t)row1 * 16 + lr] = acc1[rg];
    }
}

// ---------------- fp32 tiled GEMM (tiny-K shapes: geo K=6, pri K=33, cls2) ----------------
template<bool BIAS, bool RELU, bool STATS>
__global__ __launch_bounds__(256) void sgemm_k(
    const float* __restrict__ A, const float* __restrict__ B,
    const float* __restrict__ bias, float* __restrict__ C,
    int M, int K, int N, int ldc, float* __restrict__ stats)
{
    const int BK = 16;
    const int r = blockIdx.z;
    B += (size_t)r * K * N;
    C += (size_t)r * M * ldc;
    __shared__ float As[16][65];
    __shared__ float Bs[16][64];
    int tid = threadIdx.x;
    int tx = tid & 15, ty = tid >> 4;
    int brow = blockIdx.x * 64, bcol = blockIdx.y * 64;
    float acc[4][4] = {};
    for (int k0 = 0; k0 < K; k0 += BK) {
        #pragma unroll
        for (int i = 0; i < 4; i++) {
            int e = tid + 256 * i;
            int ar = e >> 4, ak = e & 15;
            int gr = brow + ar, gk = k0 + ak;
            As[ak][ar] = (gr < M && gk < K) ? A[(size_t)gr * K + gk] : 0.f;
            int bk = e >> 6, bn = e & 63;
            int gbk = k0 + bk, gbn = bcol + bn;
            Bs[bk][bn] = (gbk < K && gbn < N) ? B[(size_t)gbk * N + gbn] : 0.f;
        }
        __syncthreads();
        #pragma unroll
        for (int k = 0; k < BK; k++) {
            float ra[4], rb[4];
            #pragma unroll
            for (int i = 0; i < 4; i++) ra[i] = As[k][ty * 4 + i];
            #pragma unroll
            for (int j = 0; j < 4; j++) rb[j] = Bs[k][tx * 4 + j];
            #pragma unroll
            for (int i = 0; i < 4; i++)
                #pragma unroll
                for (int j = 0; j < 4; j++)
                    acc[i][j] = fmaf(ra[i], rb[j], acc[i][j]);
        }
        __syncthreads();
    }
    float s1 = 0.f, s2 = 0.f;
    #pragma unroll
    for (int i = 0; i < 4; i++) {
        int row = brow + ty * 4 + i;
        #pragma unroll
        for (int j = 0; j < 4; j++) {
            int col = bcol + tx * 4 + j;
            if (row < M && col < N) {
                float v = acc[i][j];
                if (BIAS) v += bias[col];
                if (RELU) v = v > 0.f ? v : 0.f;
                C[(size_t)row * ldc + col] = v;
                if (STATS) { s1 += v; s2 += v * v; }
            }
        }
    }
    if (STATS) {
        __shared__ float red[256];
        __syncthreads();
        red[tid] = s1; __syncthreads();
        for (int o = 128; o; o >>= 1) { if (tid < o) red[tid] += red[tid + o]; __syncthreads(); }
        if (tid == 0) atomicAdd(&stats[0], red[0]);
        __syncthreads();
        red[tid] = s2; __syncthreads();
        for (int o = 128; o; o >>= 1) { if (tid < o) red[tid] += red[tid + o]; __syncthreads(); }
        if (tid == 0) atomicAdd(&stats[1], red[0]);
    }
}

// scalar-LN of a 128-col block of H (pre-offset) from RAW sums, fused bf16 hi/lo split.
__global__ __launch_bounds__(256) void enc_norm_k(float* __restrict__ H, const float* __restrict__ w,
                           const float* __restrict__ b, const float* __restrict__ stats,
                           float cntinv, u16* __restrict__ hi, u16* __restrict__ lo)
{
    int i = blockIdx.x * 256 + threadIdx.x;   // float4 index within the 128-col block
    if (i >= Nn * 32) return;
    int n = i >> 5, c4 = i & 31;
    float m = stats[0] * cntinv;
    float var = stats[1] * cntinv - m * m;
    float s = 1.f / (sqrtf(fmaxf(var, 0.f)) + EPS);
    float4 wv = ((const float4*)w)[c4];
    float4 bv = ((const float4*)b)[c4];
    float4* p = (float4*)(H + (size_t)n * FD) + c4;
    float4 v = *p;
    v.x = (v.x - m) * s * wv.x + bv.x;
    v.y = (v.y - m) * s * wv.y + bv.y;
    v.z = (v.z - m) * s * wv.z + bv.z;
    v.w = (v.w - m) * s * wv.w + bv.w;
    *p = v;
    ushort4 hh, ll;
    hh.x = f2b(v.x); ll.x = f2b(v.x - b2f(hh.x));
    hh.y = f2b(v.y); ll.y = f2b(v.y - b2f(hh.y));
    hh.z = f2b(v.z); ll.z = f2b(v.z - b2f(hh.z));
    hh.w = f2b(v.w); ll.w = f2b(v.w - b2f(hh.w));
    ((ushort4*)(hi + (size_t)n * FD))[c4] = hh;
    ((ushort4*)(lo + (size_t)n * FD))[c4] = ll;
}

// per-edge unnormalized attention weights from fused QIK[row][16] (q: 0-7, k: 8-15)
__global__ __launch_bounds__(256) void ew_k(const float* __restrict__ qik,
    const int* __restrict__ eidx, const int* __restrict__ dste, float* __restrict__ ew)
{
    int e = blockIdx.x * 256 + threadIdx.x;
    if (e >= ETOT) return;
    int p = eidx[e];
    int src = p & 0xFFFFFF, et = p >> 24;
    int dst = dste[e];
    const float4* q4 = (const float4*)(qik + ((size_t)et * Nn + dst) * 16);
    const float4* k4 = (const float4*)(qik + ((size_t)et * Nn + src) * 16 + 8);
    float4 out[2];
    #pragma unroll
    for (int half = 0; half < 2; half++) {
        float4 qv = q4[half], kv = k4[half];
        float a0 = qv.x + kv.x, a1 = qv.y + kv.y, a2 = qv.z + kv.z, a3 = qv.w + kv.w;
        a0 = (a0 > 0.f) ? a0 : 0.2f * a0;
        a1 = (a1 > 0.f) ? a1 : 0.2f * a1;
        a2 = (a2 > 0.f) ? a2 : 0.2f * a2;
        a3 = (a3 > 0.f) ? a3 : 0.2f * a3;
        out[half] = make_float4(__expf(a0), __expf(a1), __expf(a2), __expf(a3));
    }
    float4* ew4 = (float4*)(ew + (size_t)e * 8);
    ew4[0] = out[0];
    ew4[1] = out[1];
}

__global__ void edge_count_k(const int* __restrict__ e0, const int* __restrict__ e1,
                             const int* __restrict__ e2, int* __restrict__ cnt)
{
    int e = blockIdx.x * 256 + threadIdx.x;
    if (e >= ETOT) return;
    int r = e / EREL, i = e - r * EREL;
    const int* ei = (r == 0) ? e0 : (r == 1) ? e1 : e2;
    atomicAdd(&cnt[ei[EREL + i]], 1);
}

__global__ void edge_fill_k(const int* __restrict__ e0, const int* __restrict__ e1,
                            const int* __restrict__ e2, int* __restrict__ cursor,
                            int* __restrict__ eidx, int* __restrict__ dste)
{
    int e = blockIdx.x * 256 + threadIdx.x;
    if (e >= ETOT) return;
    int r = e / EREL, i = e - r * EREL;
    const int* ei = (r == 0) ? e0 : (r == 1) ? e1 : e2;
    int src = ei[i], dst = ei[EREL + i];
    int pos = atomicAdd(&cursor[dst], 1);
    eidx[pos] = src | (r << 24);
    dste[pos] = dst;
}

__global__ __launch_bounds__(1024) void scan_k(const int* __restrict__ cnt,
                                               int* __restrict__ rowptr, int* __restrict__ cursor)
{
    __shared__ int lds[1024];
    __shared__ int carry;
    int t = threadIdx.x;
    if (t == 0) carry = 0;
    __syncthreads();
    for (int base = 0; base < Nn; base += 1024) {
        int i = base + t;
        int v = (i < Nn) ? cnt[i] : 0;
        lds[t] = v; __syncthreads();
        for (int o = 1; o < 1024; o <<= 1) {
            int x = (t >= o) ? lds[t - o] : 0;
            __syncthreads();
            lds[t] += x;
            __syncthreads();
        }
        int c = carry;
        if (i < Nn) { int ex = c + lds[t] - v; rowptr[i] = ex; cursor[i] = ex; }
        __syncthreads();
        if (t == 1023) carry = c + lds[1023];
        __syncthreads();
    }
    if (t == 0) rowptr[Nn] = carry;
}

// per-graph node counts via LDS histogram: 1 global atomic per (block, graph)
__global__ __launch_bounds__(256) void gcount_k(const int* __restrict__ batch, int* __restrict__ gcnt)
{
    __shared__ int bins[NG];
    int t = threadIdx.x;
    if (t < NG) bins[t] = 0;
    __syncthreads();
    int n = blockIdx.x * 256 + t;
    if (n < Nn) atomicAdd(&bins[batch[n]], 1);
    __syncthreads();
    if (t < NG && bins[t]) atomicAdd(&gcnt[t], bins[t]);
}

// RGAT aggregation from precomputed EW. One wave per dst node, single pass, 4x edge
// unroll with batched loads (12 gathers + 4 ew loads in flight per iteration -> MLP).
// Rows gathered as dwords (2 bf16/lane/chunk, bit-shift convert). Fused elu/residual/stats.
__global__ __launch_bounds__(256) void aggr_k(const u16* __restrict__ xr,
    const float* __restrict__ ew, const int* __restrict__ rowptr, const int* __restrict__ eidx,
    const float* __restrict__ bias, const float* __restrict__ hin,
    const int* __restrict__ batch, float* __restrict__ out,
    float* __restrict__ gsum, float* __restrict__ gsq)
{
    __shared__ float ls[NG], lq[NG];
    int t = threadIdx.x;
    if (t < NG) { ls[t] = 0.f; lq[t] = 0.f; }
    __syncthreads();
    int node = blockIdx.x * 4 + (t >> 6);
    int lane = t & 63;
    int e0 = rowptr[node], e1 = rowptr[node + 1];
    int hd[3];
    #pragma unroll
    for (int j = 0; j < 3; j++) hd[j] = (lane * 2 + 128 * j) / 48;  // c,c+1 same head (c even)
    float den = 0.f;                 // lane h < 8 accumulates head h
    float accx[3] = {}, accy[3] = {};

    int e = e0;
    while (e + 4 <= e1) {
        int p0 = eidx[e], p1 = eidx[e + 1], p2 = eidx[e + 2], p3 = eidx[e + 3];
        const u32* r0 = (const u32*)(xr + ((size_t)(p0 >> 24) * Nn + (p0 & 0xFFFFFF)) * FD);
        const u32* r1 = (const u32*)(xr + ((size_t)(p1 >> 24) * Nn + (p1 & 0xFFFFFF)) * FD);
        const u32* r2 = (const u32*)(xr + ((size_t)(p2 >> 24) * Nn + (p2 & 0xFFFFFF)) * FD);
        const u32* r3 = (const u32*)(xr + ((size_t)(p3 >> 24) * Nn + (p3 & 0xFFFFFF)) * FD);
        float ev0 = (lane < 8) ? ew[(size_t)e * 8 + lane] : 0.f;
        float ev1 = (lane < 8) ? ew[(size_t)(e + 1) * 8 + lane] : 0.f;
        float ev2 = (lane < 8) ? ew[(size_t)(e + 2) * 8 + lane] : 0.f;
        float ev3 = (lane < 8) ? ew[(size_t)(e + 3) * 8 + lane] : 0.f;
        u32 u0[3], u1[3], u2[3], u3[3];
        #pragma unroll
        for (int j = 0; j < 3; j++) u0[j] = r0[lane + 64 * j];
        #pragma unroll
        for (int j = 0; j < 3; j++) u1[j] = r1[lane + 64 * j];
        #pragma unroll
        for (int j = 0; j < 3; j++) u2[j] = r2[lane + 64 * j];
        #pragma unroll
        for (int j = 0; j < 3; j++) u3[j] = r3[lane + 64 * j];
        den += ev0 + ev1 + ev2 + ev3;
        #pragma unroll
        for (int j = 0; j < 3; j++) {
            float a0 = __shfl(ev0, hd[j]), a1 = __shfl(ev1, hd[j]);
            float a2 = __shfl(ev2, hd[j]), a3 = __shfl(ev3, hd[j]);
            accx[j] = fmaf(a0, __uint_as_float(u0[j] << 16), accx[j]);
            accy[j] = fmaf(a0, __uint_as_float(u0[j] & 0xffff0000u), accy[j]);
            accx[j] = fmaf(a1, __uint_as_float(u1[j] << 16), accx[j]);
            accy[j] = fmaf(a1, __uint_as_float(u1[j] & 0xffff0000u), accy[j]);
            accx[j] = fmaf(a2, __uint_as_float(u2[j] << 16), accx[j]);
            accy[j] = fmaf(a2, __uint_as_float(u2[j] & 0xffff0000u), accy[j]);
            accx[j] = fmaf(a3, __uint_as_float(u3[j] << 16), accx[j]);
            accy[j] = fmaf(a3, __uint_as_float(u3[j] & 0xffff0000u), accy[j]);
        }
        e += 4;
    }
    for (; e < e1; e++) {
        int p = eidx[e];
        int srcn = p & 0xFFFFFF, et = p >> 24;
        float ev = (lane < 8) ? ew[(size_t)e * 8 + lane] : 0.f;
        den += ev;
        const u32* row = (const u32*)(xr + ((size_t)et * Nn + srcn) * FD);
        #pragma unroll
        for (int j = 0; j < 3; j++) {
            float a = __shfl(ev, hd[j]);
            u32 u = row[lane + 64 * j];
            accx[j] = fmaf(a, __uint_as_float(u << 16), accx[j]);
            accy[j] = fmaf(a, __uint_as_float(u & 0xffff0000u), accy[j]);
        }
    }

    float s1 = 0.f, s2 = 0.f;
    #pragma unroll
    for (int j = 0; j < 3; j++) {
        float dh = __shfl(den, hd[j]);
        float rcp = 1.f / (dh + 1e-16f);
        int c = lane * 2 + 128 * j;
        float2 bv = *(const float2*)(bias + c);
        float2 hv = *(const float2*)(hin + (size_t)node * FD + c);
        float vx = accx[j] * rcp + bv.x;
        float vy = accy[j] * rcp + bv.y;
        vx = (vx > 0.f) ? vx : expm1f(vx);
        vy = (vy > 0.f) ? vy : expm1f(vy);
        vx += hv.x; vy += hv.y;
        *(float2*)(out + (size_t)node * FD + c) = make_float2(vx, vy);
        s1 += vx + vy; s2 += vx * vx + vy * vy;
    }
    #pragma unroll
    for (int o = 32; o; o >>= 1) { s1 += __shfl_down(s1, o); s2 += __shfl_down(s2, o); }
    int g = batch[node];   // wave-uniform
    if (lane == 0) { atomicAdd(&ls[g], s1); atomicAdd(&lq[g], s2); }
    __syncthreads();
    if (t < NG && (ls[t] != 0.f || lq[t] != 0.f)) {
        atomicAdd(&gsum[t], ls[t]);
        atomicAdd(&gsq[t], lq[t]);
    }
}

// graph-LN (stats finalized inline from raw sums) + fused bf16 hi/lo split.
// WF=false skips the fp32 writeback when the fp32 tensor is dead downstream.
template<bool WF>
__global__ __launch_bounds__(256) void gnorm_split_k(float* __restrict__ y,
    const int* __restrict__ batch, const float* __restrict__ gsum, const float* __restrict__ gsq,
    const int* __restrict__ gcnt, const float* __restrict__ w, const float* __restrict__ b,
    u16* __restrict__ hi, u16* __restrict__ lo)
{
    int i = blockIdx.x * 256 + threadIdx.x;   // float4 index
    if (i >= Nn * (FD / 4)) return;
    int n = i / 96, c4 = i - n * 96;
    int g = batch[n];
    float norm = fmaxf((float)gcnt[g], 1.f) * (float)FD;
    float m = gsum[g] / norm;
    float var = gsq[g] / norm - m * m;
    float rstd = rsqrtf(var + EPS);
    float4 wv = ((const float4*)w)[c4];
    float4 bv = ((const float4*)b)[c4];
    float4 v = ((const float4*)y)[i];
    v.x = (v.x - m) * rstd * wv.x + bv.x;
    v.y = (v.y - m) * rstd * wv.y + bv.y;
    v.z = (v.z - m) * rstd * wv.z + bv.z;
    v.w = (v.w - m) * rstd * wv.w + bv.w;
    if (WF) ((float4*)y)[i] = v;
    ushort4 hh, ll;
    hh.x = f2b(v.x); ll.x = f2b(v.x - b2f(hh.x));
    hh.y = f2b(v.y); ll.y = f2b(v.y - b2f(hh.y));
    hh.z = f2b(v.z); ll.z = f2b(v.z - b2f(hh.z));
    hh.w = f2b(v.w); ll.w = f2b(v.w - b2f(hh.w));
    ((ushort4*)hi)[i] = hh;
    ((ushort4*)lo)[i] = ll;
}

__global__ void softmax_prior_k(const float* __restrict__ logits, float* __restrict__ prior)
{
    int n = blockIdx.x * 8 + (threadIdx.x >> 5);
    int l = threadIdx.x & 31;
    if (n >= Nn) return;
    float v = logits[n * 32 + l];
    float m = v;
    #pragma unroll
    for (int o = 16; o; o >>= 1) m = fmaxf(m, __shfl_xor(m, o, 32));
    float e = __expf(v - m);
    float s = e;
    #pragma unroll
    for (int o = 16; o; o >>= 1) s += __shfl_xor(s, o, 32);
    prior[(size_t)n * 33 + l] = e / s;
    if (l == 0) prior[(size_t)n * 33 + 32] = 1.f / s;
}

extern "C" void kernel_launch(void* const* d_in, const int* in_sizes, int n_in,
                              void* d_out, int out_size, void* d_ws, size_t ws_size,
                              hipStream_t stream)
{
    const float* x_visual = (const float*)d_in[0];
    const float* x_geom   = (const float*)d_in[1];
    const float* x_prior  = (const float*)d_in[2];
    const int* ei0   = (const int*)d_in[3];
    const int* ei1   = (const int*)d_in[4];
    const int* ei2   = (const int*)d_in[5];
    const int* batch = (const int*)d_in[6];
    const float* vis_W = (const float*)d_in[7];  const float* vis_b = (const float*)d_in[8];
    const float* vis_lnw = (const float*)d_in[9]; const float* vis_lnb = (const float*)d_in[10];
    const float* geo_W = (const float*)d_in[11]; const float* geo_b = (const float*)d_in[12];
    const float* geo_lnw = (const float*)d_in[13]; const float* geo_lnb = (const float*)d_in[14];
    const float* pri_W = (const float*)d_in[15]; const float* pri_b = (const float*)d_in[16];
    const float* pri_lnw = (const float*)d_in[17]; const float* pri_lnb = (const float*)d_in[18];
    const float* rgat_W[2]    = { (const float*)d_in[19], (const float*)d_in[25] };
    const float* rgat_q[2]    = { (const float*)d_in[20], (const float*)d_in[26] };
    const float* rgat_kk[2]   = { (const float*)d_in[21], (const float*)d_in[27] };
    const float* rgat_bias[2] = { (const float*)d_in[22], (const float*)d_in[28] };
    const float* ln_w[2]      = { (const float*)d_in[23], (const float*)d_in[29] };
    const float* ln_b[2]      = { (const float*)d_in[24], (const float*)d_in[30] };
    const float* cls_W1 = (const float*)d_in[31]; const float* cls_b1 = (const float*)d_in[32];
    const float* cls_W2 = (const float*)d_in[33]; const float* cls_b2 = (const float*)d_in[34];
    float* OUT = (float*)d_out;

    // ---------------- workspace layout ----------------
    float* ws = (float*)d_ws;
    float* XRreg = ws;                         // 3*Nn*FD floats reserved (92.2 MB region)
    u16*   XR16  = (u16*)XRreg;                // XR stored bf16: first 46 MB of the region
    float* HCAT  = XRreg + (size_t)3 * Nn * FD;
    float* HA    = HCAT + (size_t)Nn * FD;
    float* HB    = HA + (size_t)Nn * FD;
    float* PRIOR = HB + (size_t)Nn * FD;       // Nn*33
    float* QIK   = PRIOR + (size_t)Nn * 33;    // 3*Nn*16 (q heads 0-7, k heads 8-15)
    u16* HS0_HI  = (u16*)(QIK + (size_t)3 * Nn * 16);  // HCAT split
    u16* HS0_LO  = HS0_HI + (size_t)Nn * FD;
    u16* HS1_HI  = HS0_LO + (size_t)Nn * FD;          // HA split
    u16* HS1_LO  = HS1_HI + (size_t)Nn * FD;
    u16* RW_HI   = HS1_LO + (size_t)Nn * FD;   // 2*3*384*384
    u16* RW_LO   = RW_HI + (size_t)2 * 3 * 384 * 384;
    u16* VW_HI   = RW_LO + (size_t)2 * 3 * 384 * 384; // 128*1024
    u16* VW_LO   = VW_HI + (size_t)128 * 1024;
    u16* CW_HI   = VW_LO + (size_t)128 * 1024;        // 128*384
    u16* CW_LO   = CW_HI + (size_t)128 * 384;
    u16* QKW_HI  = CW_LO + (size_t)128 * 384;         // 2 layers * 16*384
    u16* QKW_LO  = QKW_HI + (size_t)2 * 16 * 384;
    float* STATS = (float*)(QKW_LO + (size_t)2 * 16 * 384); // 2
    float* GSUM  = STATS + 2;                  // 64
    float* GSQ   = GSUM + 64;
    int* CNT    = (int*)(GSQ + 64);
    int* ROWPTR = CNT + Nn;
    int* CURSOR = ROWPTR + Nn + 1;
    int* EIDX   = CURSOR + Nn;
    int* GCNT   = EIDX + ETOT;
    int* DSTE   = GCNT + 64;                   // ETOT
    float* EW   = (float*)(DSTE + ETOT);       // ETOT*8 floats (5.76 MB)
    // aliases into the XR region (temporally dead sub-ranges):
    u16* VA_HI = (u16*)XRreg;                  // x_visual split [0,82MB): dead after vis gemm
    u16* VA_LO = VA_HI + (size_t)Nn * 1024;
    float* CLSH = XRreg;                       // classifier hidden [0,10.3MB): after last aggr
    u16* HS2_HI = (u16*)(XRreg + (size_t)12 * 1000 * 1000); // HB split [48MB,78.7MB): after last aggr
    u16* HS2_LO = HS2_HI + (size_t)Nn * FD;

    // ---------------- CSR build (reused by all 4 RGAT calls) ----------------
    hipMemsetAsync(CNT, 0, Nn * sizeof(int), stream);
    edge_count_k<<<cdiv(ETOT, 256), 256, 0, stream>>>(ei0, ei1, ei2, CNT);
    scan_k<<<1, 1024, 0, stream>>>(CNT, ROWPTR, CURSOR);
    edge_fill_k<<<cdiv(ETOT, 256), 256, 0, stream>>>(ei0, ei1, ei2, CURSOR, EIDX, DSTE);
    hipMemsetAsync(GCNT, 0, 64 * sizeof(int), stream);
    gcount_k<<<cdiv(Nn, 256), 256, 0, stream>>>(batch, GCNT);

    // ---------------- weight + x_visual conversions ----------------
    tsplit_k<<<cdiv(3 * 384 * 384, 256), 256, 0, stream>>>(rgat_W[0], RW_HI, RW_LO, 384, 384, 3 * 384 * 384);
    tsplit_k<<<cdiv(3 * 384 * 384, 256), 256, 0, stream>>>(rgat_W[1], RW_HI + 3 * 384 * 384, RW_LO + 3 * 384 * 384, 384, 384, 3 * 384 * 384);
    tsplit_k<<<cdiv(1024 * 128, 256), 256, 0, stream>>>(vis_W, VW_HI, VW_LO, 1024, 128, 1024 * 128);
    tsplit_k<<<cdiv(384 * 128, 256), 256, 0, stream>>>(cls_W1, CW_HI, CW_LO, 384, 128, 384 * 128);
    prep_qkw_k<<<cdiv(16 * 384, 256), 256, 0, stream>>>(rgat_q[0], rgat_kk[0], QKW_HI, QKW_LO);
    prep_qkw_k<<<cdiv(16 * 384, 256), 256, 0, stream>>>(rgat_q[1], rgat_kk[1], QKW_HI + 16 * 384, QKW_LO + 16 * 384);
    split_k<<<cdiv(Nn * 1024 / 4, 256), 256, 0, stream>>>(x_visual, VA_HI, VA_LO, Nn * 1024 / 4);

    const int MB = cdiv(Nn, 128);   // 157
    const int XRBLK = 160 * 9;      // padded rows * (3 cols x 3 rels), XCD-swizzled

    // ---------------- vis encoder (MFMA) -> HCAT[:,0:128) ----------------
    hipMemsetAsync(STATS, 0, 2 * sizeof(float), stream);
    mgemm_k<true, true, true, false, 3, false><<<dim3(MB, 1, 1), 256, 0, stream>>>(
        VA_HI, VA_LO, VW_HI, VW_LO, vis_b, HCAT, Nn, 1024, FD, 0, STATS);
    enc_norm_k<<<cdiv(Nn * 32, 256), 256, 0, stream>>>(HCAT, vis_lnw, vis_lnb, STATS, 1.f / ((float)Nn * 128.f), HS0_HI, HS0_LO);

    // ---------------- geo encoder (fp32, K=6) -> HCAT[:,128:256) ----------------
    dim3 genc(cdiv(Nn, 64), 2, 1);
    hipMemsetAsync(STATS, 0, 2 * sizeof(float), stream);
    sgemm_k<true, true, true><<<genc, 256, 0, stream>>>(x_geom, geo_W, geo_b, HCAT + 128, Nn, 6, 128, FD, STATS);
    enc_norm_k<<<cdiv(Nn * 32, 256), 256, 0, stream>>>(HCAT + 128, geo_lnw, geo_lnb, STATS, 1.f / ((float)Nn * 128.f), HS0_HI + 128, HS0_LO + 128);

    for (int t = 0; t < 2; t++) {
        // prior encoder (fp32, K=33) -> HCAT[:,256:384)
        const float* pin = t ? PRIOR : x_prior;
        hipMemsetAsync(STATS, 0, 2 * sizeof(float), stream);
        sgemm_k<true, true, true><<<genc, 256, 0, stream>>>(pin, pri_W, pri_b, HCAT + 256, Nn, 33, 128, FD, STATS);
        enc_norm_k<<<cdiv(Nn * 32, 256), 256, 0, stream>>>(HCAT + 256, pri_lnw, pri_lnb, STATS, 1.f / ((float)Nn * 128.f), HS0_HI + 256, HS0_LO + 256);

        float* hin = HCAT;
        for (int L = 0; L < 2; L++) {
            float* hout = L ? HB : HA;
            const u16* ahi = L ? HS1_HI : HS0_HI;
            const u16* alo = L ? HS1_LO : HS0_LO;
            u16* shi = L ? HS2_HI : HS1_HI;
            u16* slo = L ? HS2_LO : HS1_LO;
            mgemm_k<false, false, false, true, 2, true><<<dim3(XRBLK, 1, 1), 256, 0, stream>>>(
                ahi, alo, RW_HI + (size_t)L * 3 * 384 * 384, RW_LO + (size_t)L * 3 * 384 * 384,
                nullptr, XR16, Nn, 384, FD, 384 * 384, nullptr);
            proj_k<<<cdiv(3 * Nn, 128), 256, 0, stream>>>(XR16,
                QKW_HI + (size_t)L * 16 * 384, QKW_LO + (size_t)L * 16 * 384, QIK);
            ew_k<<<cdiv(ETOT, 256), 256, 0, stream>>>(QIK, EIDX, DSTE, EW);
            hipMemsetAsync(GSUM, 0, 128 * sizeof(float), stream);  // GSUM+GSQ contiguous
            aggr_k<<<cdiv(Nn, 4), 256, 0, stream>>>(XR16, EW, ROWPTR, EIDX, rgat_bias[L],
                                                    hin, batch, hout, GSUM, GSQ);
            if (L == 0)
                gnorm_split_k<true><<<cdiv(Nn * 96, 256), 256, 0, stream>>>(hout, batch, GSUM, GSQ, GCNT, ln_w[L], ln_b[L], shi, slo);
            else
                gnorm_split_k<false><<<cdiv(Nn * 96, 256), 256, 0, stream>>>(hout, batch, GSUM, GSQ, GCNT, ln_w[L], ln_b[L], shi, slo);
            hin = hout;
        }

        // classifier: cls1 (MFMA, reads HS2 split) -> CLSH, cls2 (fp32) -> OUT
        mgemm_k<true, true, false, false, 3, false><<<dim3(MB, 1, 1), 256, 0, stream>>>(
            HS2_HI, HS2_LO, CW_HI, CW_LO, cls_b1, CLSH, Nn, 384, 128, 0, nullptr);
        sgemm_k<true, false, false><<<dim3(cdiv(Nn, 64), 1, 1), 256, 0, stream>>>(
            CLSH, cls_W2, cls_b2, OUT, Nn, 128, 32, 32, nullptr);

        if (t == 0)
            softmax_prior_k<<<cdiv(Nn, 8), 256, 0, stream>>>(OUT, PRIOR);
    }
}

// Round 11
// 803.840 us; speedup vs baseline: 1.7610x; 1.1236x over previous
//
#include <hip/hip_runtime.h>
#include <hip/hip_bf16.h>

#define Nn 20000
#define EREL 60000
#define ETOT 180000
#define NG 64
#define FD 384
#define EPS 1e-5f

typedef unsigned short u16;
typedef unsigned int u32;
typedef __attribute__((ext_vector_type(8))) short s8v;     // 8 bf16 (4 VGPR) MFMA A/B frag
typedef __attribute__((ext_vector_type(4))) float f4v;     // MFMA C/D frag

static inline int cdiv(int a, int b) { return (a + b - 1) / b; }

__device__ inline u16 f2b(float f) {
    __hip_bfloat16 h = __float2bfloat16(f);
    union { __hip_bfloat16 b; u16 u; } c; c.b = h; return c.u;
}
__device__ inline float b2f(u16 u) {
    union { __hip_bfloat16 b; u16 u; } c; c.u = u; return __bfloat162float(c.b);
}

// ---------------- split fp32 -> bf16 hi/lo (vectorized by float4) ----------------
__global__ __launch_bounds__(256) void split_k(const float* __restrict__ x,
    u16* __restrict__ hi, u16* __restrict__ lo, int n4)
{
    int i = blockIdx.x * 256 + threadIdx.x;
    if (i >= n4) return;
    float4 v = ((const float4*)x)[i];
    ushort4 h, l;
    h.x = f2b(v.x); l.x = f2b(v.x - b2f(h.x));
    h.y = f2b(v.y); l.y = f2b(v.y - b2f(h.y));
    h.z = f2b(v.z); l.z = f2b(v.z - b2f(h.z));
    h.w = f2b(v.w); l.w = f2b(v.w - b2f(h.w));
    ((ushort4*)hi)[i] = h;
    ((ushort4*)lo)[i] = l;
}

// transpose + split: W[b][K][N] -> T[b][N][K] hi/lo
__global__ void tsplit_k(const float* __restrict__ W, u16* __restrict__ hi,
                         u16* __restrict__ lo, int K, int N, int total)
{
    int idx = blockIdx.x * 256 + threadIdx.x;
    if (idx >= total) return;
    int kn = K * N;
    int b = idx / kn, rem = idx - b * kn;
    int k = rem / N, n = rem - k * N;
    float v = W[idx];
    u16 h = f2b(v), l = f2b(v - b2f(h));
    int o = b * kn + n * K + k;
    hi[o] = h; lo[o] = l;
}

// pack q (384x8) and k (384x8) into QKW[16][384] hi/lo: col<8 = q head, col>=8 = k head
__global__ void prep_qkw_k(const float* __restrict__ q, const float* __restrict__ kk,
                           u16* __restrict__ hi, u16* __restrict__ lo)
{
    int idx = blockIdx.x * 256 + threadIdx.x;
    if (idx >= 16 * 384) return;
    int col = idx / 384, k = idx - col * 384;
    float v = (col < 8) ? q[k * 8 + col] : kk[k * 8 + col - 8];
    u16 h = f2b(v), l = f2b(v - b2f(h));
    hi[idx] = h; lo[idx] = l;
}

// ---------------- split-bf16 MFMA GEMM ----------------
// C[M,N] = A[M,K] @ B[N,K]^T, A,B bf16 (hi,lo) pairs row-major ld=K. 128x128 tile,
// 4 waves of 64x64, 16x16x32 MFMA.
// TERMS=1: ah*bh (pure bf16 — for bf16-stored outputs). TERMS=2: + al*bh.
// TERMS=3: + ah*bl (~fp32). SWZ: XCD-aware grid for the XR shape.
#define USEI(i) ((i) < 2 || ((i) >= 4 && (i) < 6) || (TERMS >= 2 && ((i) == 2 || (i) == 3)) || (TERMS >= 3 && (i) >= 6))
template<bool BIAS, bool RELU, bool STATS, bool OB16, int TERMS, bool SWZ>
__global__ __launch_bounds__(256) void mgemm_k(
    const u16* __restrict__ Ahi, const u16* __restrict__ Alo,
    const u16* __restrict__ Bhi, const u16* __restrict__ Blo,
    const float* __restrict__ bias, void* __restrict__ Cv,
    int M, int K, int ldc, int bstride, float* __restrict__ stats)
{
    __shared__ u16 lds[4 * 128 * 32];   // Ahi | Alo | Bhi | Blo tiles, [128][32] each
    __shared__ float red[256];
    const int t = threadIdx.x;
    int brow, bcol, z;
    if (SWZ) {
        int d = blockIdx.x;
        int xcd = d & 7, s = d >> 3;
        int row = xcd + 8 * (s / 9);
        int c = s % 9;
        brow = row * 128;
        if (brow >= M) return;
        bcol = (c % 3) * 128;
        z = c / 3;
    } else {
        brow = blockIdx.x * 128; bcol = blockIdx.y * 128; z = blockIdx.z;
    }
    Bhi += (size_t)z * bstride;
    Blo += (size_t)z * bstride;
    float* Cf = OB16 ? nullptr : (float*)Cv + (size_t)z * M * ldc;
    u16*   Ch = OB16 ? (u16*)Cv + (size_t)z * M * ldc : nullptr;

    const int r0 = t >> 2, sl = t & 3;
    const int rA0 = min(brow + r0, M - 1);
    const int rA1 = min(brow + r0 + 64, M - 1);
    const u16* gsrc[8];
    gsrc[0] = Ahi + (size_t)rA0 * K + sl * 8;
    gsrc[1] = Ahi + (size_t)rA1 * K + sl * 8;
    gsrc[2] = Alo + (size_t)rA0 * K + sl * 8;
    gsrc[3] = Alo + (size_t)rA1 * K + sl * 8;
    gsrc[4] = Bhi + (size_t)(bcol + r0) * K + sl * 8;
    gsrc[5] = Bhi + (size_t)(bcol + r0 + 64) * K + sl * 8;
    gsrc[6] = Blo + (size_t)(bcol + r0) * K + sl * 8;
    gsrc[7] = Blo + (size_t)(bcol + r0 + 64) * K + sl * 8;
    const int swz = (sl ^ (r0 & 3)) << 3;
    int ldst[8];
    #pragma unroll
    for (int i = 0; i < 8; i++) {
        int tile = i >> 1, row = r0 + 64 * (i & 1);
        ldst[i] = tile * 4096 + row * 32 + swz;
    }

    const int l = t & 63, w = t >> 6;
    const int wr = (w >> 1) * 64, wc = (w & 1) * 64;
    const int lr = l & 15, kq = l >> 4;

    f4v acc[4][4] = {};
    const int NK = K >> 5;

    s8v stg[8];
    #pragma unroll
    for (int i = 0; i < 8; i++) if (USEI(i)) stg[i] = *(const s8v*)gsrc[i];

    for (int kc = 0; kc < NK; kc++) {
        if (kc) __syncthreads();
        #pragma unroll
        for (int i = 0; i < 8; i++) if (USEI(i)) *(s8v*)(lds + ldst[i]) = stg[i];
        __syncthreads();
        if (kc + 1 < NK) {
            const int ko = (kc + 1) * 32;
            #pragma unroll
            for (int i = 0; i < 8; i++) if (USEI(i)) stg[i] = *(const s8v*)(gsrc[i] + ko);
        }
        #define LDR(T, row) (*(const s8v*)(lds + (T) * 4096 + (row) * 32 + ((kq ^ ((row) & 3)) << 3)))
        s8v bh[4], bl[4];
        #pragma unroll
        for (int tn = 0; tn < 4; tn++) {
            int rb = wc + tn * 16 + lr;
            bh[tn] = LDR(2, rb);
            if (TERMS >= 3) bl[tn] = LDR(3, rb);
        }
        #pragma unroll
        for (int tm = 0; tm < 4; tm++) {
            int ra = wr + tm * 16 + lr;
            s8v ah = LDR(0, ra);
            s8v al;
            if (TERMS >= 2) al = LDR(1, ra);
            #pragma unroll
            for (int tn = 0; tn < 4; tn++) {
                acc[tm][tn] = __builtin_amdgcn_mfma_f32_16x16x32_bf16(ah, bh[tn], acc[tm][tn], 0, 0, 0);
                if (TERMS >= 2)
                    acc[tm][tn] = __builtin_amdgcn_mfma_f32_16x16x32_bf16(al, bh[tn], acc[tm][tn], 0, 0, 0);
                if (TERMS >= 3)
                    acc[tm][tn] = __builtin_amdgcn_mfma_f32_16x16x32_bf16(ah, bl[tn], acc[tm][tn], 0, 0, 0);
            }
        }
        #undef LDR
    }

    float s1 = 0.f, s2 = 0.f;
    #pragma unroll
    for (int tm = 0; tm < 4; tm++) {
        #pragma unroll
        for (int rg = 0; rg < 4; rg++) {
            int row = brow + wr + tm * 16 + kq * 4 + rg;
            if (row < M) {
                #pragma unroll
                for (int tn = 0; tn < 4; tn++) {
                    int col = bcol + wc + tn * 16 + lr;
                    float v = acc[tm][tn][rg];
                    if (BIAS) v += bias[col];
                    if (RELU) v = fmaxf(v, 0.f);
                    if (OB16) Ch[(size_t)row * ldc + col] = f2b(v);
                    else      Cf[(size_t)row * ldc + col] = v;
                    if (STATS) { s1 += v; s2 += v * v; }
                }
            }
        }
    }
    if (STATS) {
        __syncthreads();
        red[t] = s1; __syncthreads();
        for (int o = 128; o; o >>= 1) { if (t < o) red[t] += red[t + o]; __syncthreads(); }
        if (t == 0) atomicAdd(&stats[0], red[0]);
        __syncthreads();
        red[t] = s2; __syncthreads();
        for (int o = 128; o; o >>= 1) { if (t < o) red[t] += red[t + o]; __syncthreads(); }
        if (t == 0) atomicAdd(&stats[1], red[0]);
    }
}
#undef USEI

// ---------------- proj GEMM: QIK[3Nn,16] = XR[3Nn,384] @ QKW[16,384]^T ----------------
__global__ __launch_bounds__(256) void proj_k(const u16* __restrict__ xr,
    const u16* __restrict__ qkw_hi, const u16* __restrict__ qkw_lo,
    float* __restrict__ qik)
{
    const int M3 = 3 * Nn;
    __shared__ u16 a_lds[128 * 32];
    __shared__ u16 b_lds[2][16 * 392];
    int t = threadIdx.x;
    int brow = blockIdx.x * 128;

    for (int i = t; i < 768; i += 256) {
        int col = i / 48, c8 = (i - col * 48) * 8;
        *(s8v*)&b_lds[0][col * 392 + c8] = *(const s8v*)(qkw_hi + col * 384 + c8);
        *(s8v*)&b_lds[1][col * 392 + c8] = *(const s8v*)(qkw_lo + col * 384 + c8);
    }

    int ar = t >> 1;
    int sl0 = (t & 1) * 2;
    int grow = min(brow + ar, M3 - 1);
    const u16* asrc = xr + (size_t)grow * 384;
    int adst0 = ar * 32 + ((sl0 ^ (ar & 3)) << 3);
    int adst1 = ar * 32 + (((sl0 + 1) ^ (ar & 3)) << 3);

    int l = t & 63, w = t >> 6;
    int lr = l & 15, kq = l >> 4;
    f4v acc0 = {}, acc1 = {};

    s8v stg0 = *(const s8v*)(asrc + sl0 * 8);
    s8v stg1 = *(const s8v*)(asrc + sl0 * 8 + 8);
    for (int kc = 0; kc < 12; kc++) {
        if (kc) __syncthreads();
        *(s8v*)&a_lds[adst0] = stg0;
        *(s8v*)&a_lds[adst1] = stg1;
        __syncthreads();
        if (kc + 1 < 12) {
            int ko = (kc + 1) * 32 + sl0 * 8;
            stg0 = *(const s8v*)(asrc + ko);
            stg1 = *(const s8v*)(asrc + ko + 8);
        }
        s8v bh = *(const s8v*)&b_lds[0][lr * 392 + kc * 32 + kq * 8];
        s8v bl = *(const s8v*)&b_lds[1][lr * 392 + kc * 32 + kq * 8];
        int r0 = w * 32 + lr;
        s8v a0 = *(const s8v*)&a_lds[r0 * 32 + ((kq ^ (r0 & 3)) << 3)];
        int r1 = r0 + 16;
        s8v a1 = *(const s8v*)&a_lds[r1 * 32 + ((kq ^ (r1 & 3)) << 3)];
        acc0 = __builtin_amdgcn_mfma_f32_16x16x32_bf16(a0, bh, acc0, 0, 0, 0);
        acc0 = __builtin_amdgcn_mfma_f32_16x16x32_bf16(a0, bl, acc0, 0, 0, 0);
        acc1 = __builtin_amdgcn_mfma_f32_16x16x32_bf16(a1, bh, acc1, 0, 0, 0);
        acc1 = __builtin_amdgcn_mfma_f32_16x16x32_bf16(a1, bl, acc1, 0, 0, 0);
    }
    #pragma unroll
    for (int rg = 0; rg < 4; rg++) {
        int row0 = brow + w * 32 + kq * 4 + rg;
        if (row0 < M3) qik[(size_t)row0 * 16 + lr] = acc0[rg];
        int row1 = row0 + 16;
        if (row1 < M3) qik[(size_t)row1 * 16 + lr] = acc1[rg];
    }
}

// ---------------- fp32 tiled GEMM (tiny-K shapes: geo K=6, pri K=33, cls2) ----------------
template<bool BIAS, bool RELU, bool STATS>
__global__ __launch_bounds__(256) void sgemm_k(
    const float* __restrict__ A, const float* __restrict__ B,
    const float* __restrict__ bias, float* __restrict__ C,
    int M, int K, int N, int ldc, float* __restrict__ stats)
{
    const int BK = 16;
    const int r = blockIdx.z;
    B += (size_t)r * K * N;
    C += (size_t)r * M * ldc;
    __shared__ float As[16][65];
    __shared__ float Bs[16][64];
    int tid = threadIdx.x;
    int tx = tid & 15, ty = tid >> 4;
    int brow = blockIdx.x * 64, bcol = blockIdx.y * 64;
    float acc[4][4] = {};
    for (int k0 = 0; k0 < K; k0 += BK) {
        #pragma unroll
        for (int i = 0; i < 4; i++) {
            int e = tid + 256 * i;
            int ar = e >> 4, ak = e & 15;
            int gr = brow + ar, gk = k0 + ak;
            As[ak][ar] = (gr < M && gk < K) ? A[(size_t)gr * K + gk] : 0.f;
            int bk = e >> 6, bn = e & 63;
            int gbk = k0 + bk, gbn = bcol + bn;
            Bs[bk][bn] = (gbk < K && gbn < N) ? B[(size_t)gbk * N + gbn] : 0.f;
        }
        __syncthreads();
        #pragma unroll
        for (int k = 0; k < BK; k++) {
            float ra[4], rb[4];
            #pragma unroll
            for (int i = 0; i < 4; i++) ra[i] = As[k][ty * 4 + i];
            #pragma unroll
            for (int j = 0; j < 4; j++) rb[j] = Bs[k][tx * 4 + j];
            #pragma unroll
            for (int i = 0; i < 4; i++)
                #pragma unroll
                for (int j = 0; j < 4; j++)
                    acc[i][j] = fmaf(ra[i], rb[j], acc[i][j]);
        }
        __syncthreads();
    }
    float s1 = 0.f, s2 = 0.f;
    #pragma unroll
    for (int i = 0; i < 4; i++) {
        int row = brow + ty * 4 + i;
        #pragma unroll
        for (int j = 0; j < 4; j++) {
            int col = bcol + tx * 4 + j;
            if (row < M && col < N) {
                float v = acc[i][j];
                if (BIAS) v += bias[col];
                if (RELU) v = v > 0.f ? v : 0.f;
                C[(size_t)row * ldc + col] = v;
                if (STATS) { s1 += v; s2 += v * v; }
            }
        }
    }
    if (STATS) {
        __shared__ float red[256];
        __syncthreads();
        red[tid] = s1; __syncthreads();
        for (int o = 128; o; o >>= 1) { if (tid < o) red[tid] += red[tid + o]; __syncthreads(); }
        if (tid == 0) atomicAdd(&stats[0], red[0]);
        __syncthreads();
        red[tid] = s2; __syncthreads();
        for (int o = 128; o; o >>= 1) { if (tid < o) red[tid] += red[tid + o]; __syncthreads(); }
        if (tid == 0) atomicAdd(&stats[1], red[0]);
    }
}

// scalar-LN of a 128-col block of H (pre-offset, fp32 pre-norm) from RAW sums.
// Writes ONLY the bf16 normalized values into hi (pre-offset) — no fp32 writeback, no lo.
__global__ __launch_bounds__(256) void enc_norm_k(const float* __restrict__ H,
                           const float* __restrict__ w, const float* __restrict__ b,
                           const float* __restrict__ stats, float cntinv, u16* __restrict__ hi)
{
    int i = blockIdx.x * 256 + threadIdx.x;   // float4 index within the 128-col block
    if (i >= Nn * 32) return;
    int n = i >> 5, c4 = i & 31;
    float m = stats[0] * cntinv;
    float var = stats[1] * cntinv - m * m;
    float s = 1.f / (sqrtf(fmaxf(var, 0.f)) + EPS);
    float4 wv = ((const float4*)w)[c4];
    float4 bv = ((const float4*)b)[c4];
    float4 v = ((const float4*)(H + (size_t)n * FD))[c4];
    ushort4 hh;
    hh.x = f2b((v.x - m) * s * wv.x + bv.x);
    hh.y = f2b((v.y - m) * s * wv.y + bv.y);
    hh.z = f2b((v.z - m) * s * wv.z + bv.z);
    hh.w = f2b((v.w - m) * s * wv.w + bv.w);
    ((ushort4*)(hi + (size_t)n * FD))[c4] = hh;
}

// per-edge unnormalized attention weights from fused QIK[row][16] (q: 0-7, k: 8-15)
__global__ __launch_bounds__(256) void ew_k(const float* __restrict__ qik,
    const int* __restrict__ eidx, const int* __restrict__ dste, float* __restrict__ ew)
{
    int e = blockIdx.x * 256 + threadIdx.x;
    if (e >= ETOT) return;
    int p = eidx[e];
    int src = p & 0xFFFFFF, et = p >> 24;
    int dst = dste[e];
    const float4* q4 = (const float4*)(qik + ((size_t)et * Nn + dst) * 16);
    const float4* k4 = (const float4*)(qik + ((size_t)et * Nn + src) * 16 + 8);
    float4 out[2];
    #pragma unroll
    for (int half = 0; half < 2; half++) {
        float4 qv = q4[half], kv = k4[half];
        float a0 = qv.x + kv.x, a1 = qv.y + kv.y, a2 = qv.z + kv.z, a3 = qv.w + kv.w;
        a0 = (a0 > 0.f) ? a0 : 0.2f * a0;
        a1 = (a1 > 0.f) ? a1 : 0.2f * a1;
        a2 = (a2 > 0.f) ? a2 : 0.2f * a2;
        a3 = (a3 > 0.f) ? a3 : 0.2f * a3;
        out[half] = make_float4(__expf(a0), __expf(a1), __expf(a2), __expf(a3));
    }
    float4* ew4 = (float4*)(ew + (size_t)e * 8);
    ew4[0] = out[0];
    ew4[1] = out[1];
}

__global__ void edge_count_k(const int* __restrict__ e0, const int* __restrict__ e1,
                             const int* __restrict__ e2, int* __restrict__ cnt)
{
    int e = blockIdx.x * 256 + threadIdx.x;
    if (e >= ETOT) return;
    int r = e / EREL, i = e - r * EREL;
    const int* ei = (r == 0) ? e0 : (r == 1) ? e1 : e2;
    atomicAdd(&cnt[ei[EREL + i]], 1);
}

__global__ void edge_fill_k(const int* __restrict__ e0, const int* __restrict__ e1,
                            const int* __restrict__ e2, int* __restrict__ cursor,
                            int* __restrict__ eidx, int* __restrict__ dste)
{
    int e = blockIdx.x * 256 + threadIdx.x;
    if (e >= ETOT) return;
    int r = e / EREL, i = e - r * EREL;
    const int* ei = (r == 0) ? e0 : (r == 1) ? e1 : e2;
    int src = ei[i], dst = ei[EREL + i];
    int pos = atomicAdd(&cursor[dst], 1);
    eidx[pos] = src | (r << 24);
    dste[pos] = dst;
}

// exclusive scan via per-wave shuffle scan + 16-wave LDS combine (3 barriers/chunk)
__global__ __launch_bounds__(1024) void scan_k(const int* __restrict__ cnt,
                                               int* __restrict__ rowptr, int* __restrict__ cursor)
{
    __shared__ int wsum[16], wpre[16];
    __shared__ int carry, tot;
    int t = threadIdx.x, lane = t & 63, wid = t >> 6;
    if (t == 0) carry = 0;
    __syncthreads();
    for (int base = 0; base < Nn; base += 1024) {
        int i = base + t;
        int v = (i < Nn) ? cnt[i] : 0;
        int s = v;
        #pragma unroll
        for (int o = 1; o < 64; o <<= 1) {
            int x = __shfl_up(s, o);
            if (lane >= o) s += x;
        }
        if (lane == 63) wsum[wid] = s;
        __syncthreads();
        if (t < 16) {
            int wv = wsum[t];
            int ws = wv;
            #pragma unroll
            for (int o = 1; o < 16; o <<= 1) {
                int x = __shfl_up(ws, o);
                if (t >= o) ws += x;
            }
            wpre[t] = ws - wv;
            if (t == 15) tot = ws;
        }
        __syncthreads();
        if (i < Nn) {
            int ex = carry + wpre[wid] + s - v;
            rowptr[i] = ex; cursor[i] = ex;
        }
        __syncthreads();
        if (t == 0) carry += tot;
    }
    __syncthreads();
    if (t == 0) rowptr[Nn] = carry;
}

// per-graph node counts via LDS histogram: 1 global atomic per (block, graph)
__global__ __launch_bounds__(256) void gcount_k(const int* __restrict__ batch, int* __restrict__ gcnt)
{
    __shared__ int bins[NG];
    int t = threadIdx.x;
    if (t < NG) bins[t] = 0;
    __syncthreads();
    int n = blockIdx.x * 256 + t;
    if (n < Nn) atomicAdd(&bins[batch[n]], 1);
    __syncthreads();
    if (t < NG && bins[t]) atomicAdd(&gcnt[t], bins[t]);
}

// RGAT aggregation from precomputed EW. One wave per dst node, single pass, 4x edge
// unroll. hin (residual) is bf16 (the normalized prev-layer values); out written bf16.
// Fused elu/residual/per-graph-stats.
__global__ __launch_bounds__(256) void aggr_k(const u16* __restrict__ xr,
    const float* __restrict__ ew, const int* __restrict__ rowptr, const int* __restrict__ eidx,
    const float* __restrict__ bias, const u16* __restrict__ hinb,
    const int* __restrict__ batch, u16* __restrict__ outb,
    float* __restrict__ gsum, float* __restrict__ gsq)
{
    __shared__ float ls[NG], lq[NG];
    int t = threadIdx.x;
    if (t < NG) { ls[t] = 0.f; lq[t] = 0.f; }
    __syncthreads();
    int node = blockIdx.x * 4 + (t >> 6);
    int lane = t & 63;
    int e0 = rowptr[node], e1 = rowptr[node + 1];
    int hd[3];
    #pragma unroll
    for (int j = 0; j < 3; j++) hd[j] = (lane * 2 + 128 * j) / 48;  // c,c+1 same head (c even)
    float den = 0.f;                 // lane h < 8 accumulates head h
    float accx[3] = {}, accy[3] = {};

    int e = e0;
    while (e + 4 <= e1) {
        int p0 = eidx[e], p1 = eidx[e + 1], p2 = eidx[e + 2], p3 = eidx[e + 3];
        const u32* r0 = (const u32*)(xr + ((size_t)(p0 >> 24) * Nn + (p0 & 0xFFFFFF)) * FD);
        const u32* r1 = (const u32*)(xr + ((size_t)(p1 >> 24) * Nn + (p1 & 0xFFFFFF)) * FD);
        const u32* r2 = (const u32*)(xr + ((size_t)(p2 >> 24) * Nn + (p2 & 0xFFFFFF)) * FD);
        const u32* r3 = (const u32*)(xr + ((size_t)(p3 >> 24) * Nn + (p3 & 0xFFFFFF)) * FD);
        float ev0 = (lane < 8) ? ew[(size_t)e * 8 + lane] : 0.f;
        float ev1 = (lane < 8) ? ew[(size_t)(e + 1) * 8 + lane] : 0.f;
        float ev2 = (lane < 8) ? ew[(size_t)(e + 2) * 8 + lane] : 0.f;
        float ev3 = (lane < 8) ? ew[(size_t)(e + 3) * 8 + lane] : 0.f;
        u32 u0[3], u1[3], u2[3], u3[3];
        #pragma unroll
        for (int j = 0; j < 3; j++) u0[j] = r0[lane + 64 * j];
        #pragma unroll
        for (int j = 0; j < 3; j++) u1[j] = r1[lane + 64 * j];
        #pragma unroll
        for (int j = 0; j < 3; j++) u2[j] = r2[lane + 64 * j];
        #pragma unroll
        for (int j = 0; j < 3; j++) u3[j] = r3[lane + 64 * j];
        den += ev0 + ev1 + ev2 + ev3;
        #pragma unroll
        for (int j = 0; j < 3; j++) {
            float a0 = __shfl(ev0, hd[j]), a1 = __shfl(ev1, hd[j]);
            float a2 = __shfl(ev2, hd[j]), a3 = __shfl(ev3, hd[j]);
            accx[j] = fmaf(a0, __uint_as_float(u0[j] << 16), accx[j]);
            accy[j] = fmaf(a0, __uint_as_float(u0[j] & 0xffff0000u), accy[j]);
            accx[j] = fmaf(a1, __uint_as_float(u1[j] << 16), accx[j]);
            accy[j] = fmaf(a1, __uint_as_float(u1[j] & 0xffff0000u), accy[j]);
            accx[j] = fmaf(a2, __uint_as_float(u2[j] << 16), accx[j]);
            accy[j] = fmaf(a2, __uint_as_float(u2[j] & 0xffff0000u), accy[j]);
            accx[j] = fmaf(a3, __uint_as_float(u3[j] << 16), accx[j]);
            accy[j] = fmaf(a3, __uint_as_float(u3[j] & 0xffff0000u), accy[j]);
        }
        e += 4;
    }
    for (; e < e1; e++) {
        int p = eidx[e];
        int srcn = p & 0xFFFFFF, et = p >> 24;
        float ev = (lane < 8) ? ew[(size_t)e * 8 + lane] : 0.f;
        den += ev;
        const u32* row = (const u32*)(xr + ((size_t)et * Nn + srcn) * FD);
        #pragma unroll
        for (int j = 0; j < 3; j++) {
            float a = __shfl(ev, hd[j]);
            u32 u = row[lane + 64 * j];
            accx[j] = fmaf(a, __uint_as_float(u << 16), accx[j]);
            accy[j] = fmaf(a, __uint_as_float(u & 0xffff0000u), accy[j]);
        }
    }

    float s1 = 0.f, s2 = 0.f;
    #pragma unroll
    for (int j = 0; j < 3; j++) {
        float dh = __shfl(den, hd[j]);
        float rcp = 1.f / (dh + 1e-16f);
        int c = lane * 2 + 128 * j;
        float2 bv = *(const float2*)(bias + c);
        u32 hb = ((const u32*)(hinb + (size_t)node * FD))[lane + 64 * j];
        float vx = accx[j] * rcp + bv.x;
        float vy = accy[j] * rcp + bv.y;
        vx = (vx > 0.f) ? vx : expm1f(vx);
        vy = (vy > 0.f) ? vy : expm1f(vy);
        vx += b2f((u16)(hb & 0xffffu));
        vy += b2f((u16)(hb >> 16));
        u32 pb = (u32)f2b(vx) | ((u32)f2b(vy) << 16);
        ((u32*)(outb + (size_t)node * FD))[lane + 64 * j] = pb;
        s1 += vx + vy; s2 += vx * vx + vy * vy;
    }
    #pragma unroll
    for (int o = 32; o; o >>= 1) { s1 += __shfl_down(s1, o); s2 += __shfl_down(s2, o); }
    int g = batch[node];   // wave-uniform
    if (lane == 0) { atomicAdd(&ls[g], s1); atomicAdd(&lq[g], s2); }
    __syncthreads();
    if (t < NG && (ls[t] != 0.f || lq[t] != 0.f)) {
        atomicAdd(&gsum[t], ls[t]);
        atomicAdd(&gsq[t], lq[t]);
    }
}

// graph-LN from raw sums, bf16 input. Writes hi (= bf16 normalized, doubles as next
// layer's residual input) and optionally lo (only needed by the TERMS=3 cls1 GEMM).
template<bool WLO>
__global__ __launch_bounds__(256) void gnorm_split_k(const u16* __restrict__ yb,
    const int* __restrict__ batch, const float* __restrict__ gsum, const float* __restrict__ gsq,
    const int* __restrict__ gcnt, const float* __restrict__ w, const float* __restrict__ b,
    u16* __restrict__ hi, u16* __restrict__ lo)
{
    int i = blockIdx.x * 256 + threadIdx.x;   // 4-element group index
    if (i >= Nn * (FD / 4)) return;
    int n = i / 96;
    int c4 = i - n * 96;
    int g = batch[n];
    float norm = fmaxf((float)gcnt[g], 1.f) * (float)FD;
    float m = gsum[g] / norm;
    float var = gsq[g] / norm - m * m;
    float rstd = rsqrtf(var + EPS);
    float4 wv = ((const float4*)w)[c4];
    float4 bv = ((const float4*)b)[c4];
    uint2 yv = ((const uint2*)yb)[i];
    float v0 = (b2f((u16)(yv.x & 0xffffu)) - m) * rstd * wv.x + bv.x;
    float v1 = (b2f((u16)(yv.x >> 16))     - m) * rstd * wv.y + bv.y;
    float v2 = (b2f((u16)(yv.y & 0xffffu)) - m) * rstd * wv.z + bv.z;
    float v3 = (b2f((u16)(yv.y >> 16))     - m) * rstd * wv.w + bv.w;
    ushort4 hh;
    hh.x = f2b(v0); hh.y = f2b(v1); hh.z = f2b(v2); hh.w = f2b(v3);
    ((ushort4*)hi)[i] = hh;
    if (WLO) {
        ushort4 ll;
        ll.x = f2b(v0 - b2f(hh.x));
        ll.y = f2b(v1 - b2f(hh.y));
        ll.z = f2b(v2 - b2f(hh.z));
        ll.w = f2b(v3 - b2f(hh.w));
        ((ushort4*)lo)[i] = ll;
    }
}

__global__ void softmax_prior_k(const float* __restrict__ logits, float* __restrict__ prior)
{
    int n = blockIdx.x * 8 + (threadIdx.x >> 5);
    int l = threadIdx.x & 31;
    if (n >= Nn) return;
    float v = logits[n * 32 + l];
    float m = v;
    #pragma unroll
    for (int o = 16; o; o >>= 1) m = fmaxf(m, __shfl_xor(m, o, 32));
    float e = __expf(v - m);
    float s = e;
    #pragma unroll
    for (int o = 16; o; o >>= 1) s += __shfl_xor(s, o, 32);
    prior[(size_t)n * 33 + l] = e / s;
    if (l == 0) prior[(size_t)n * 33 + 32] = 1.f / s;
}

extern "C" void kernel_launch(void* const* d_in, const int* in_sizes, int n_in,
                              void* d_out, int out_size, void* d_ws, size_t ws_size,
                              hipStream_t stream)
{
    const float* x_visual = (const float*)d_in[0];
    const float* x_geom   = (const float*)d_in[1];
    const float* x_prior  = (const float*)d_in[2];
    const int* ei0   = (const int*)d_in[3];
    const int* ei1   = (const int*)d_in[4];
    const int* ei2   = (const int*)d_in[5];
    const int* batch = (const int*)d_in[6];
    const float* vis_W = (const float*)d_in[7];  const float* vis_b = (const float*)d_in[8];
    const float* vis_lnw = (const float*)d_in[9]; const float* vis_lnb = (const float*)d_in[10];
    const float* geo_W = (const float*)d_in[11]; const float* geo_b = (const float*)d_in[12];
    const float* geo_lnw = (const float*)d_in[13]; const float* geo_lnb = (const float*)d_in[14];
    const float* pri_W = (const float*)d_in[15]; const float* pri_b = (const float*)d_in[16];
    const float* pri_lnw = (const float*)d_in[17]; const float* pri_lnb = (const float*)d_in[18];
    const float* rgat_W[2]    = { (const float*)d_in[19], (const float*)d_in[25] };
    const float* rgat_q[2]    = { (const float*)d_in[20], (const float*)d_in[26] };
    const float* rgat_kk[2]   = { (const float*)d_in[21], (const float*)d_in[27] };
    const float* rgat_bias[2] = { (const float*)d_in[22], (const float*)d_in[28] };
    const float* ln_w[2]      = { (const float*)d_in[23], (const float*)d_in[29] };
    const float* ln_b[2]      = { (const float*)d_in[24], (const float*)d_in[30] };
    const float* cls_W1 = (const float*)d_in[31]; const float* cls_b1 = (const float*)d_in[32];
    const float* cls_W2 = (const float*)d_in[33]; const float* cls_b2 = (const float*)d_in[34];
    float* OUT = (float*)d_out;

    // ---------------- workspace layout ----------------
    float* ws = (float*)d_ws;
    float* XRreg = ws;                         // 3*Nn*FD floats reserved (92.2 MB region)
    u16*   XR16  = (u16*)XRreg;                // XR stored bf16: first 46 MB of the region
    float* HCAT  = XRreg + (size_t)3 * Nn * FD; // fp32 pre-norm encoder outputs
    float* HA    = HCAT + (size_t)Nn * FD;
    float* HB    = HA + (size_t)Nn * FD;
    float* PRIOR = HB + (size_t)Nn * FD;       // Nn*33
    float* QIK   = PRIOR + (size_t)Nn * 33;    // 3*Nn*16 (q heads 0-7, k heads 8-15)
    u16* HS0_HI  = (u16*)(QIK + (size_t)3 * Nn * 16);  // normalized HCAT (bf16)
    u16* HS0_LO  = HS0_HI + (size_t)Nn * FD;           // (dead — kept for layout)
    u16* HS1_HI  = HS0_LO + (size_t)Nn * FD;           // normalized layer-0 out (bf16)
    u16* HS1_LO  = HS1_HI + (size_t)Nn * FD;           // (dead)
    u16* RW_HI   = HS1_LO + (size_t)Nn * FD;   // 2*3*384*384
    u16* RW_LO   = RW_HI + (size_t)2 * 3 * 384 * 384;  // (dead for XR TERMS=1)
    u16* VW_HI   = RW_LO + (size_t)2 * 3 * 384 * 384; // 128*1024
    u16* VW_LO   = VW_HI + (size_t)128 * 1024;        // (dead for vis TERMS=2)
    u16* CW_HI   = VW_LO + (size_t)128 * 1024;        // 128*384
    u16* CW_LO   = CW_HI + (size_t)128 * 384;
    u16* QKW_HI  = CW_LO + (size_t)128 * 384;         // 2 layers * 16*384
    u16* QKW_LO  = QKW_HI + (size_t)2 * 16 * 384;
    float* STATS = (float*)(QKW_LO + (size_t)2 * 16 * 384); // 2
    float* GSUM  = STATS + 2;                  // 64
    float* GSQ   = GSUM + 64;
    int* CNT    = (int*)(GSQ + 64);
    int* ROWPTR = CNT + Nn;
    int* CURSOR = ROWPTR + Nn + 1;
    int* EIDX   = CURSOR + Nn;
    int* GCNT   = EIDX + ETOT;
    int* DSTE   = GCNT + 64;                   // ETOT
    float* EW   = (float*)(DSTE + ETOT);       // ETOT*8 floats (5.76 MB)
    // aliases (temporally dead sub-ranges):
    u16* VA_HI = (u16*)XRreg;                  // x_visual split [0,82MB): dead after vis gemm
    u16* VA_LO = VA_HI + (size_t)Nn * 1024;
    float* CLSH = XRreg;                       // classifier hidden [0,10.3MB): after last aggr
    u16* HS2_HI = (u16*)(XRreg + (size_t)12 * 1000 * 1000); // HB split [48MB,78.7MB)
    u16* HS2_LO = HS2_HI + (size_t)Nn * FD;
    u16* YB0 = (u16*)HA;                       // aggr L=0 out (bf16 pre-norm)
    u16* YB1 = (u16*)HB;                       // aggr L=1 out (bf16 pre-norm)

    // ---------------- CSR build (reused by all 4 RGAT calls) ----------------
    hipMemsetAsync(CNT, 0, Nn * sizeof(int), stream);
    edge_count_k<<<cdiv(ETOT, 256), 256, 0, stream>>>(ei0, ei1, ei2, CNT);
    scan_k<<<1, 1024, 0, stream>>>(CNT, ROWPTR, CURSOR);
    edge_fill_k<<<cdiv(ETOT, 256), 256, 0, stream>>>(ei0, ei1, ei2, CURSOR, EIDX, DSTE);
    hipMemsetAsync(GCNT, 0, 64 * sizeof(int), stream);
    gcount_k<<<cdiv(Nn, 256), 256, 0, stream>>>(batch, GCNT);

    // ---------------- weight + x_visual conversions ----------------
    tsplit_k<<<cdiv(3 * 384 * 384, 256), 256, 0, stream>>>(rgat_W[0], RW_HI, RW_LO, 384, 384, 3 * 384 * 384);
    tsplit_k<<<cdiv(3 * 384 * 384, 256), 256, 0, stream>>>(rgat_W[1], RW_HI + 3 * 384 * 384, RW_LO + 3 * 384 * 384, 384, 384, 3 * 384 * 384);
    tsplit_k<<<cdiv(1024 * 128, 256), 256, 0, stream>>>(vis_W, VW_HI, VW_LO, 1024, 128, 1024 * 128);
    tsplit_k<<<cdiv(384 * 128, 256), 256, 0, stream>>>(cls_W1, CW_HI, CW_LO, 384, 128, 384 * 128);
    prep_qkw_k<<<cdiv(16 * 384, 256), 256, 0, stream>>>(rgat_q[0], rgat_kk[0], QKW_HI, QKW_LO);
    prep_qkw_k<<<cdiv(16 * 384, 256), 256, 0, stream>>>(rgat_q[1], rgat_kk[1], QKW_HI + 16 * 384, QKW_LO + 16 * 384);
    split_k<<<cdiv(Nn * 1024 / 4, 256), 256, 0, stream>>>(x_visual, VA_HI, VA_LO, Nn * 1024 / 4);

    const int MB = cdiv(Nn, 128);   // 157
    const int XRBLK = 160 * 9;      // padded rows * (3 cols x 3 rels), XCD-swizzled

    // ---------------- vis encoder (MFMA, TERMS=2) -> HCAT[:,0:128) fp32 pre-norm ----------------
    hipMemsetAsync(STATS, 0, 2 * sizeof(float), stream);
    mgemm_k<true, true, true, false, 2, false><<<dim3(MB, 1, 1), 256, 0, stream>>>(
        VA_HI, VA_LO, VW_HI, VW_LO, vis_b, HCAT, Nn, 1024, FD, 0, STATS);
    enc_norm_k<<<cdiv(Nn * 32, 256), 256, 0, stream>>>(HCAT, vis_lnw, vis_lnb, STATS, 1.f / ((float)Nn * 128.f), HS0_HI);

    // ---------------- geo encoder (fp32, K=6) -> HCAT[:,128:256) ----------------
    dim3 genc(cdiv(Nn, 64), 2, 1);
    hipMemsetAsync(STATS, 0, 2 * sizeof(float), stream);
    sgemm_k<true, true, true><<<genc, 256, 0, stream>>>(x_geom, geo_W, geo_b, HCAT + 128, Nn, 6, 128, FD, STATS);
    enc_norm_k<<<cdiv(Nn * 32, 256), 256, 0, stream>>>(HCAT + 128, geo_lnw, geo_lnb, STATS, 1.f / ((float)Nn * 128.f), HS0_HI + 128);

    for (int t = 0; t < 2; t++) {
        // prior encoder (fp32, K=33) -> HCAT[:,256:384)
        const float* pin = t ? PRIOR : x_prior;
        hipMemsetAsync(STATS, 0, 2 * sizeof(float), stream);
        sgemm_k<true, true, true><<<genc, 256, 0, stream>>>(pin, pri_W, pri_b, HCAT + 256, Nn, 33, 128, FD, STATS);
        enc_norm_k<<<cdiv(Nn * 32, 256), 256, 0, stream>>>(HCAT + 256, pri_lnw, pri_lnb, STATS, 1.f / ((float)Nn * 128.f), HS0_HI + 256);

        for (int L = 0; L < 2; L++) {
            const u16* ahi = L ? HS1_HI : HS0_HI;     // normalized input (bf16)
            const u16* alo = L ? HS1_LO : HS0_LO;     // unread (TERMS=1)
            u16* yout = L ? YB1 : YB0;                // aggr out (bf16 pre-norm)
            // XR = A @ W^T, pure bf16 (TERMS=1), bf16 out, XCD-swizzled grid
            mgemm_k<false, false, false, true, 1, true><<<dim3(XRBLK, 1, 1), 256, 0, stream>>>(
                ahi, alo, RW_HI + (size_t)L * 3 * 384 * 384, RW_LO + (size_t)L * 3 * 384 * 384,
                nullptr, XR16, Nn, 384, FD, 384 * 384, nullptr);
            proj_k<<<cdiv(3 * Nn, 128), 256, 0, stream>>>(XR16,
                QKW_HI + (size_t)L * 16 * 384, QKW_LO + (size_t)L * 16 * 384, QIK);
            ew_k<<<cdiv(ETOT, 256), 256, 0, stream>>>(QIK, EIDX, DSTE, EW);
            hipMemsetAsync(GSUM, 0, 128 * sizeof(float), stream);  // GSUM+GSQ contiguous
            aggr_k<<<cdiv(Nn, 4), 256, 0, stream>>>(XR16, EW, ROWPTR, EIDX, rgat_bias[L],
                                                    ahi, batch, yout, GSUM, GSQ);
            if (L == 0)
                gnorm_split_k<false><<<cdiv(Nn * 96, 256), 256, 0, stream>>>(
                    YB0, batch, GSUM, GSQ, GCNT, ln_w[0], ln_b[0], HS1_HI, HS1_LO);
            else
                gnorm_split_k<true><<<cdiv(Nn * 96, 256), 256, 0, stream>>>(
                    YB1, batch, GSUM, GSQ, GCNT, ln_w[1], ln_b[1], HS2_HI, HS2_LO);
        }

        // classifier: cls1 (MFMA TERMS=3, reads HS2 hi+lo) -> CLSH, cls2 (fp32) -> OUT
        mgemm_k<true, true, false, false, 3, false><<<dim3(MB, 1, 1), 256, 0, stream>>>(
            HS2_HI, HS2_LO, CW_HI, CW_LO, cls_b1, CLSH, Nn, 384, 128, 0, nullptr);
        sgemm_k<true, false, false><<<dim3(cdiv(Nn, 64), 1, 1), 256, 0, stream>>>(
            CLSH, cls_W2, cls_b2, OUT, Nn, 128, 32, 32, nullptr);

        if (t == 0)
            softmax_prior_k<<<cdiv(Nn, 8), 256, 0, stream>>>(OUT, PRIOR);
    }
}

// Round 12
// 770.207 us; speedup vs baseline: 1.8379x; 1.0437x over previous
//
#include <hip/hip_runtime.h>
#include <hip/hip_bf16.h>

#define Nn 20000
#define EREL 60000
#define ETOT 180000
#define NG 64
#define FD 384
#define EPS 1e-5f

typedef unsigned short u16;
typedef unsigned int u32;
typedef __attribute__((ext_vector_type(8))) short s8v;     // 8 bf16 (4 VGPR) MFMA A/B frag
typedef __attribute__((ext_vector_type(4))) float f4v;     // MFMA C/D frag

static inline int cdiv(int a, int b) { return (a + b - 1) / b; }

__device__ inline u16 f2b(float f) {
    __hip_bfloat16 h = __float2bfloat16(f);
    union { __hip_bfloat16 b; u16 u; } c; c.b = h; return c.u;
}
__device__ inline float b2f(u16 u) {
    union { __hip_bfloat16 b; u16 u; } c; c.u = u; return __bfloat162float(c.b);
}

// ---------------- split fp32 -> bf16 hi(/lo) (vectorized by float4) ----------------
template<bool WLO>
__global__ __launch_bounds__(256) void split_k(const float* __restrict__ x,
    u16* __restrict__ hi, u16* __restrict__ lo, int n4)
{
    int i = blockIdx.x * 256 + threadIdx.x;
    if (i >= n4) return;
    float4 v = ((const float4*)x)[i];
    ushort4 h;
    h.x = f2b(v.x); h.y = f2b(v.y); h.z = f2b(v.z); h.w = f2b(v.w);
    ((ushort4*)hi)[i] = h;
    if (WLO) {
        ushort4 l;
        l.x = f2b(v.x - b2f(h.x));
        l.y = f2b(v.y - b2f(h.y));
        l.z = f2b(v.z - b2f(h.z));
        l.w = f2b(v.w - b2f(h.w));
        ((ushort4*)lo)[i] = l;
    }
}

// transpose + split: W[b][K][N] -> T[b][N][K] hi(/lo)
template<bool WLO>
__global__ void tsplit_k(const float* __restrict__ W, u16* __restrict__ hi,
                         u16* __restrict__ lo, int K, int N, int total)
{
    int idx = blockIdx.x * 256 + threadIdx.x;
    if (idx >= total) return;
    int kn = K * N;
    int b = idx / kn, rem = idx - b * kn;
    int k = rem / N, n = rem - k * N;
    float v = W[idx];
    u16 h = f2b(v);
    int o = b * kn + n * K + k;
    hi[o] = h;
    if (WLO) lo[o] = f2b(v - b2f(h));
}

// W2T[L][r*16+c][kin] = sum_d W[L][r][kin][d] * (c<8 ? q[d][c] : k[d][c-8])  (bf16 hi/lo)
__global__ __launch_bounds__(256) void w2_k(const float* __restrict__ W0,
    const float* __restrict__ q0, const float* __restrict__ k0,
    const float* __restrict__ W1, const float* __restrict__ q1, const float* __restrict__ k1,
    u16* __restrict__ hi, u16* __restrict__ lo)
{
    int idx = blockIdx.x * 256 + threadIdx.x;   // ((L*3+r)*384 + kin)*16 + c
    if (idx >= 2 * 3 * 384 * 16) return;
    int c = idx & 15;
    int rest = idx >> 4;
    int kin = rest % 384;
    int lr3 = rest / 384;
    int L = lr3 / 3, r = lr3 - L * 3;
    const float* W = (L ? W1 : W0) + ((size_t)r * 384 + kin) * 384;
    const float* qm = (c < 8) ? (L ? q1 : q0) : (L ? k1 : k0);
    int h = c & 7;
    float s = 0.f;
    for (int d = 0; d < 384; d++) s = fmaf(W[d], qm[d * 8 + h], s);
    u16 hh = f2b(s);
    size_t o = ((size_t)L * 48 + r * 16 + c) * 384 + kin;
    hi[o] = hh;
    lo[o] = f2b(s - b2f(hh));
}

// ---------------- split-bf16 MFMA GEMM ----------------
// C[M,N] = A[M,K] @ B[N,K]^T, bf16 (hi,lo) row-major ld=K. 128x128 tile, 4 waves,
// 16x16x32 MFMA. TERMS=1: ah*bh. TERMS=2: +al*bh. TERMS=3: +ah*bl (~fp32).
// SWZ: XCD-aware grid for the XR shape (9 col/rel blocks share an A strip -> same XCD L2).
#define USEI(i) ((i) < 2 || ((i) >= 4 && (i) < 6) || (TERMS >= 2 && ((i) == 2 || (i) == 3)) || (TERMS >= 3 && (i) >= 6))
template<bool BIAS, bool RELU, bool STATS, bool OB16, int TERMS, bool SWZ>
__global__ __launch_bounds__(256) void mgemm_k(
    const u16* __restrict__ Ahi, const u16* __restrict__ Alo,
    const u16* __restrict__ Bhi, const u16* __restrict__ Blo,
    const float* __restrict__ bias, void* __restrict__ Cv,
    int M, int K, int ldc, int bstride, float* __restrict__ stats)
{
    __shared__ u16 lds[4 * 128 * 32];
    __shared__ float red[256];
    const int t = threadIdx.x;
    int brow, bcol, z;
    if (SWZ) {
        int d = blockIdx.x;
        int xcd = d & 7, s = d >> 3;
        int row = xcd + 8 * (s / 9);
        int c = s % 9;
        brow = row * 128;
        if (brow >= M) return;
        bcol = (c % 3) * 128;
        z = c / 3;
    } else {
        brow = blockIdx.x * 128; bcol = blockIdx.y * 128; z = blockIdx.z;
    }
    Bhi += (size_t)z * bstride;
    Blo += (size_t)z * bstride;
    float* Cf = OB16 ? nullptr : (float*)Cv + (size_t)z * M * ldc;
    u16*   Ch = OB16 ? (u16*)Cv + (size_t)z * M * ldc : nullptr;

    const int r0 = t >> 2, sl = t & 3;
    const int rA0 = min(brow + r0, M - 1);
    const int rA1 = min(brow + r0 + 64, M - 1);
    const u16* gsrc[8];
    gsrc[0] = Ahi + (size_t)rA0 * K + sl * 8;
    gsrc[1] = Ahi + (size_t)rA1 * K + sl * 8;
    gsrc[2] = Alo + (size_t)rA0 * K + sl * 8;
    gsrc[3] = Alo + (size_t)rA1 * K + sl * 8;
    gsrc[4] = Bhi + (size_t)(bcol + r0) * K + sl * 8;
    gsrc[5] = Bhi + (size_t)(bcol + r0 + 64) * K + sl * 8;
    gsrc[6] = Blo + (size_t)(bcol + r0) * K + sl * 8;
    gsrc[7] = Blo + (size_t)(bcol + r0 + 64) * K + sl * 8;
    const int swz = (sl ^ (r0 & 3)) << 3;
    int ldst[8];
    #pragma unroll
    for (int i = 0; i < 8; i++) {
        int tile = i >> 1, row = r0 + 64 * (i & 1);
        ldst[i] = tile * 4096 + row * 32 + swz;
    }

    const int l = t & 63, w = t >> 6;
    const int wr = (w >> 1) * 64, wc = (w & 1) * 64;
    const int lr = l & 15, kq = l >> 4;

    f4v acc[4][4] = {};
    const int NK = K >> 5;

    s8v stg[8];
    #pragma unroll
    for (int i = 0; i < 8; i++) if (USEI(i)) stg[i] = *(const s8v*)gsrc[i];

    for (int kc = 0; kc < NK; kc++) {
        if (kc) __syncthreads();
        #pragma unroll
        for (int i = 0; i < 8; i++) if (USEI(i)) *(s8v*)(lds + ldst[i]) = stg[i];
        __syncthreads();
        if (kc + 1 < NK) {
            const int ko = (kc + 1) * 32;
            #pragma unroll
            for (int i = 0; i < 8; i++) if (USEI(i)) stg[i] = *(const s8v*)(gsrc[i] + ko);
        }
        #define LDR(T, row) (*(const s8v*)(lds + (T) * 4096 + (row) * 32 + ((kq ^ ((row) & 3)) << 3)))
        s8v bh[4], bl[4];
        #pragma unroll
        for (int tn = 0; tn < 4; tn++) {
            int rb = wc + tn * 16 + lr;
            bh[tn] = LDR(2, rb);
            if (TERMS >= 3) bl[tn] = LDR(3, rb);
        }
        #pragma unroll
        for (int tm = 0; tm < 4; tm++) {
            int ra = wr + tm * 16 + lr;
            s8v ah = LDR(0, ra);
            s8v al;
            if (TERMS >= 2) al = LDR(1, ra);
            #pragma unroll
            for (int tn = 0; tn < 4; tn++) {
                acc[tm][tn] = __builtin_amdgcn_mfma_f32_16x16x32_bf16(ah, bh[tn], acc[tm][tn], 0, 0, 0);
                if (TERMS >= 2)
                    acc[tm][tn] = __builtin_amdgcn_mfma_f32_16x16x32_bf16(al, bh[tn], acc[tm][tn], 0, 0, 0);
                if (TERMS >= 3)
                    acc[tm][tn] = __builtin_amdgcn_mfma_f32_16x16x32_bf16(ah, bl[tn], acc[tm][tn], 0, 0, 0);
            }
        }
        #undef LDR
    }

    float s1 = 0.f, s2 = 0.f;
    #pragma unroll
    for (int tm = 0; tm < 4; tm++) {
        #pragma unroll
        for (int rg = 0; rg < 4; rg++) {
            int row = brow + wr + tm * 16 + kq * 4 + rg;
            if (row < M) {
                #pragma unroll
                for (int tn = 0; tn < 4; tn++) {
                    int col = bcol + wc + tn * 16 + lr;
                    float v = acc[tm][tn][rg];
                    if (BIAS) v += bias[col];
                    if (RELU) v = fmaxf(v, 0.f);
                    if (OB16) Ch[(size_t)row * ldc + col] = f2b(v);
                    else      Cf[(size_t)row * ldc + col] = v;
                    if (STATS) { s1 += v; s2 += v * v; }
                }
            }
        }
    }
    if (STATS) {
        __syncthreads();
        red[t] = s1; __syncthreads();
        for (int o = 128; o; o >>= 1) { if (t < o) red[t] += red[t + o]; __syncthreads(); }
        if (t == 0) atomicAdd(&stats[0], red[0]);
        __syncthreads();
        red[t] = s2; __syncthreads();
        for (int o = 128; o; o >>= 1) { if (t < o) red[t] += red[t + o]; __syncthreads(); }
        if (t == 0) atomicAdd(&stats[1], red[0]);
    }
}
#undef USEI

// ---------------- projh GEMM: QIK[Nn,48] = HS(bf16) @ W2T[48,384]^T (2-term B split) ----
__global__ __launch_bounds__(256) void projh_k(const u16* __restrict__ hs,
    const u16* __restrict__ w2hi, const u16* __restrict__ w2lo, float* __restrict__ qik)
{
    __shared__ u16 a_lds[128 * 32];
    __shared__ u16 b_lds[2][48 * 392];
    int t = threadIdx.x;
    int brow = blockIdx.x * 128;

    for (int i = t; i < 2304; i += 256) {    // 48 cols * 48 chunks of 8
        int col = i / 48, c8 = (i - col * 48) * 8;
        *(s8v*)&b_lds[0][col * 392 + c8] = *(const s8v*)(w2hi + col * 384 + c8);
        *(s8v*)&b_lds[1][col * 392 + c8] = *(const s8v*)(w2lo + col * 384 + c8);
    }

    int ar = t >> 1, sl0 = (t & 1) * 2;
    int grow = min(brow + ar, Nn - 1);
    const u16* asrc = hs + (size_t)grow * FD;
    int adst0 = ar * 32 + ((sl0 ^ (ar & 3)) << 3);
    int adst1 = ar * 32 + (((sl0 + 1) ^ (ar & 3)) << 3);

    int l = t & 63, w = t >> 6;
    int lr = l & 15, kq = l >> 4;
    f4v acc[2][3] = {};

    s8v stg0 = *(const s8v*)(asrc + sl0 * 8);
    s8v stg1 = *(const s8v*)(asrc + sl0 * 8 + 8);
    for (int kc = 0; kc < 12; kc++) {
        if (kc) __syncthreads();
        *(s8v*)&a_lds[adst0] = stg0;
        *(s8v*)&a_lds[adst1] = stg1;
        __syncthreads();
        if (kc + 1 < 12) {
            int ko = (kc + 1) * 32 + sl0 * 8;
            stg0 = *(const s8v*)(asrc + ko);
            stg1 = *(const s8v*)(asrc + ko + 8);
        }
        s8v bh[3], bl[3];
        #pragma unroll
        for (int cf = 0; cf < 3; cf++) {
            bh[cf] = *(const s8v*)&b_lds[0][(cf * 16 + lr) * 392 + kc * 32 + kq * 8];
            bl[cf] = *(const s8v*)&b_lds[1][(cf * 16 + lr) * 392 + kc * 32 + kq * 8];
        }
        #pragma unroll
        for (int rf = 0; rf < 2; rf++) {
            int rr = w * 32 + rf * 16 + lr;
            s8v a = *(const s8v*)&a_lds[rr * 32 + ((kq ^ (rr & 3)) << 3)];
            #pragma unroll
            for (int cf = 0; cf < 3; cf++) {
                acc[rf][cf] = __builtin_amdgcn_mfma_f32_16x16x32_bf16(a, bh[cf], acc[rf][cf], 0, 0, 0);
                acc[rf][cf] = __builtin_amdgcn_mfma_f32_16x16x32_bf16(a, bl[cf], acc[rf][cf], 0, 0, 0);
            }
        }
    }
    #pragma unroll
    for (int rf = 0; rf < 2; rf++)
        #pragma unroll
        for (int cf = 0; cf < 3; cf++)
            #pragma unroll
            for (int rg = 0; rg < 4; rg++) {
                int row = brow + w * 32 + rf * 16 + kq * 4 + rg;
                if (row < Nn) qik[(size_t)row * 48 + cf * 16 + lr] = acc[rf][cf][rg];
            }
}

// ---------------- fp32 tiled GEMM (tiny-K shapes: geo K=6, pri K=33, cls2) ----------------
template<bool BIAS, bool RELU, bool STATS>
__global__ __launch_bounds__(256) void sgemm_k(
    const float* __restrict__ A, const float* __restrict__ B,
    const float* __restrict__ bias, float* __restrict__ C,
    int M, int K, int N, int ldc, float* __restrict__ stats)
{
    const int BK = 16;
    const int r = blockIdx.z;
    B += (size_t)r * K * N;
    C += (size_t)r * M * ldc;
    __shared__ float As[16][65];
    __shared__ float Bs[16][64];
    int tid = threadIdx.x;
    int tx = tid & 15, ty = tid >> 4;
    int brow = blockIdx.x * 64, bcol = blockIdx.y * 64;
    float acc[4][4] = {};
    for (int k0 = 0; k0 < K; k0 += BK) {
        #pragma unroll
        for (int i = 0; i < 4; i++) {
            int e = tid + 256 * i;
            int ar = e >> 4, ak = e & 15;
            int gr = brow + ar, gk = k0 + ak;
            As[ak][ar] = (gr < M && gk < K) ? A[(size_t)gr * K + gk] : 0.f;
            int bk = e >> 6, bn = e & 63;
            int gbk = k0 + bk, gbn = bcol + bn;
            Bs[bk][bn] = (gbk < K && gbn < N) ? B[(size_t)gbk * N + gbn] : 0.f;
        }
        __syncthreads();
        #pragma unroll
        for (int k = 0; k < BK; k++) {
            float ra[4], rb[4];
            #pragma unroll
            for (int i = 0; i < 4; i++) ra[i] = As[k][ty * 4 + i];
            #pragma unroll
            for (int j = 0; j < 4; j++) rb[j] = Bs[k][tx * 4 + j];
            #pragma unroll
            for (int i = 0; i < 4; i++)
                #pragma unroll
                for (int j = 0; j < 4; j++)
                    acc[i][j] = fmaf(ra[i], rb[j], acc[i][j]);
        }
        __syncthreads();
    }
    float s1 = 0.f, s2 = 0.f;
    #pragma unroll
    for (int i = 0; i < 4; i++) {
        int row = brow + ty * 4 + i;
        #pragma unroll
        for (int j = 0; j < 4; j++) {
            int col = bcol + tx * 4 + j;
            if (row < M && col < N) {
                float v = acc[i][j];
                if (BIAS) v += bias[col];
                if (RELU) v = v > 0.f ? v : 0.f;
                C[(size_t)row * ldc + col] = v;
                if (STATS) { s1 += v; s2 += v * v; }
            }
        }
    }
    if (STATS) {
        __shared__ float red[256];
        __syncthreads();
        red[tid] = s1; __syncthreads();
        for (int o = 128; o; o >>= 1) { if (tid < o) red[tid] += red[tid + o]; __syncthreads(); }
        if (tid == 0) atomicAdd(&stats[0], red[0]);
        __syncthreads();
        red[tid] = s2; __syncthreads();
        for (int o = 128; o; o >>= 1) { if (tid < o) red[tid] += red[tid + o]; __syncthreads(); }
        if (tid == 0) atomicAdd(&stats[1], red[0]);
    }
}

// scalar-LN of a 128-col block of H (pre-offset, fp32 pre-norm) from RAW sums -> bf16 hi
__global__ __launch_bounds__(256) void enc_norm_k(const float* __restrict__ H,
                           const float* __restrict__ w, const float* __restrict__ b,
                           const float* __restrict__ stats, float cntinv, u16* __restrict__ hi)
{
    int i = blockIdx.x * 256 + threadIdx.x;
    if (i >= Nn * 32) return;
    int n = i >> 5, c4 = i & 31;
    float m = stats[0] * cntinv;
    float var = stats[1] * cntinv - m * m;
    float s = 1.f / (sqrtf(fmaxf(var, 0.f)) + EPS);
    float4 wv = ((const float4*)w)[c4];
    float4 bv = ((const float4*)b)[c4];
    float4 v = ((const float4*)(H + (size_t)n * FD))[c4];
    ushort4 hh;
    hh.x = f2b((v.x - m) * s * wv.x + bv.x);
    hh.y = f2b((v.y - m) * s * wv.y + bv.y);
    hh.z = f2b((v.z - m) * s * wv.z + bv.z);
    hh.w = f2b((v.w - m) * s * wv.w + bv.w);
    ((ushort4*)(hi + (size_t)n * FD))[c4] = hh;
}

__global__ void edge_count_k(const int* __restrict__ e0, const int* __restrict__ e1,
                             const int* __restrict__ e2, int* __restrict__ cnt)
{
    int e = blockIdx.x * 256 + threadIdx.x;
    if (e >= ETOT) return;
    int r = e / EREL, i = e - r * EREL;
    const int* ei = (r == 0) ? e0 : (r == 1) ? e1 : e2;
    atomicAdd(&cnt[ei[EREL + i]], 1);
}

__global__ void edge_fill_k(const int* __restrict__ e0, const int* __restrict__ e1,
                            const int* __restrict__ e2, int* __restrict__ cursor,
                            int* __restrict__ eidx)
{
    int e = blockIdx.x * 256 + threadIdx.x;
    if (e >= ETOT) return;
    int r = e / EREL, i = e - r * EREL;
    const int* ei = (r == 0) ? e0 : (r == 1) ? e1 : e2;
    int src = ei[i], dst = ei[EREL + i];
    int pos = atomicAdd(&cursor[dst], 1);
    eidx[pos] = src | (r << 24);
}

// exclusive scan via per-wave shuffle scan + 16-wave LDS combine
__global__ __launch_bounds__(1024) void scan_k(const int* __restrict__ cnt,
                                               int* __restrict__ rowptr, int* __restrict__ cursor)
{
    __shared__ int wsum[16], wpre[16];
    __shared__ int carry, tot;
    int t = threadIdx.x, lane = t & 63, wid = t >> 6;
    if (t == 0) carry = 0;
    __syncthreads();
    for (int base = 0; base < Nn; base += 1024) {
        int i = base + t;
        int v = (i < Nn) ? cnt[i] : 0;
        int s = v;
        #pragma unroll
        for (int o = 1; o < 64; o <<= 1) {
            int x = __shfl_up(s, o);
            if (lane >= o) s += x;
        }
        if (lane == 63) wsum[wid] = s;
        __syncthreads();
        if (t < 16) {
            int wv = wsum[t];
            int ws = wv;
            #pragma unroll
            for (int o = 1; o < 16; o <<= 1) {
                int x = __shfl_up(ws, o);
                if (t >= o) ws += x;
            }
            wpre[t] = ws - wv;
            if (t == 15) tot = ws;
        }
        __syncthreads();
        if (i < Nn) {
            int ex = carry + wpre[wid] + s - v;
            rowptr[i] = ex; cursor[i] = ex;
        }
        __syncthreads();
        if (t == 0) carry += tot;
    }
    __syncthreads();
    if (t == 0) rowptr[Nn] = carry;
}

// per-graph node counts via LDS histogram
__global__ __launch_bounds__(256) void gcount_k(const int* __restrict__ batch, int* __restrict__ gcnt)
{
    __shared__ int bins[NG];
    int t = threadIdx.x;
    if (t < NG) bins[t] = 0;
    __syncthreads();
    int n = blockIdx.x * 256 + t;
    if (n < Nn) atomicAdd(&bins[batch[n]], 1);
    __syncthreads();
    if (t < NG && bins[t]) atomicAdd(&gcnt[t], bins[t]);
}

// RGAT aggregation, softmax fused (reads QIK[n][48]: q=r*16+h, k=r*16+8+h).
// One wave per dst node, 4x edge unroll. Lane owns channels 6l..6l+5 (one head ->
// 1 shfl/edge); rows gathered as dwordx3. Fused elu/residual/per-graph-stats.
__global__ __launch_bounds__(256) void aggr_k(const u16* __restrict__ xr,
    const float* __restrict__ qik, const int* __restrict__ rowptr, const int* __restrict__ eidx,
    const float* __restrict__ bias, const u16* __restrict__ hinb,
    const int* __restrict__ batch, u16* __restrict__ outb,
    float* __restrict__ gsum, float* __restrict__ gsq)
{
    __shared__ float ls[NG], lq[NG];
    int t = threadIdx.x;
    if (t < NG) { ls[t] = 0.f; lq[t] = 0.f; }
    __syncthreads();
    int node = blockIdx.x * 4 + (t >> 6);
    int lane = t & 63;
    int e0 = rowptr[node], e1 = rowptr[node + 1];
    int hd = lane >> 3;
    float qv = (lane < 48) ? qik[(size_t)node * 48 + lane] : 0.f;
    float den = 0.f;
    float acc[6] = {};

    int e = e0;
    while (e + 4 <= e1) {
        int p0 = eidx[e], p1 = eidx[e + 1], p2 = eidx[e + 2], p3 = eidx[e + 3];
        int n0 = p0 & 0xFFFFFF, et0 = p0 >> 24;
        int n1 = p1 & 0xFFFFFF, et1 = p1 >> 24;
        int n2 = p2 & 0xFFFFFF, et2 = p2 >> 24;
        int n3 = p3 & 0xFFFFFF, et3 = p3 >> 24;
        float kv0 = (lane < 8) ? qik[(size_t)n0 * 48 + et0 * 16 + 8 + lane] : 0.f;
        float kv1 = (lane < 8) ? qik[(size_t)n1 * 48 + et1 * 16 + 8 + lane] : 0.f;
        float kv2 = (lane < 8) ? qik[(size_t)n2 * 48 + et2 * 16 + 8 + lane] : 0.f;
        float kv3 = (lane < 8) ? qik[(size_t)n3 * 48 + et3 * 16 + 8 + lane] : 0.f;
        const u32* r0 = (const u32*)(xr + ((size_t)et0 * Nn + n0) * FD);
        const u32* r1 = (const u32*)(xr + ((size_t)et1 * Nn + n1) * FD);
        const u32* r2 = (const u32*)(xr + ((size_t)et2 * Nn + n2) * FD);
        const u32* r3 = (const u32*)(xr + ((size_t)et3 * Nn + n3) * FD);
        u32 u0[3], u1[3], u2[3], u3[3];
        #pragma unroll
        for (int j = 0; j < 3; j++) u0[j] = r0[lane * 3 + j];
        #pragma unroll
        for (int j = 0; j < 3; j++) u1[j] = r1[lane * 3 + j];
        #pragma unroll
        for (int j = 0; j < 3; j++) u2[j] = r2[lane * 3 + j];
        #pragma unroll
        for (int j = 0; j < 3; j++) u3[j] = r3[lane * 3 + j];
        float qq0 = __shfl(qv, et0 * 16 + (lane & 7));
        float qq1 = __shfl(qv, et1 * 16 + (lane & 7));
        float qq2 = __shfl(qv, et2 * 16 + (lane & 7));
        float qq3 = __shfl(qv, et3 * 16 + (lane & 7));
        float ex0 = 0.f, ex1 = 0.f, ex2 = 0.f, ex3 = 0.f;
        if (lane < 8) {
            float a0 = qq0 + kv0; a0 = (a0 > 0.f) ? a0 : 0.2f * a0; ex0 = __expf(a0);
            float a1 = qq1 + kv1; a1 = (a1 > 0.f) ? a1 : 0.2f * a1; ex1 = __expf(a1);
            float a2 = qq2 + kv2; a2 = (a2 > 0.f) ? a2 : 0.2f * a2; ex2 = __expf(a2);
            float a3 = qq3 + kv3; a3 = (a3 > 0.f) ? a3 : 0.2f * a3; ex3 = __expf(a3);
        }
        den += ex0 + ex1 + ex2 + ex3;
        float w0 = __shfl(ex0, hd), w1 = __shfl(ex1, hd);
        float w2 = __shfl(ex2, hd), w3 = __shfl(ex3, hd);
        #pragma unroll
        for (int j = 0; j < 3; j++) {
            acc[2*j]   = fmaf(w0, __uint_as_float(u0[j] << 16), acc[2*j]);
            acc[2*j+1] = fmaf(w0, __uint_as_float(u0[j] & 0xffff0000u), acc[2*j+1]);
            acc[2*j]   = fmaf(w1, __uint_as_float(u1[j] << 16), acc[2*j]);
            acc[2*j+1] = fmaf(w1, __uint_as_float(u1[j] & 0xffff0000u), acc[2*j+1]);
            acc[2*j]   = fmaf(w2, __uint_as_float(u2[j] << 16), acc[2*j]);
            acc[2*j+1] = fmaf(w2, __uint_as_float(u2[j] & 0xffff0000u), acc[2*j+1]);
            acc[2*j]   = fmaf(w3, __uint_as_float(u3[j] << 16), acc[2*j]);
            acc[2*j+1] = fmaf(w3, __uint_as_float(u3[j] & 0xffff0000u), acc[2*j+1]);
        }
        e += 4;
    }
    for (; e < e1; e++) {
        int p = eidx[e];
        int sn = p & 0xFFFFFF, et = p >> 24;
        float kv = (lane < 8) ? qik[(size_t)sn * 48 + et * 16 + 8 + lane] : 0.f;
        const u32* rr = (const u32*)(xr + ((size_t)et * Nn + sn) * FD);
        u32 u[3];
        #pragma unroll
        for (int j = 0; j < 3; j++) u[j] = rr[lane * 3 + j];
        float qq = __shfl(qv, et * 16 + (lane & 7));
        float ex = 0.f;
        if (lane < 8) { float a = qq + kv; a = (a > 0.f) ? a : 0.2f * a; ex = __expf(a); }
        den += ex;
        float wv_ = __shfl(ex, hd);
        #pragma unroll
        for (int j = 0; j < 3; j++) {
            acc[2*j]   = fmaf(wv_, __uint_as_float(u[j] << 16), acc[2*j]);
            acc[2*j+1] = fmaf(wv_, __uint_as_float(u[j] & 0xffff0000u), acc[2*j+1]);
        }
    }

    float dh = __shfl(den, hd);
    float rcp = 1.f / (dh + 1e-16f);
    const u32* hp = (const u32*)(hinb + (size_t)node * FD);
    u32* op = (u32*)(outb + (size_t)node * FD);
    float s1 = 0.f, s2 = 0.f;
    #pragma unroll
    for (int j = 0; j < 3; j++) {
        int c = lane * 6 + 2 * j;
        float2 bv = *(const float2*)(bias + c);
        u32 hb = hp[lane * 3 + j];
        float vx = acc[2*j] * rcp + bv.x;
        float vy = acc[2*j+1] * rcp + bv.y;
        vx = (vx > 0.f) ? vx : expm1f(vx);
        vy = (vy > 0.f) ? vy : expm1f(vy);
        vx += b2f((u16)(hb & 0xffffu));
        vy += b2f((u16)(hb >> 16));
        op[lane * 3 + j] = (u32)f2b(vx) | ((u32)f2b(vy) << 16);
        s1 += vx + vy; s2 += vx * vx + vy * vy;
    }
    #pragma unroll
    for (int o = 32; o; o >>= 1) { s1 += __shfl_down(s1, o); s2 += __shfl_down(s2, o); }
    int g = batch[node];
    if (lane == 0) { atomicAdd(&ls[g], s1); atomicAdd(&lq[g], s2); }
    __syncthreads();
    if (t < NG && (ls[t] != 0.f || lq[t] != 0.f)) {
        atomicAdd(&gsum[t], ls[t]);
        atomicAdd(&gsq[t], lq[t]);
    }
}

// graph-LN from raw sums, bf16 input -> bf16 hi (+lo only for the TERMS=3 cls1 GEMM)
template<bool WLO>
__global__ __launch_bounds__(256) void gnorm_split_k(const u16* __restrict__ yb,
    const int* __restrict__ batch, const float* __restrict__ gsum, const float* __restrict__ gsq,
    const int* __restrict__ gcnt, const float* __restrict__ w, const float* __restrict__ b,
    u16* __restrict__ hi, u16* __restrict__ lo)
{
    int i = blockIdx.x * 256 + threadIdx.x;
    if (i >= Nn * (FD / 4)) return;
    int n = i / 96;
    int c4 = i - n * 96;
    int g = batch[n];
    float norm = fmaxf((float)gcnt[g], 1.f) * (float)FD;
    float m = gsum[g] / norm;
    float var = gsq[g] / norm - m * m;
    float rstd = rsqrtf(var + EPS);
    float4 wv = ((const float4*)w)[c4];
    float4 bv = ((const float4*)b)[c4];
    uint2 yv = ((const uint2*)yb)[i];
    float v0 = (b2f((u16)(yv.x & 0xffffu)) - m) * rstd * wv.x + bv.x;
    float v1 = (b2f((u16)(yv.x >> 16))     - m) * rstd * wv.y + bv.y;
    float v2 = (b2f((u16)(yv.y & 0xffffu)) - m) * rstd * wv.z + bv.z;
    float v3 = (b2f((u16)(yv.y >> 16))     - m) * rstd * wv.w + bv.w;
    ushort4 hh;
    hh.x = f2b(v0); hh.y = f2b(v1); hh.z = f2b(v2); hh.w = f2b(v3);
    ((ushort4*)hi)[i] = hh;
    if (WLO) {
        ushort4 ll;
        ll.x = f2b(v0 - b2f(hh.x));
        ll.y = f2b(v1 - b2f(hh.y));
        ll.z = f2b(v2 - b2f(hh.z));
        ll.w = f2b(v3 - b2f(hh.w));
        ((ushort4*)lo)[i] = ll;
    }
}

__global__ void softmax_prior_k(const float* __restrict__ logits, float* __restrict__ prior)
{
    int n = blockIdx.x * 8 + (threadIdx.x >> 5);
    int l = threadIdx.x & 31;
    if (n >= Nn) return;
    float v = logits[n * 32 + l];
    float m = v;
    #pragma unroll
    for (int o = 16; o; o >>= 1) m = fmaxf(m, __shfl_xor(m, o, 32));
    float e = __expf(v - m);
    float s = e;
    #pragma unroll
    for (int o = 16; o; o >>= 1) s += __shfl_xor(s, o, 32);
    prior[(size_t)n * 33 + l] = e / s;
    if (l == 0) prior[(size_t)n * 33 + 32] = 1.f / s;
}

extern "C" void kernel_launch(void* const* d_in, const int* in_sizes, int n_in,
                              void* d_out, int out_size, void* d_ws, size_t ws_size,
                              hipStream_t stream)
{
    const float* x_visual = (const float*)d_in[0];
    const float* x_geom   = (const float*)d_in[1];
    const float* x_prior  = (const float*)d_in[2];
    const int* ei0   = (const int*)d_in[3];
    const int* ei1   = (const int*)d_in[4];
    const int* ei2   = (const int*)d_in[5];
    const int* batch = (const int*)d_in[6];
    const float* vis_W = (const float*)d_in[7];  const float* vis_b = (const float*)d_in[8];
    const float* vis_lnw = (const float*)d_in[9]; const float* vis_lnb = (const float*)d_in[10];
    const float* geo_W = (const float*)d_in[11]; const float* geo_b = (const float*)d_in[12];
    const float* geo_lnw = (const float*)d_in[13]; const float* geo_lnb = (const float*)d_in[14];
    const float* pri_W = (const float*)d_in[15]; const float* pri_b = (const float*)d_in[16];
    const float* pri_lnw = (const float*)d_in[17]; const float* pri_lnb = (const float*)d_in[18];
    const float* rgat_W[2]    = { (const float*)d_in[19], (const float*)d_in[25] };
    const float* rgat_q[2]    = { (const float*)d_in[20], (const float*)d_in[26] };
    const float* rgat_kk[2]   = { (const float*)d_in[21], (const float*)d_in[27] };
    const float* rgat_bias[2] = { (const float*)d_in[22], (const float*)d_in[28] };
    const float* ln_w[2]      = { (const float*)d_in[23], (const float*)d_in[29] };
    const float* ln_b[2]      = { (const float*)d_in[24], (const float*)d_in[30] };
    const float* cls_W1 = (const float*)d_in[31]; const float* cls_b1 = (const float*)d_in[32];
    const float* cls_W2 = (const float*)d_in[33]; const float* cls_b2 = (const float*)d_in[34];
    float* OUT = (float*)d_out;

    // ---------------- workspace layout ----------------
    float* ws = (float*)d_ws;
    float* XRreg = ws;                         // 3*Nn*FD floats reserved (92.2 MB region)
    u16*   XR16  = (u16*)XRreg;                // XR stored bf16 (46 MB)
    float* HCAT  = XRreg + (size_t)3 * Nn * FD; // fp32 pre-norm encoder outputs
    float* HA    = HCAT + (size_t)Nn * FD;
    float* HB    = HA + (size_t)Nn * FD;
    float* PRIOR = HB + (size_t)Nn * FD;       // Nn*33
    float* QIK   = PRIOR + (size_t)Nn * 33;    // Nn*48 (per rel: q h0-7 | k h0-7)
    u16* HS0_HI  = (u16*)(QIK + (size_t)Nn * 48);      // normalized HCAT (bf16)
    u16* HS0_LO  = HS0_HI + (size_t)Nn * FD;           // (dead — layout keep)
    u16* HS1_HI  = HS0_LO + (size_t)Nn * FD;           // normalized layer-0 out (bf16)
    u16* HS1_LO  = HS1_HI + (size_t)Nn * FD;           // (dead)
    u16* RW_HI   = HS1_LO + (size_t)Nn * FD;   // 2*3*384*384
    u16* RW_LO   = RW_HI + (size_t)2 * 3 * 384 * 384;  // (dead, unwritten)
    u16* VW_HI   = RW_LO + (size_t)2 * 3 * 384 * 384; // 128*1024
    u16* VW_LO   = VW_HI + (size_t)128 * 1024;        // (dead, unwritten)
    u16* CW_HI   = VW_LO + (size_t)128 * 1024;        // 128*384
    u16* CW_LO   = CW_HI + (size_t)128 * 384;
    u16* W2_HI   = CW_LO + (size_t)128 * 384;         // 2 layers * 48*384
    u16* W2_LO   = W2_HI + (size_t)2 * 48 * 384;
    float* STATS = (float*)(W2_LO + (size_t)2 * 48 * 384); // 2
    float* GSUM  = STATS + 2;                  // 64
    float* GSQ   = GSUM + 64;
    int* CNT    = (int*)(GSQ + 64);
    int* ROWPTR = CNT + Nn;
    int* CURSOR = ROWPTR + Nn + 1;
    int* EIDX   = CURSOR + Nn;
    int* GCNT   = EIDX + ETOT;
    // aliases (temporally dead sub-ranges):
    u16* VA_HI = (u16*)XRreg;                  // x_visual bf16 [0,41MB): dead after vis gemm
    float* CLSH = XRreg;                       // classifier hidden [0,10.3MB): after last aggr
    u16* HS2_HI = (u16*)(XRreg + (size_t)12 * 1000 * 1000); // HB split [48MB,78.7MB)
    u16* HS2_LO = HS2_HI + (size_t)Nn * FD;
    u16* YB0 = (u16*)HA;                       // aggr L=0 out (bf16 pre-norm)
    u16* YB1 = (u16*)HB;                       // aggr L=1 out (bf16 pre-norm)

    // ---------------- CSR build (reused by all 4 RGAT calls) ----------------
    hipMemsetAsync(CNT, 0, Nn * sizeof(int), stream);
    edge_count_k<<<cdiv(ETOT, 256), 256, 0, stream>>>(ei0, ei1, ei2, CNT);
    scan_k<<<1, 1024, 0, stream>>>(CNT, ROWPTR, CURSOR);
    edge_fill_k<<<cdiv(ETOT, 256), 256, 0, stream>>>(ei0, ei1, ei2, CURSOR, EIDX);
    hipMemsetAsync(GCNT, 0, 64 * sizeof(int), stream);
    gcount_k<<<cdiv(Nn, 256), 256, 0, stream>>>(batch, GCNT);

    // ---------------- weight + x_visual conversions ----------------
    tsplit_k<false><<<cdiv(3 * 384 * 384, 256), 256, 0, stream>>>(rgat_W[0], RW_HI, RW_LO, 384, 384, 3 * 384 * 384);
    tsplit_k<false><<<cdiv(3 * 384 * 384, 256), 256, 0, stream>>>(rgat_W[1], RW_HI + 3 * 384 * 384, RW_LO, 384, 384, 3 * 384 * 384);
    tsplit_k<false><<<cdiv(1024 * 128, 256), 256, 0, stream>>>(vis_W, VW_HI, VW_LO, 1024, 128, 1024 * 128);
    tsplit_k<true><<<cdiv(384 * 128, 256), 256, 0, stream>>>(cls_W1, CW_HI, CW_LO, 384, 128, 384 * 128);
    w2_k<<<cdiv(2 * 3 * 384 * 16, 256), 256, 0, stream>>>(rgat_W[0], rgat_q[0], rgat_kk[0],
        rgat_W[1], rgat_q[1], rgat_kk[1], W2_HI, W2_LO);
    split_k<false><<<cdiv(Nn * 1024 / 4, 256), 256, 0, stream>>>(x_visual, VA_HI, nullptr, Nn * 1024 / 4);

    const int MB = cdiv(Nn, 128);   // 157
    const int XRBLK = 160 * 9;      // padded rows * (3 cols x 3 rels), XCD-swizzled

    // ---------------- vis encoder (MFMA, TERMS=1) -> HCAT[:,0:128) fp32 pre-norm ----------------
    hipMemsetAsync(STATS, 0, 2 * sizeof(float), stream);
    mgemm_k<true, true, true, false, 1, false><<<dim3(MB, 1, 1), 256, 0, stream>>>(
        VA_HI, VA_HI, VW_HI, VW_LO, vis_b, HCAT, Nn, 1024, FD, 0, STATS);
    enc_norm_k<<<cdiv(Nn * 32, 256), 256, 0, stream>>>(HCAT, vis_lnw, vis_lnb, STATS, 1.f / ((float)Nn * 128.f), HS0_HI);

    // ---------------- geo encoder (fp32, K=6) -> HCAT[:,128:256) ----------------
    dim3 genc(cdiv(Nn, 64), 2, 1);
    hipMemsetAsync(STATS, 0, 2 * sizeof(float), stream);
    sgemm_k<true, true, true><<<genc, 256, 0, stream>>>(x_geom, geo_W, geo_b, HCAT + 128, Nn, 6, 128, FD, STATS);
    enc_norm_k<<<cdiv(Nn * 32, 256), 256, 0, stream>>>(HCAT + 128, geo_lnw, geo_lnb, STATS, 1.f / ((float)Nn * 128.f), HS0_HI + 128);

    for (int t = 0; t < 2; t++) {
        // prior encoder (fp32, K=33) -> HCAT[:,256:384)
        const float* pin = t ? PRIOR : x_prior;
        hipMemsetAsync(STATS, 0, 2 * sizeof(float), stream);
        sgemm_k<true, true, true><<<genc, 256, 0, stream>>>(pin, pri_W, pri_b, HCAT + 256, Nn, 33, 128, FD, STATS);
        enc_norm_k<<<cdiv(Nn * 32, 256), 256, 0, stream>>>(HCAT + 256, pri_lnw, pri_lnb, STATS, 1.f / ((float)Nn * 128.f), HS0_HI + 256);

        for (int L = 0; L < 2; L++) {
            const u16* ahi = L ? HS1_HI : HS0_HI;     // normalized input (bf16)
            u16* yout = L ? YB1 : YB0;                // aggr out (bf16 pre-norm)
            // XR = A @ W^T, pure bf16 (TERMS=1), bf16 out, XCD-swizzled grid
            mgemm_k<false, false, false, true, 1, true><<<dim3(XRBLK, 1, 1), 256, 0, stream>>>(
                ahi, ahi, RW_HI + (size_t)L * 3 * 384 * 384, RW_LO,
                nullptr, XR16, Nn, 384, FD, 384 * 384, nullptr);
            // QIK = HS @ W2^T (replaces per-XR projection; reads 15.4MB not 46MB)
            projh_k<<<MB, 256, 0, stream>>>(ahi,
                W2_HI + (size_t)L * 48 * 384, W2_LO + (size_t)L * 48 * 384, QIK);
            hipMemsetAsync(GSUM, 0, 128 * sizeof(float), stream);  // GSUM+GSQ contiguous
            aggr_k<<<cdiv(Nn, 4), 256, 0, stream>>>(XR16, QIK, ROWPTR, EIDX, rgat_bias[L],
                                                    ahi, batch, yout, GSUM, GSQ);
            if (L == 0)
                gnorm_split_k<false><<<cdiv(Nn * 96, 256), 256, 0, stream>>>(
                    YB0, batch, GSUM, GSQ, GCNT, ln_w[0], ln_b[0], HS1_HI, HS1_LO);
            else
                gnorm_split_k<true><<<cdiv(Nn * 96, 256), 256, 0, stream>>>(
                    YB1, batch, GSUM, GSQ, GCNT, ln_w[1], ln_b[1], HS2_HI, HS2_LO);
        }

        // classifier: cls1 (MFMA TERMS=3, reads HS2 hi+lo) -> CLSH, cls2 (fp32) -> OUT
        mgemm_k<true, true, false, false, 3, false><<<dim3(MB, 1, 1), 256, 0, stream>>>(
            HS2_HI, HS2_LO, CW_HI, CW_LO, cls_b1, CLSH, Nn, 384, 128, 0, nullptr);
        sgemm_k<true, false, false><<<dim3(cdiv(Nn, 64), 1, 1), 256, 0, stream>>>(
            CLSH, cls_W2, cls_b2, OUT, Nn, 128, 32, 32, nullptr);

        if (t == 0)
            softmax_prior_k<<<cdiv(Nn, 8), 256, 0, stream>>>(OUT, PRIOR);
    }
}

// Round 13
// 738.057 us; speedup vs baseline: 1.9179x; 1.0436x over previous
//
#include <hip/hip_runtime.h>
#include <hip/hip_bf16.h>

#define Nn 20000
#define EREL 60000
#define ETOT 180000
#define NG 64
#define FD 384
#define EPS 1e-5f

typedef unsigned short u16;
typedef unsigned int u32;
typedef __attribute__((ext_vector_type(8))) short s8v;     // 8 bf16 (4 VGPR) MFMA A/B frag
typedef __attribute__((ext_vector_type(4))) float f4v;     // MFMA C/D frag

static inline int cdiv(int a, int b) { return (a + b - 1) / b; }

__device__ inline u16 f2b(float f) {
    __hip_bfloat16 h = __float2bfloat16(f);
    union { __hip_bfloat16 b; u16 u; } c; c.b = h; return c.u;
}
__device__ inline float b2f(u16 u) {
    union { __hip_bfloat16 b; u16 u; } c; c.u = u; return __bfloat162float(c.b);
}

// transpose + split: W[b][K][N] -> T[b][N][K] hi(/lo)
template<bool WLO>
__global__ void tsplit_k(const float* __restrict__ W, u16* __restrict__ hi,
                         u16* __restrict__ lo, int K, int N, int total)
{
    int idx = blockIdx.x * 256 + threadIdx.x;
    if (idx >= total) return;
    int kn = K * N;
    int b = idx / kn, rem = idx - b * kn;
    int k = rem / N, n = rem - k * N;
    float v = W[idx];
    u16 h = f2b(v);
    int o = b * kn + n * K + k;
    hi[o] = h;
    if (WLO) lo[o] = f2b(v - b2f(h));
}

// W2T[L][r*16+c][kin] = sum_d W[L][r][kin][d] * (c<8 ? q[d][c] : k[d][c-8])
// one wave per (L,r,kin) row; hi/lo bf16 output.
__global__ __launch_bounds__(256) void w2_k(const float* __restrict__ W0,
    const float* __restrict__ q0, const float* __restrict__ k0,
    const float* __restrict__ W1, const float* __restrict__ q1, const float* __restrict__ k1,
    u16* __restrict__ hi, u16* __restrict__ lo)
{
    int row = blockIdx.x * 4 + (threadIdx.x >> 6);   // 2304 rows
    int lane = threadIdx.x & 63;
    if (row >= 2304) return;
    int kin = row % 384;
    int lr3 = row / 384;
    int L = lr3 / 3, r = lr3 - L * 3;
    const float* W = (L ? W1 : W0) + ((size_t)r * 384 + kin) * 384;
    const float* qm = L ? q1 : q0;
    const float* km = L ? k1 : k0;
    float pq[16] = {};
    #pragma unroll
    for (int j = 0; j < 6; j++) {
        int d = lane + 64 * j;
        float x = W[d];
        #pragma unroll
        for (int h = 0; h < 8; h++) {
            pq[h]     = fmaf(x, qm[d * 8 + h], pq[h]);
            pq[8 + h] = fmaf(x, km[d * 8 + h], pq[8 + h]);
        }
    }
    #pragma unroll
    for (int o = 32; o; o >>= 1) {
        #pragma unroll
        for (int h = 0; h < 16; h++) pq[h] += __shfl_down(pq[h], o);
    }
    if (lane == 0) {
        #pragma unroll
        for (int c = 0; c < 16; c++) {
            u16 hh = f2b(pq[c]);
            size_t o = ((size_t)L * 48 + r * 16 + c) * 384 + kin;
            hi[o] = hh; lo[o] = f2b(pq[c] - b2f(hh));
        }
    }
}

// ---------------- small-K encoder GEMM: out[n, 0:128) = relu(x[n,:K] @ W[K,128] + b) ----
// W staged in LDS once per block; 4 waves x 8 rows; bf16 out (col block of HENC, ld=FD);
// accumulates global sum/sumsq into stats.
__global__ __launch_bounds__(256) void enc_gemm_k(const float* __restrict__ x, int K,
    const float* __restrict__ W, const float* __restrict__ bias,
    u16* __restrict__ out, float* __restrict__ stats)
{
    __shared__ float Wl[33 * 128];
    __shared__ float bl[128];
    __shared__ float red[8];
    int t = threadIdx.x;
    for (int i = t; i < K * 128; i += 256) Wl[i] = W[i];
    if (t < 128) bl[t] = bias[t];
    __syncthreads();
    int wid = t >> 6, lane = t & 63;
    float s1 = 0.f, s2 = 0.f;
    for (int rr = 0; rr < 8; rr++) {
        int n = blockIdx.x * 32 + wid * 8 + rr;
        if (n >= Nn) break;
        float xv = (lane < K) ? x[(size_t)n * K + lane] : 0.f;
        float a0 = 0.f, a1 = 0.f;
        for (int k = 0; k < K; k++) {
            float xk = __shfl(xv, k);
            a0 = fmaf(xk, Wl[k * 128 + 2 * lane], a0);
            a1 = fmaf(xk, Wl[k * 128 + 2 * lane + 1], a1);
        }
        a0 = fmaxf(a0 + bl[2 * lane], 0.f);
        a1 = fmaxf(a1 + bl[2 * lane + 1], 0.f);
        ((u32*)(out + (size_t)n * FD))[lane] = (u32)f2b(a0) | ((u32)f2b(a1) << 16);
        s1 += a0 + a1; s2 += a0 * a0 + a1 * a1;
    }
    #pragma unroll
    for (int o = 32; o; o >>= 1) { s1 += __shfl_down(s1, o); s2 += __shfl_down(s2, o); }
    if (lane == 0) { red[wid] = s1; red[4 + wid] = s2; }
    __syncthreads();
    if (t == 0) atomicAdd(&stats[0], red[0] + red[1] + red[2] + red[3]);
    if (t == 1) atomicAdd(&stats[1], red[4] + red[5] + red[6] + red[7]);
}

// ---------------- split-bf16 MFMA GEMM ----------------
// C[M,N] = A[M,K] @ B[N,K]^T. TERMS=1: ah*bh. TERMS=2: +al*bh. TERMS=3: +ah*bl.
// AF32: A read as fp32 (Af), converted to bf16 in-reg during staging (TERMS must be 1).
// SWZ: XCD-aware grid for the XR shape.
#define USEI(i) ((i) < 2 || ((i) >= 4 && (i) < 6) || (TERMS >= 2 && ((i) == 2 || (i) == 3)) || (TERMS >= 3 && (i) >= 6))
template<bool BIAS, bool RELU, bool STATS, bool OB16, int TERMS, bool SWZ, bool AF32>
__global__ __launch_bounds__(256) void mgemm_k(
    const u16* __restrict__ Ahi, const u16* __restrict__ Alo, const float* __restrict__ Af,
    const u16* __restrict__ Bhi, const u16* __restrict__ Blo,
    const float* __restrict__ bias, void* __restrict__ Cv,
    int M, int K, int ldc, int bstride, float* __restrict__ stats)
{
    __shared__ u16 lds[4 * 128 * 32];
    __shared__ float red[256];
    const int t = threadIdx.x;
    int brow, bcol, z;
    if (SWZ) {
        int d = blockIdx.x;
        int xcd = d & 7, s = d >> 3;
        int row = xcd + 8 * (s / 9);
        int c = s % 9;
        brow = row * 128;
        if (brow >= M) return;
        bcol = (c % 3) * 128;
        z = c / 3;
    } else {
        brow = blockIdx.x * 128; bcol = blockIdx.y * 128; z = blockIdx.z;
    }
    Bhi += (size_t)z * bstride;
    Blo += (size_t)z * bstride;
    float* Cf = OB16 ? nullptr : (float*)Cv + (size_t)z * M * ldc;
    u16*   Ch = OB16 ? (u16*)Cv + (size_t)z * M * ldc : nullptr;

    const int r0 = t >> 2, sl = t & 3;
    const int rA0 = min(brow + r0, M - 1);
    const int rA1 = min(brow + r0 + 64, M - 1);
    const u16* gsrc[8];
    gsrc[0] = Ahi + (size_t)rA0 * K + sl * 8;
    gsrc[1] = Ahi + (size_t)rA1 * K + sl * 8;
    gsrc[2] = Alo + (size_t)rA0 * K + sl * 8;
    gsrc[3] = Alo + (size_t)rA1 * K + sl * 8;
    gsrc[4] = Bhi + (size_t)(bcol + r0) * K + sl * 8;
    gsrc[5] = Bhi + (size_t)(bcol + r0 + 64) * K + sl * 8;
    gsrc[6] = Blo + (size_t)(bcol + r0) * K + sl * 8;
    gsrc[7] = Blo + (size_t)(bcol + r0 + 64) * K + sl * 8;
    const float* afsrc[2];
    if (AF32) {
        afsrc[0] = Af + (size_t)rA0 * K + sl * 8;
        afsrc[1] = Af + (size_t)rA1 * K + sl * 8;
    }
    const int swz = (sl ^ (r0 & 3)) << 3;
    int ldst[8];
    #pragma unroll
    for (int i = 0; i < 8; i++) {
        int tile = i >> 1, row = r0 + 64 * (i & 1);
        ldst[i] = tile * 4096 + row * 32 + swz;
    }

    const int l = t & 63, w = t >> 6;
    const int wr = (w >> 1) * 64, wc = (w & 1) * 64;
    const int lr = l & 15, kq = l >> 4;

    f4v acc[4][4] = {};
    const int NK = K >> 5;

    #define LDA32(i, ko) ({ \
        float4 f0_ = *(const float4*)(afsrc[i] + (ko)); \
        float4 f1_ = *(const float4*)(afsrc[i] + (ko) + 4); \
        s8v r_; \
        r_[0] = (short)f2b(f0_.x); r_[1] = (short)f2b(f0_.y); \
        r_[2] = (short)f2b(f0_.z); r_[3] = (short)f2b(f0_.w); \
        r_[4] = (short)f2b(f1_.x); r_[5] = (short)f2b(f1_.y); \
        r_[6] = (short)f2b(f1_.z); r_[7] = (short)f2b(f1_.w); \
        r_; })

    s8v stg[8];
    #pragma unroll
    for (int i = 0; i < 8; i++) {
        if (AF32 && i < 2) stg[i] = LDA32(i, 0);
        else if (!(AF32 && i < 2) && USEI(i)) stg[i] = *(const s8v*)gsrc[i];
    }

    for (int kc = 0; kc < NK; kc++) {
        if (kc) __syncthreads();
        #pragma unroll
        for (int i = 0; i < 8; i++) if (USEI(i)) *(s8v*)(lds + ldst[i]) = stg[i];
        __syncthreads();
        if (kc + 1 < NK) {
            const int ko = (kc + 1) * 32;
            #pragma unroll
            for (int i = 0; i < 8; i++) {
                if (AF32 && i < 2) stg[i] = LDA32(i, ko);
                else if (!(AF32 && i < 2) && USEI(i)) stg[i] = *(const s8v*)(gsrc[i] + ko);
            }
        }
        #define LDR(T, row) (*(const s8v*)(lds + (T) * 4096 + (row) * 32 + ((kq ^ ((row) & 3)) << 3)))
        s8v bh[4], bl[4];
        #pragma unroll
        for (int tn = 0; tn < 4; tn++) {
            int rb = wc + tn * 16 + lr;
            bh[tn] = LDR(2, rb);
            if (TERMS >= 3) bl[tn] = LDR(3, rb);
        }
        #pragma unroll
        for (int tm = 0; tm < 4; tm++) {
            int ra = wr + tm * 16 + lr;
            s8v ah = LDR(0, ra);
            s8v al;
            if (TERMS >= 2) al = LDR(1, ra);
            #pragma unroll
            for (int tn = 0; tn < 4; tn++) {
                acc[tm][tn] = __builtin_amdgcn_mfma_f32_16x16x32_bf16(ah, bh[tn], acc[tm][tn], 0, 0, 0);
                if (TERMS >= 2)
                    acc[tm][tn] = __builtin_amdgcn_mfma_f32_16x16x32_bf16(al, bh[tn], acc[tm][tn], 0, 0, 0);
                if (TERMS >= 3)
                    acc[tm][tn] = __builtin_amdgcn_mfma_f32_16x16x32_bf16(ah, bl[tn], acc[tm][tn], 0, 0, 0);
            }
        }
        #undef LDR
    }
    #undef LDA32

    float s1 = 0.f, s2 = 0.f;
    #pragma unroll
    for (int tm = 0; tm < 4; tm++) {
        #pragma unroll
        for (int rg = 0; rg < 4; rg++) {
            int row = brow + wr + tm * 16 + kq * 4 + rg;
            if (row < M) {
                #pragma unroll
                for (int tn = 0; tn < 4; tn++) {
                    int col = bcol + wc + tn * 16 + lr;
                    float v = acc[tm][tn][rg];
                    if (BIAS) v += bias[col];
                    if (RELU) v = fmaxf(v, 0.f);
                    if (OB16) Ch[(size_t)row * ldc + col] = f2b(v);
                    else      Cf[(size_t)row * ldc + col] = v;
                    if (STATS) { s1 += v; s2 += v * v; }
                }
            }
        }
    }
    if (STATS) {
        __syncthreads();
        red[t] = s1; __syncthreads();
        for (int o = 128; o; o >>= 1) { if (t < o) red[t] += red[t + o]; __syncthreads(); }
        if (t == 0) atomicAdd(&stats[0], red[0]);
        __syncthreads();
        red[t] = s2; __syncthreads();
        for (int o = 128; o; o >>= 1) { if (t < o) red[t] += red[t + o]; __syncthreads(); }
        if (t == 0) atomicAdd(&stats[1], red[0]);
    }
}
#undef USEI

// ---------------- projh GEMM: QIK[Nn,48] = HS(bf16) @ W2T[48,384]^T (2-term B split) ----
__global__ __launch_bounds__(256) void projh_k(const u16* __restrict__ hs,
    const u16* __restrict__ w2hi, const u16* __restrict__ w2lo, float* __restrict__ qik)
{
    __shared__ u16 a_lds[128 * 32];
    __shared__ u16 b_lds[2][48 * 392];
    int t = threadIdx.x;
    int brow = blockIdx.x * 128;

    for (int i = t; i < 2304; i += 256) {
        int col = i / 48, c8 = (i - col * 48) * 8;
        *(s8v*)&b_lds[0][col * 392 + c8] = *(const s8v*)(w2hi + col * 384 + c8);
        *(s8v*)&b_lds[1][col * 392 + c8] = *(const s8v*)(w2lo + col * 384 + c8);
    }

    int ar = t >> 1, sl0 = (t & 1) * 2;
    int grow = min(brow + ar, Nn - 1);
    const u16* asrc = hs + (size_t)grow * FD;
    int adst0 = ar * 32 + ((sl0 ^ (ar & 3)) << 3);
    int adst1 = ar * 32 + (((sl0 + 1) ^ (ar & 3)) << 3);

    int l = t & 63, w = t >> 6;
    int lr = l & 15, kq = l >> 4;
    f4v acc[2][3] = {};

    s8v stg0 = *(const s8v*)(asrc + sl0 * 8);
    s8v stg1 = *(const s8v*)(asrc + sl0 * 8 + 8);
    for (int kc = 0; kc < 12; kc++) {
        if (kc) __syncthreads();
        *(s8v*)&a_lds[adst0] = stg0;
        *(s8v*)&a_lds[adst1] = stg1;
        __syncthreads();
        if (kc + 1 < 12) {
            int ko = (kc + 1) * 32 + sl0 * 8;
            stg0 = *(const s8v*)(asrc + ko);
            stg1 = *(const s8v*)(asrc + ko + 8);
        }
        s8v bh[3], bl[3];
        #pragma unroll
        for (int cf = 0; cf < 3; cf++) {
            bh[cf] = *(const s8v*)&b_lds[0][(cf * 16 + lr) * 392 + kc * 32 + kq * 8];
            bl[cf] = *(const s8v*)&b_lds[1][(cf * 16 + lr) * 392 + kc * 32 + kq * 8];
        }
        #pragma unroll
        for (int rf = 0; rf < 2; rf++) {
            int rr = w * 32 + rf * 16 + lr;
            s8v a = *(const s8v*)&a_lds[rr * 32 + ((kq ^ (rr & 3)) << 3)];
            #pragma unroll
            for (int cf = 0; cf < 3; cf++) {
                acc[rf][cf] = __builtin_amdgcn_mfma_f32_16x16x32_bf16(a, bh[cf], acc[rf][cf], 0, 0, 0);
                acc[rf][cf] = __builtin_amdgcn_mfma_f32_16x16x32_bf16(a, bl[cf], acc[rf][cf], 0, 0, 0);
            }
        }
    }
    #pragma unroll
    for (int rf = 0; rf < 2; rf++)
        #pragma unroll
        for (int cf = 0; cf < 3; cf++)
            #pragma unroll
            for (int rg = 0; rg < 4; rg++) {
                int row = brow + w * 32 + rf * 16 + kq * 4 + rg;
                if (row < Nn) qik[(size_t)row * 48 + cf * 16 + lr] = acc[rf][cf][rg];
            }
}

// ---------------- fp32 tiled GEMM (cls2: K=128, N=32) ----------------
template<bool BIAS, bool RELU>
__global__ __launch_bounds__(256) void sgemm_k(
    const float* __restrict__ A, const float* __restrict__ B,
    const float* __restrict__ bias, float* __restrict__ C,
    int M, int K, int N, int ldc)
{
    const int BK = 16;
    __shared__ float As[16][65];
    __shared__ float Bs[16][64];
    int tid = threadIdx.x;
    int tx = tid & 15, ty = tid >> 4;
    int brow = blockIdx.x * 64, bcol = blockIdx.y * 64;
    float acc[4][4] = {};
    for (int k0 = 0; k0 < K; k0 += BK) {
        #pragma unroll
        for (int i = 0; i < 4; i++) {
            int e = tid + 256 * i;
            int ar = e >> 4, ak = e & 15;
            int gr = brow + ar, gk = k0 + ak;
            As[ak][ar] = (gr < M && gk < K) ? A[(size_t)gr * K + gk] : 0.f;
            int bk = e >> 6, bn = e & 63;
            int gbk = k0 + bk, gbn = bcol + bn;
            Bs[bk][bn] = (gbk < K && gbn < N) ? B[(size_t)gbk * N + gbn] : 0.f;
        }
        __syncthreads();
        #pragma unroll
        for (int k = 0; k < BK; k++) {
            float ra[4], rb[4];
            #pragma unroll
            for (int i = 0; i < 4; i++) ra[i] = As[k][ty * 4 + i];
            #pragma unroll
            for (int j = 0; j < 4; j++) rb[j] = Bs[k][tx * 4 + j];
            #pragma unroll
            for (int i = 0; i < 4; i++)
                #pragma unroll
                for (int j = 0; j < 4; j++)
                    acc[i][j] = fmaf(ra[i], rb[j], acc[i][j]);
        }
        __syncthreads();
    }
    #pragma unroll
    for (int i = 0; i < 4; i++) {
        int row = brow + ty * 4 + i;
        #pragma unroll
        for (int j = 0; j < 4; j++) {
            int col = bcol + tx * 4 + j;
            if (row < M && col < N) {
                float v = acc[i][j];
                if (BIAS) v += bias[col];
                if (RELU) v = v > 0.f ? v : 0.f;
                C[(size_t)row * ldc + col] = v;
            }
        }
    }
}

// scalar-LN of a 128-col block (bf16 pre-norm, pre-offset) from RAW sums -> bf16 hi
__global__ __launch_bounds__(256) void enc_norm_k(const u16* __restrict__ H,
                           const float* __restrict__ w, const float* __restrict__ b,
                           const float* __restrict__ stats, float cntinv, u16* __restrict__ hi)
{
    int i = blockIdx.x * 256 + threadIdx.x;   // 4-elem group within col block
    if (i >= Nn * 32) return;
    int n = i >> 5, c4 = i & 31;
    float m = stats[0] * cntinv;
    float var = stats[1] * cntinv - m * m;
    float s = 1.f / (sqrtf(fmaxf(var, 0.f)) + EPS);
    float4 wv = ((const float4*)w)[c4];
    float4 bv = ((const float4*)b)[c4];
    uint2 yv = ((const uint2*)(H + (size_t)n * FD))[c4];
    ushort4 hh;
    hh.x = f2b((b2f((u16)(yv.x & 0xffffu)) - m) * s * wv.x + bv.x);
    hh.y = f2b((b2f((u16)(yv.x >> 16))     - m) * s * wv.y + bv.y);
    hh.z = f2b((b2f((u16)(yv.y & 0xffffu)) - m) * s * wv.z + bv.z);
    hh.w = f2b((b2f((u16)(yv.y >> 16))     - m) * s * wv.w + bv.w);
    ((ushort4*)(hi + (size_t)n * FD))[c4] = hh;
}

__global__ void edge_count_k(const int* __restrict__ e0, const int* __restrict__ e1,
                             const int* __restrict__ e2, int* __restrict__ cnt)
{
    int e = blockIdx.x * 256 + threadIdx.x;
    if (e >= ETOT) return;
    int r = e / EREL, i = e - r * EREL;
    const int* ei = (r == 0) ? e0 : (r == 1) ? e1 : e2;
    atomicAdd(&cnt[ei[EREL + i]], 1);
}

__global__ void edge_fill_k(const int* __restrict__ e0, const int* __restrict__ e1,
                            const int* __restrict__ e2, int* __restrict__ cursor,
                            int* __restrict__ eidx)
{
    int e = blockIdx.x * 256 + threadIdx.x;
    if (e >= ETOT) return;
    int r = e / EREL, i = e - r * EREL;
    const int* ei = (r == 0) ? e0 : (r == 1) ? e1 : e2;
    int src = ei[i], dst = ei[EREL + i];
    int pos = atomicAdd(&cursor[dst], 1);
    eidx[pos] = src | (r << 24);
}

// exclusive scan via per-wave shuffle scan + 16-wave LDS combine
__global__ __launch_bounds__(1024) void scan_k(const int* __restrict__ cnt,
                                               int* __restrict__ rowptr, int* __restrict__ cursor)
{
    __shared__ int wsum[16], wpre[16];
    __shared__ int carry, tot;
    int t = threadIdx.x, lane = t & 63, wid = t >> 6;
    if (t == 0) carry = 0;
    __syncthreads();
    for (int base = 0; base < Nn; base += 1024) {
        int i = base + t;
        int v = (i < Nn) ? cnt[i] : 0;
        int s = v;
        #pragma unroll
        for (int o = 1; o < 64; o <<= 1) {
            int x = __shfl_up(s, o);
            if (lane >= o) s += x;
        }
        if (lane == 63) wsum[wid] = s;
        __syncthreads();
        if (t < 16) {
            int wv = wsum[t];
            int ws = wv;
            #pragma unroll
            for (int o = 1; o < 16; o <<= 1) {
                int x = __shfl_up(ws, o);
                if (t >= o) ws += x;
            }
            wpre[t] = ws - wv;
            if (t == 15) tot = ws;
        }
        __syncthreads();
        if (i < Nn) {
            int ex = carry + wpre[wid] + s - v;
            rowptr[i] = ex; cursor[i] = ex;
        }
        __syncthreads();
        if (t == 0) carry += tot;
    }
    __syncthreads();
    if (t == 0) rowptr[Nn] = carry;
}

// per-graph node counts via LDS histogram
__global__ __launch_bounds__(256) void gcount_k(const int* __restrict__ batch, int* __restrict__ gcnt)
{
    __shared__ int bins[NG];
    int t = threadIdx.x;
    if (t < NG) bins[t] = 0;
    __syncthreads();
    int n = blockIdx.x * 256 + t;
    if (n < Nn) atomicAdd(&bins[batch[n]], 1);
    __syncthreads();
    if (t < NG && bins[t]) atomicAdd(&gcnt[t], bins[t]);
}

// RGAT aggregation, softmax fused (QIK[n][48]: q=r*16+h, k=r*16+8+h). One wave per node,
// 4x edge unroll, dwordx3 row gather, fused elu/residual/stats.
__global__ __launch_bounds__(256) void aggr_k(const u16* __restrict__ xr,
    const float* __restrict__ qik, const int* __restrict__ rowptr, const int* __restrict__ eidx,
    const float* __restrict__ bias, const u16* __restrict__ hinb,
    const int* __restrict__ batch, u16* __restrict__ outb,
    float* __restrict__ gsum, float* __restrict__ gsq)
{
    __shared__ float ls[NG], lq[NG];
    int t = threadIdx.x;
    if (t < NG) { ls[t] = 0.f; lq[t] = 0.f; }
    __syncthreads();
    int node = blockIdx.x * 4 + (t >> 6);
    int lane = t & 63;
    int e0 = rowptr[node], e1 = rowptr[node + 1];
    int hd = lane >> 3;
    float qv = (lane < 48) ? qik[(size_t)node * 48 + lane] : 0.f;
    float den = 0.f;
    float acc[6] = {};

    int e = e0;
    while (e + 4 <= e1) {
        int p0 = eidx[e], p1 = eidx[e + 1], p2 = eidx[e + 2], p3 = eidx[e + 3];
        int n0 = p0 & 0xFFFFFF, et0 = p0 >> 24;
        int n1 = p1 & 0xFFFFFF, et1 = p1 >> 24;
        int n2 = p2 & 0xFFFFFF, et2 = p2 >> 24;
        int n3 = p3 & 0xFFFFFF, et3 = p3 >> 24;
        float kv0 = (lane < 8) ? qik[(size_t)n0 * 48 + et0 * 16 + 8 + lane] : 0.f;
        float kv1 = (lane < 8) ? qik[(size_t)n1 * 48 + et1 * 16 + 8 + lane] : 0.f;
        float kv2 = (lane < 8) ? qik[(size_t)n2 * 48 + et2 * 16 + 8 + lane] : 0.f;
        float kv3 = (lane < 8) ? qik[(size_t)n3 * 48 + et3 * 16 + 8 + lane] : 0.f;
        const u32* r0 = (const u32*)(xr + ((size_t)et0 * Nn + n0) * FD);
        const u32* r1 = (const u32*)(xr + ((size_t)et1 * Nn + n1) * FD);
        const u32* r2 = (const u32*)(xr + ((size_t)et2 * Nn + n2) * FD);
        const u32* r3 = (const u32*)(xr + ((size_t)et3 * Nn + n3) * FD);
        u32 u0[3], u1[3], u2[3], u3[3];
        #pragma unroll
        for (int j = 0; j < 3; j++) u0[j] = r0[lane * 3 + j];
        #pragma unroll
        for (int j = 0; j < 3; j++) u1[j] = r1[lane * 3 + j];
        #pragma unroll
        for (int j = 0; j < 3; j++) u2[j] = r2[lane * 3 + j];
        #pragma unroll
        for (int j = 0; j < 3; j++) u3[j] = r3[lane * 3 + j];
        float qq0 = __shfl(qv, et0 * 16 + (lane & 7));
        float qq1 = __shfl(qv, et1 * 16 + (lane & 7));
        float qq2 = __shfl(qv, et2 * 16 + (lane & 7));
        float qq3 = __shfl(qv, et3 * 16 + (lane & 7));
        float ex0 = 0.f, ex1 = 0.f, ex2 = 0.f, ex3 = 0.f;
        if (lane < 8) {
            float a0 = qq0 + kv0; a0 = (a0 > 0.f) ? a0 : 0.2f * a0; ex0 = __expf(a0);
            float a1 = qq1 + kv1; a1 = (a1 > 0.f) ? a1 : 0.2f * a1; ex1 = __expf(a1);
            float a2 = qq2 + kv2; a2 = (a2 > 0.f) ? a2 : 0.2f * a2; ex2 = __expf(a2);
            float a3 = qq3 + kv3; a3 = (a3 > 0.f) ? a3 : 0.2f * a3; ex3 = __expf(a3);
        }
        den += ex0 + ex1 + ex2 + ex3;
        float w0 = __shfl(ex0, hd), w1 = __shfl(ex1, hd);
        float w2 = __shfl(ex2, hd), w3 = __shfl(ex3, hd);
        #pragma unroll
        for (int j = 0; j < 3; j++) {
            acc[2*j]   = fmaf(w0, __uint_as_float(u0[j] << 16), acc[2*j]);
            acc[2*j+1] = fmaf(w0, __uint_as_float(u0[j] & 0xffff0000u), acc[2*j+1]);
            acc[2*j]   = fmaf(w1, __uint_as_float(u1[j] << 16), acc[2*j]);
            acc[2*j+1] = fmaf(w1, __uint_as_float(u1[j] & 0xffff0000u), acc[2*j+1]);
            acc[2*j]   = fmaf(w2, __uint_as_float(u2[j] << 16), acc[2*j]);
            acc[2*j+1] = fmaf(w2, __uint_as_float(u2[j] & 0xffff0000u), acc[2*j+1]);
            acc[2*j]   = fmaf(w3, __uint_as_float(u3[j] << 16), acc[2*j]);
            acc[2*j+1] = fmaf(w3, __uint_as_float(u3[j] & 0xffff0000u), acc[2*j+1]);
        }
        e += 4;
    }
    for (; e < e1; e++) {
        int p = eidx[e];
        int sn = p & 0xFFFFFF, et = p >> 24;
        float kv = (lane < 8) ? qik[(size_t)sn * 48 + et * 16 + 8 + lane] : 0.f;
        const u32* rr = (const u32*)(xr + ((size_t)et * Nn + sn) * FD);
        u32 u[3];
        #pragma unroll
        for (int j = 0; j < 3; j++) u[j] = rr[lane * 3 + j];
        float qq = __shfl(qv, et * 16 + (lane & 7));
        float ex = 0.f;
        if (lane < 8) { float a = qq + kv; a = (a > 0.f) ? a : 0.2f * a; ex = __expf(a); }
        den += ex;
        float wv_ = __shfl(ex, hd);
        #pragma unroll
        for (int j = 0; j < 3; j++) {
            acc[2*j]   = fmaf(wv_, __uint_as_float(u[j] << 16), acc[2*j]);
            acc[2*j+1] = fmaf(wv_, __uint_as_float(u[j] & 0xffff0000u), acc[2*j+1]);
        }
    }

    float dh = __shfl(den, hd);
    float rcp = 1.f / (dh + 1e-16f);
    const u32* hp = (const u32*)(hinb + (size_t)node * FD);
    u32* op = (u32*)(outb + (size_t)node * FD);
    float s1 = 0.f, s2 = 0.f;
    #pragma unroll
    for (int j = 0; j < 3; j++) {
        int c = lane * 6 + 2 * j;
        float2 bv = *(const float2*)(bias + c);
        u32 hb = hp[lane * 3 + j];
        float vx = acc[2*j] * rcp + bv.x;
        float vy = acc[2*j+1] * rcp + bv.y;
        vx = (vx > 0.f) ? vx : expm1f(vx);
        vy = (vy > 0.f) ? vy : expm1f(vy);
        vx += b2f((u16)(hb & 0xffffu));
        vy += b2f((u16)(hb >> 16));
        op[lane * 3 + j] = (u32)f2b(vx) | ((u32)f2b(vy) << 16);
        s1 += vx + vy; s2 += vx * vx + vy * vy;
    }
    #pragma unroll
    for (int o = 32; o; o >>= 1) { s1 += __shfl_down(s1, o); s2 += __shfl_down(s2, o); }
    int g = batch[node];
    if (lane == 0) { atomicAdd(&ls[g], s1); atomicAdd(&lq[g], s2); }
    __syncthreads();
    if (t < NG && (ls[t] != 0.f || lq[t] != 0.f)) {
        atomicAdd(&gsum[t], ls[t]);
        atomicAdd(&gsq[t], lq[t]);
    }
}

// graph-LN from raw sums, bf16 input -> bf16 hi (+lo only for the TERMS=3 cls1 GEMM)
template<bool WLO>
__global__ __launch_bounds__(256) void gnorm_split_k(const u16* __restrict__ yb,
    const int* __restrict__ batch, const float* __restrict__ gsum, const float* __restrict__ gsq,
    const int* __restrict__ gcnt, const float* __restrict__ w, const float* __restrict__ b,
    u16* __restrict__ hi, u16* __restrict__ lo)
{
    int i = blockIdx.x * 256 + threadIdx.x;
    if (i >= Nn * (FD / 4)) return;
    int n = i / 96;
    int c4 = i - n * 96;
    int g = batch[n];
    float norm = fmaxf((float)gcnt[g], 1.f) * (float)FD;
    float m = gsum[g] / norm;
    float var = gsq[g] / norm - m * m;
    float rstd = rsqrtf(var + EPS);
    float4 wv = ((const float4*)w)[c4];
    float4 bv = ((const float4*)b)[c4];
    uint2 yv = ((const uint2*)yb)[i];
    float v0 = (b2f((u16)(yv.x & 0xffffu)) - m) * rstd * wv.x + bv.x;
    float v1 = (b2f((u16)(yv.x >> 16))     - m) * rstd * wv.y + bv.y;
    float v2 = (b2f((u16)(yv.y & 0xffffu)) - m) * rstd * wv.z + bv.z;
    float v3 = (b2f((u16)(yv.y >> 16))     - m) * rstd * wv.w + bv.w;
    ushort4 hh;
    hh.x = f2b(v0); hh.y = f2b(v1); hh.z = f2b(v2); hh.w = f2b(v3);
    ((ushort4*)hi)[i] = hh;
    if (WLO) {
        ushort4 ll;
        ll.x = f2b(v0 - b2f(hh.x));
        ll.y = f2b(v1 - b2f(hh.y));
        ll.z = f2b(v2 - b2f(hh.z));
        ll.w = f2b(v3 - b2f(hh.w));
        ((ushort4*)lo)[i] = ll;
    }
}

__global__ void softmax_prior_k(const float* __restrict__ logits, float* __restrict__ prior)
{
    int n = blockIdx.x * 8 + (threadIdx.x >> 5);
    int l = threadIdx.x & 31;
    if (n >= Nn) return;
    float v = logits[n * 32 + l];
    float m = v;
    #pragma unroll
    for (int o = 16; o; o >>= 1) m = fmaxf(m, __shfl_xor(m, o, 32));
    float e = __expf(v - m);
    float s = e;
    #pragma unroll
    for (int o = 16; o; o >>= 1) s += __shfl_xor(s, o, 32);
    prior[(size_t)n * 33 + l] = e / s;
    if (l == 0) prior[(size_t)n * 33 + 32] = 1.f / s;
}

extern "C" void kernel_launch(void* const* d_in, const int* in_sizes, int n_in,
                              void* d_out, int out_size, void* d_ws, size_t ws_size,
                              hipStream_t stream)
{
    const float* x_visual = (const float*)d_in[0];
    const float* x_geom   = (const float*)d_in[1];
    const float* x_prior  = (const float*)d_in[2];
    const int* ei0   = (const int*)d_in[3];
    const int* ei1   = (const int*)d_in[4];
    const int* ei2   = (const int*)d_in[5];
    const int* batch = (const int*)d_in[6];
    const float* vis_W = (const float*)d_in[7];  const float* vis_b = (const float*)d_in[8];
    const float* vis_lnw = (const float*)d_in[9]; const float* vis_lnb = (const float*)d_in[10];
    const float* geo_W = (const float*)d_in[11]; const float* geo_b = (const float*)d_in[12];
    const float* geo_lnw = (const float*)d_in[13]; const float* geo_lnb = (const float*)d_in[14];
    const float* pri_W = (const float*)d_in[15]; const float* pri_b = (const float*)d_in[16];
    const float* pri_lnw = (const float*)d_in[17]; const float* pri_lnb = (const float*)d_in[18];
    const float* rgat_W[2]    = { (const float*)d_in[19], (const float*)d_in[25] };
    const float* rgat_q[2]    = { (const float*)d_in[20], (const float*)d_in[26] };
    const float* rgat_kk[2]   = { (const float*)d_in[21], (const float*)d_in[27] };
    const float* rgat_bias[2] = { (const float*)d_in[22], (const float*)d_in[28] };
    const float* ln_w[2]      = { (const float*)d_in[23], (const float*)d_in[29] };
    const float* ln_b[2]      = { (const float*)d_in[24], (const float*)d_in[30] };
    const float* cls_W1 = (const float*)d_in[31]; const float* cls_b1 = (const float*)d_in[32];
    const float* cls_W2 = (const float*)d_in[33]; const float* cls_b2 = (const float*)d_in[34];
    float* OUT = (float*)d_out;

    // ---------------- workspace layout ----------------
    float* ws = (float*)d_ws;
    float* XRreg = ws;                         // 3*Nn*FD floats reserved (92.2 MB region)
    u16*   XR16  = (u16*)XRreg;                // XR stored bf16 (46 MB)
    float* HCAT  = XRreg + (size_t)3 * Nn * FD; // region reused: HENC bf16 pre-norm
    u16*   HENC  = (u16*)HCAT;                 // [Nn][384] bf16 pre-norm encoder out
    float* HA    = HCAT + (size_t)Nn * FD;
    float* HB    = HA + (size_t)Nn * FD;
    float* PRIOR = HB + (size_t)Nn * FD;       // Nn*33
    float* QIK   = PRIOR + (size_t)Nn * 33;    // Nn*48
    u16* HS0_HI  = (u16*)(QIK + (size_t)Nn * 48);      // normalized HCAT (bf16)
    u16* HS0_LO  = HS0_HI + (size_t)Nn * FD;           // (dead)
    u16* HS1_HI  = HS0_LO + (size_t)Nn * FD;           // normalized layer-0 out (bf16)
    u16* HS1_LO  = HS1_HI + (size_t)Nn * FD;           // (dead)
    u16* RW_HI   = HS1_LO + (size_t)Nn * FD;   // 2*3*384*384
    u16* RW_LO   = RW_HI + (size_t)2 * 3 * 384 * 384;  // (dead, unwritten)
    u16* VW_HI   = RW_LO + (size_t)2 * 3 * 384 * 384; // 128*1024
    u16* VW_LO   = VW_HI + (size_t)128 * 1024;        // (dead)
    u16* CW_HI   = VW_LO + (size_t)128 * 1024;        // 128*384
    u16* CW_LO   = CW_HI + (size_t)128 * 384;
    u16* W2_HI   = CW_LO + (size_t)128 * 384;         // 2 layers * 48*384
    u16* W2_LO   = W2_HI + (size_t)2 * 48 * 384;
    float* GS    = (float*)(W2_LO + (size_t)2 * 48 * 384); // 4 slots * 128 (sum|sq)
    float* STATS = GS + 512;                   // 4 slots * 2
    int* CNT    = (int*)(STATS + 8);
    int* ROWPTR = CNT + Nn;
    int* CURSOR = ROWPTR + Nn + 1;
    int* EIDX   = CURSOR + Nn;
    int* GCNT   = EIDX + ETOT;
    // aliases (temporally dead sub-ranges):
    float* CLSH = XRreg;                       // classifier hidden [0,10.3MB): after last aggr
    u16* HS2_HI = (u16*)(XRreg + (size_t)12 * 1000 * 1000); // HB split [48MB,78.7MB)
    u16* HS2_LO = HS2_HI + (size_t)Nn * FD;
    u16* YB0 = (u16*)HA;                       // aggr L=0 out (bf16 pre-norm)
    u16* YB1 = (u16*)HB;                       // aggr L=1 out (bf16 pre-norm)

    // ---------------- CSR build (reused by all 4 RGAT calls) ----------------
    hipMemsetAsync(CNT, 0, Nn * sizeof(int), stream);
    edge_count_k<<<cdiv(ETOT, 256), 256, 0, stream>>>(ei0, ei1, ei2, CNT);
    scan_k<<<1, 1024, 0, stream>>>(CNT, ROWPTR, CURSOR);
    edge_fill_k<<<cdiv(ETOT, 256), 256, 0, stream>>>(ei0, ei1, ei2, CURSOR, EIDX);
    hipMemsetAsync(GCNT, 0, 64 * sizeof(int), stream);
    gcount_k<<<cdiv(Nn, 256), 256, 0, stream>>>(batch, GCNT);
    hipMemsetAsync(GS, 0, 520 * sizeof(float), stream);   // GS (4x128) + STATS (4x2)

    // ---------------- weight conversions ----------------
    tsplit_k<false><<<cdiv(3 * 384 * 384, 256), 256, 0, stream>>>(rgat_W[0], RW_HI, RW_LO, 384, 384, 3 * 384 * 384);
    tsplit_k<false><<<cdiv(3 * 384 * 384, 256), 256, 0, stream>>>(rgat_W[1], RW_HI + 3 * 384 * 384, RW_LO, 384, 384, 3 * 384 * 384);
    tsplit_k<false><<<cdiv(1024 * 128, 256), 256, 0, stream>>>(vis_W, VW_HI, VW_LO, 1024, 128, 1024 * 128);
    tsplit_k<true><<<cdiv(384 * 128, 256), 256, 0, stream>>>(cls_W1, CW_HI, CW_LO, 384, 128, 384 * 128);
    w2_k<<<576, 256, 0, stream>>>(rgat_W[0], rgat_q[0], rgat_kk[0],
                                  rgat_W[1], rgat_q[1], rgat_kk[1], W2_HI, W2_LO);

    const int MB = cdiv(Nn, 128);   // 157
    const int XRBLK = 160 * 9;      // padded rows * (3 cols x 3 rels), XCD-swizzled
    const float cinv = 1.f / ((float)Nn * 128.f);

    // ---------------- vis encoder (MFMA TERMS=1, fp32 A staged in-kernel) -> HENC[:,0:128) ----
    mgemm_k<true, true, true, true, 1, false, true><<<dim3(MB, 1, 1), 256, 0, stream>>>(
        nullptr, nullptr, x_visual, VW_HI, VW_LO, vis_b, HENC, Nn, 1024, FD, 0, STATS + 0);
    enc_norm_k<<<cdiv(Nn * 32, 256), 256, 0, stream>>>(HENC, vis_lnw, vis_lnb, STATS + 0, cinv, HS0_HI);

    // ---------------- geo encoder (small-K) -> HENC[:,128:256) ----------------
    enc_gemm_k<<<cdiv(Nn, 32), 256, 0, stream>>>(x_geom, 6, geo_W, geo_b, HENC + 128, STATS + 2);
    enc_norm_k<<<cdiv(Nn * 32, 256), 256, 0, stream>>>(HENC + 128, geo_lnw, geo_lnb, STATS + 2, cinv, HS0_HI + 128);

    for (int t = 0; t < 2; t++) {
        // prior encoder (small-K) -> HENC[:,256:384)
        const float* pin = t ? PRIOR : x_prior;
        enc_gemm_k<<<cdiv(Nn, 32), 256, 0, stream>>>(pin, 33, pri_W, pri_b, HENC + 256, STATS + 4 + 2 * t);
        enc_norm_k<<<cdiv(Nn * 32, 256), 256, 0, stream>>>(HENC + 256, pri_lnw, pri_lnb, STATS + 4 + 2 * t, cinv, HS0_HI + 256);

        for (int L = 0; L < 2; L++) {
            const u16* ahi = L ? HS1_HI : HS0_HI;     // normalized input (bf16)
            u16* yout = L ? YB1 : YB0;                // aggr out (bf16 pre-norm)
            float* gsum = GS + (t * 2 + L) * 128;     // pre-zeroed slot
            // XR = A @ W^T, pure bf16 (TERMS=1), bf16 out, XCD-swizzled grid
            mgemm_k<false, false, false, true, 1, true, false><<<dim3(XRBLK, 1, 1), 256, 0, stream>>>(
                ahi, ahi, nullptr, RW_HI + (size_t)L * 3 * 384 * 384, RW_LO,
                nullptr, XR16, Nn, 384, FD, 384 * 384, nullptr);
            projh_k<<<MB, 256, 0, stream>>>(ahi,
                W2_HI + (size_t)L * 48 * 384, W2_LO + (size_t)L * 48 * 384, QIK);
            aggr_k<<<cdiv(Nn, 4), 256, 0, stream>>>(XR16, QIK, ROWPTR, EIDX, rgat_bias[L],
                                                    ahi, batch, yout, gsum, gsum + 64);
            if (L == 0)
                gnorm_split_k<false><<<cdiv(Nn * 96, 256), 256, 0, stream>>>(
                    YB0, batch, gsum, gsum + 64, GCNT, ln_w[0], ln_b[0], HS1_HI, HS1_LO);
            else
                gnorm_split_k<true><<<cdiv(Nn * 96, 256), 256, 0, stream>>>(
                    YB1, batch, gsum, gsum + 64, GCNT, ln_w[1], ln_b[1], HS2_HI, HS2_LO);
        }

        // classifier: cls1 (MFMA TERMS=3, reads HS2 hi+lo) -> CLSH, cls2 (fp32) -> OUT
        mgemm_k<true, true, false, false, 3, false, false><<<dim3(MB, 1, 1), 256, 0, stream>>>(
            HS2_HI, HS2_LO, nullptr, CW_HI, CW_LO, cls_b1, CLSH, Nn, 384, 128, 0, nullptr);
        sgemm_k<true, false><<<dim3(cdiv(Nn, 64), 1, 1), 256, 0, stream>>>(
            CLSH, cls_W2, cls_b2, OUT, Nn, 128, 32, 32);

        if (t == 0)
            softmax_prior_k<<<cdiv(Nn, 8), 256, 0, stream>>>(OUT, PRIOR);
    }
}

// Round 14
// 679.733 us; speedup vs baseline: 2.0825x; 1.0858x over previous
//
#include <hip/hip_runtime.h>
#include <hip/hip_bf16.h>

#define Nn 20000
#define EREL 60000
#define ETOT 180000
#define NG 64
#define FD 384
#define EPS 1e-5f

typedef unsigned short u16;
typedef unsigned int u32;
typedef __attribute__((ext_vector_type(8))) short s8v;     // 8 bf16 (4 VGPR) MFMA A/B frag
typedef __attribute__((ext_vector_type(4))) float f4v;     // MFMA C/D frag

static inline int cdiv(int a, int b) { return (a + b - 1) / b; }

__device__ inline u16 f2b(float f) {
    __hip_bfloat16 h = __float2bfloat16(f);
    union { __hip_bfloat16 b; u16 u; } c; c.b = h; return c.u;
}
__device__ inline float b2f(u16 u) {
    union { __hip_bfloat16 b; u16 u; } c; c.u = u; return __bfloat162float(c.b);
}

// transpose + split: W[b][K][N] -> T[b][N][K] hi(/lo)
template<bool WLO>
__global__ void tsplit_k(const float* __restrict__ W, u16* __restrict__ hi,
                         u16* __restrict__ lo, int K, int N, int total)
{
    int idx = blockIdx.x * 256 + threadIdx.x;
    if (idx >= total) return;
    int kn = K * N;
    int b = idx / kn, rem = idx - b * kn;
    int k = rem / N, n = rem - k * N;
    float v = W[idx];
    u16 h = f2b(v);
    int o = b * kn + n * K + k;
    hi[o] = h;
    if (WLO) lo[o] = f2b(v - b2f(h));
}

// W2T[L][r*16+c][kin] = sum_d W[L][r][kin][d] * (c<8 ? q[d][c] : k[d][c-8])
// one wave per (L,r,kin) row; hi/lo bf16 output.
__global__ __launch_bounds__(256) void w2_k(const float* __restrict__ W0,
    const float* __restrict__ q0, const float* __restrict__ k0,
    const float* __restrict__ W1, const float* __restrict__ q1, const float* __restrict__ k1,
    u16* __restrict__ hi, u16* __restrict__ lo)
{
    int row = blockIdx.x * 4 + (threadIdx.x >> 6);   // 2304 rows
    int lane = threadIdx.x & 63;
    if (row >= 2304) return;
    int kin = row % 384;
    int lr3 = row / 384;
    int L = lr3 / 3, r = lr3 - L * 3;
    const float* W = (L ? W1 : W0) + ((size_t)r * 384 + kin) * 384;
    const float* qm = L ? q1 : q0;
    const float* km = L ? k1 : k0;
    float pq[16] = {};
    #pragma unroll
    for (int j = 0; j < 6; j++) {
        int d = lane + 64 * j;
        float x = W[d];
        #pragma unroll
        for (int h = 0; h < 8; h++) {
            pq[h]     = fmaf(x, qm[d * 8 + h], pq[h]);
            pq[8 + h] = fmaf(x, km[d * 8 + h], pq[8 + h]);
        }
    }
    #pragma unroll
    for (int o = 32; o; o >>= 1) {
        #pragma unroll
        for (int h = 0; h < 16; h++) pq[h] += __shfl_down(pq[h], o);
    }
    if (lane == 0) {
        #pragma unroll
        for (int c = 0; c < 16; c++) {
            u16 hh = f2b(pq[c]);
            size_t o = ((size_t)L * 48 + r * 16 + c) * 384 + kin;
            hi[o] = hh; lo[o] = f2b(pq[c] - b2f(hh));
        }
    }
}

// ---------------- small-K encoder GEMM: out[n, 0:128) = relu(x[n,:K] @ W[K,128] + b) ----
__global__ __launch_bounds__(256) void enc_gemm_k(const float* __restrict__ x, int K,
    const float* __restrict__ W, const float* __restrict__ bias,
    u16* __restrict__ out, float* __restrict__ stats)
{
    __shared__ float Wl[33 * 128];
    __shared__ float bl[128];
    __shared__ float red[8];
    int t = threadIdx.x;
    for (int i = t; i < K * 128; i += 256) Wl[i] = W[i];
    if (t < 128) bl[t] = bias[t];
    __syncthreads();
    int wid = t >> 6, lane = t & 63;
    float s1 = 0.f, s2 = 0.f;
    for (int rr = 0; rr < 8; rr++) {
        int n = blockIdx.x * 32 + wid * 8 + rr;
        if (n >= Nn) break;
        float xv = (lane < K) ? x[(size_t)n * K + lane] : 0.f;
        float a0 = 0.f, a1 = 0.f;
        for (int k = 0; k < K; k++) {
            float xk = __shfl(xv, k);
            a0 = fmaf(xk, Wl[k * 128 + 2 * lane], a0);
            a1 = fmaf(xk, Wl[k * 128 + 2 * lane + 1], a1);
        }
        a0 = fmaxf(a0 + bl[2 * lane], 0.f);
        a1 = fmaxf(a1 + bl[2 * lane + 1], 0.f);
        ((u32*)(out + (size_t)n * FD))[lane] = (u32)f2b(a0) | ((u32)f2b(a1) << 16);
        s1 += a0 + a1; s2 += a0 * a0 + a1 * a1;
    }
    #pragma unroll
    for (int o = 32; o; o >>= 1) { s1 += __shfl_down(s1, o); s2 += __shfl_down(s2, o); }
    if (lane == 0) { red[wid] = s1; red[4 + wid] = s2; }
    __syncthreads();
    if (t == 0) atomicAdd(&stats[0], red[0] + red[1] + red[2] + red[3]);
    if (t == 1) atomicAdd(&stats[1], red[4] + red[5] + red[6] + red[7]);
}

// ---------------- split-bf16 MFMA GEMM ----------------
#define USEI(i) ((i) < 2 || ((i) >= 4 && (i) < 6) || (TERMS >= 2 && ((i) == 2 || (i) == 3)) || (TERMS >= 3 && (i) >= 6))
template<bool BIAS, bool RELU, bool STATS, bool OB16, int TERMS, bool SWZ, bool AF32>
__global__ __launch_bounds__(256) void mgemm_k(
    const u16* __restrict__ Ahi, const u16* __restrict__ Alo, const float* __restrict__ Af,
    const u16* __restrict__ Bhi, const u16* __restrict__ Blo,
    const float* __restrict__ bias, void* __restrict__ Cv,
    int M, int K, int ldc, int bstride, float* __restrict__ stats)
{
    __shared__ u16 lds[4 * 128 * 32];
    __shared__ float red[256];
    const int t = threadIdx.x;
    int brow, bcol, z;
    if (SWZ) {
        int d = blockIdx.x;
        int xcd = d & 7, s = d >> 3;
        int row = xcd + 8 * (s / 9);
        int c = s % 9;
        brow = row * 128;
        if (brow >= M) return;
        bcol = (c % 3) * 128;
        z = c / 3;
    } else {
        brow = blockIdx.x * 128; bcol = blockIdx.y * 128; z = blockIdx.z;
    }
    Bhi += (size_t)z * bstride;
    Blo += (size_t)z * bstride;
    float* Cf = OB16 ? nullptr : (float*)Cv + (size_t)z * M * ldc;
    u16*   Ch = OB16 ? (u16*)Cv + (size_t)z * M * ldc : nullptr;

    const int r0 = t >> 2, sl = t & 3;
    const int rA0 = min(brow + r0, M - 1);
    const int rA1 = min(brow + r0 + 64, M - 1);
    const u16* gsrc[8];
    gsrc[0] = Ahi + (size_t)rA0 * K + sl * 8;
    gsrc[1] = Ahi + (size_t)rA1 * K + sl * 8;
    gsrc[2] = Alo + (size_t)rA0 * K + sl * 8;
    gsrc[3] = Alo + (size_t)rA1 * K + sl * 8;
    gsrc[4] = Bhi + (size_t)(bcol + r0) * K + sl * 8;
    gsrc[5] = Bhi + (size_t)(bcol + r0 + 64) * K + sl * 8;
    gsrc[6] = Blo + (size_t)(bcol + r0) * K + sl * 8;
    gsrc[7] = Blo + (size_t)(bcol + r0 + 64) * K + sl * 8;
    const float* afsrc[2];
    if (AF32) {
        afsrc[0] = Af + (size_t)rA0 * K + sl * 8;
        afsrc[1] = Af + (size_t)rA1 * K + sl * 8;
    }
    const int swz = (sl ^ (r0 & 3)) << 3;
    int ldst[8];
    #pragma unroll
    for (int i = 0; i < 8; i++) {
        int tile = i >> 1, row = r0 + 64 * (i & 1);
        ldst[i] = tile * 4096 + row * 32 + swz;
    }

    const int l = t & 63, w = t >> 6;
    const int wr = (w >> 1) * 64, wc = (w & 1) * 64;
    const int lr = l & 15, kq = l >> 4;

    f4v acc[4][4] = {};
    const int NK = K >> 5;

    #define LDA32(i, ko) ({ \
        float4 f0_ = *(const float4*)(afsrc[i] + (ko)); \
        float4 f1_ = *(const float4*)(afsrc[i] + (ko) + 4); \
        s8v r_; \
        r_[0] = (short)f2b(f0_.x); r_[1] = (short)f2b(f0_.y); \
        r_[2] = (short)f2b(f0_.z); r_[3] = (short)f2b(f0_.w); \
        r_[4] = (short)f2b(f1_.x); r_[5] = (short)f2b(f1_.y); \
        r_[6] = (short)f2b(f1_.z); r_[7] = (short)f2b(f1_.w); \
        r_; })

    s8v stg[8];
    #pragma unroll
    for (int i = 0; i < 8; i++) {
        if (AF32 && i < 2) stg[i] = LDA32(i, 0);
        else if (!(AF32 && i < 2) && USEI(i)) stg[i] = *(const s8v*)gsrc[i];
    }

    for (int kc = 0; kc < NK; kc++) {
        if (kc) __syncthreads();
        #pragma unroll
        for (int i = 0; i < 8; i++) if (USEI(i)) *(s8v*)(lds + ldst[i]) = stg[i];
        __syncthreads();
        if (kc + 1 < NK) {
            const int ko = (kc + 1) * 32;
            #pragma unroll
            for (int i = 0; i < 8; i++) {
                if (AF32 && i < 2) stg[i] = LDA32(i, ko);
                else if (!(AF32 && i < 2) && USEI(i)) stg[i] = *(const s8v*)(gsrc[i] + ko);
            }
        }
        #define LDR(T, row) (*(const s8v*)(lds + (T) * 4096 + (row) * 32 + ((kq ^ ((row) & 3)) << 3)))
        s8v bh[4], bl[4];
        #pragma unroll
        for (int tn = 0; tn < 4; tn++) {
            int rb = wc + tn * 16 + lr;
            bh[tn] = LDR(2, rb);
            if (TERMS >= 3) bl[tn] = LDR(3, rb);
        }
        #pragma unroll
        for (int tm = 0; tm < 4; tm++) {
            int ra = wr + tm * 16 + lr;
            s8v ah = LDR(0, ra);
            s8v al;
            if (TERMS >= 2) al = LDR(1, ra);
            #pragma unroll
            for (int tn = 0; tn < 4; tn++) {
                acc[tm][tn] = __builtin_amdgcn_mfma_f32_16x16x32_bf16(ah, bh[tn], acc[tm][tn], 0, 0, 0);
                if (TERMS >= 2)
                    acc[tm][tn] = __builtin_amdgcn_mfma_f32_16x16x32_bf16(al, bh[tn], acc[tm][tn], 0, 0, 0);
                if (TERMS >= 3)
                    acc[tm][tn] = __builtin_amdgcn_mfma_f32_16x16x32_bf16(ah, bl[tn], acc[tm][tn], 0, 0, 0);
            }
        }
        #undef LDR
    }
    #undef LDA32

    float s1 = 0.f, s2 = 0.f;
    #pragma unroll
    for (int tm = 0; tm < 4; tm++) {
        #pragma unroll
        for (int rg = 0; rg < 4; rg++) {
            int row = brow + wr + tm * 16 + kq * 4 + rg;
            if (row < M) {
                #pragma unroll
                for (int tn = 0; tn < 4; tn++) {
                    int col = bcol + wc + tn * 16 + lr;
                    float v = acc[tm][tn][rg];
                    if (BIAS) v += bias[col];
                    if (RELU) v = fmaxf(v, 0.f);
                    if (OB16) Ch[(size_t)row * ldc + col] = f2b(v);
                    else      Cf[(size_t)row * ldc + col] = v;
                    if (STATS) { s1 += v; s2 += v * v; }
                }
            }
        }
    }
    if (STATS) {
        __syncthreads();
        red[t] = s1; __syncthreads();
        for (int o = 128; o; o >>= 1) { if (t < o) red[t] += red[t + o]; __syncthreads(); }
        if (t == 0) atomicAdd(&stats[0], red[0]);
        __syncthreads();
        red[t] = s2; __syncthreads();
        for (int o = 128; o; o >>= 1) { if (t < o) red[t] += red[t + o]; __syncthreads(); }
        if (t == 0) atomicAdd(&stats[1], red[0]);
    }
}
#undef USEI

// ---------------- fused classifier: OUT = relu(HS2@W1^T + b1)@W2 + b2 (+ softmax prior) ----
// Stage1: 128x128 pure-bf16 GEMM (K=384) -> bias+relu -> h2 in LDS (bf16, stride 132).
// Stage2: h2 @ W2T (hi+lo in LDS) -> logits fp32 -> OUT; DOSM: fused row softmax -> prior.
template<bool DOSM>
__global__ __launch_bounds__(256) void mcls_k(
    const u16* __restrict__ A, const u16* __restrict__ Bh, const float* __restrict__ b1,
    const u16* __restrict__ w2hi, const u16* __restrict__ w2lo, const float* __restrict__ b2,
    float* __restrict__ outp, float* __restrict__ prior)
{
    __shared__ u16 lds[128 * 132];      // stage1 tiles (first 16384) / stage2 h2
    __shared__ u16 w2lds[2][32 * 132];
    const int t = threadIdx.x;
    const int brow = blockIdx.x * 128;

    for (int i = t; i < 512; i += 256) {   // W2T 32x128 hi+lo -> LDS
        int row = i >> 4, c8 = (i & 15) * 8;
        *(s8v*)&w2lds[0][row * 132 + c8] = *(const s8v*)(w2hi + row * 128 + c8);
        *(s8v*)&w2lds[1][row * 132 + c8] = *(const s8v*)(w2lo + row * 128 + c8);
    }

    const int r0 = t >> 2, sl = t & 3;
    const int rA0 = min(brow + r0, Nn - 1);
    const int rA1 = min(brow + r0 + 64, Nn - 1);
    const u16* gA0 = A + (size_t)rA0 * FD + sl * 8;
    const u16* gA1 = A + (size_t)rA1 * FD + sl * 8;
    const u16* gB0 = Bh + (size_t)r0 * FD + sl * 8;
    const u16* gB1 = Bh + (size_t)(r0 + 64) * FD + sl * 8;
    const int swz = (sl ^ (r0 & 3)) << 3;
    const int la0 = r0 * 32 + swz, la1 = (r0 + 64) * 32 + swz;
    const int lb0 = 2 * 4096 + r0 * 32 + swz, lb1 = 2 * 4096 + (r0 + 64) * 32 + swz;

    const int l = t & 63, w = t >> 6;
    const int wr = (w >> 1) * 64, wc = (w & 1) * 64;
    const int lr = l & 15, kq = l >> 4;

    f4v acc[4][4] = {};
    s8v sA0 = *(const s8v*)gA0, sA1 = *(const s8v*)gA1;
    s8v sB0 = *(const s8v*)gB0, sB1 = *(const s8v*)gB1;
    for (int kc = 0; kc < 12; kc++) {
        if (kc) __syncthreads();
        *(s8v*)(lds + la0) = sA0; *(s8v*)(lds + la1) = sA1;
        *(s8v*)(lds + lb0) = sB0; *(s8v*)(lds + lb1) = sB1;
        __syncthreads();
        if (kc + 1 < 12) {
            int ko = (kc + 1) * 32;
            sA0 = *(const s8v*)(gA0 + ko); sA1 = *(const s8v*)(gA1 + ko);
            sB0 = *(const s8v*)(gB0 + ko); sB1 = *(const s8v*)(gB1 + ko);
        }
        #define LDR(T, row) (*(const s8v*)(lds + (T) * 4096 + (row) * 32 + ((kq ^ ((row) & 3)) << 3)))
        s8v bh[4];
        #pragma unroll
        for (int tn = 0; tn < 4; tn++) bh[tn] = LDR(2, wc + tn * 16 + lr);
        #pragma unroll
        for (int tm = 0; tm < 4; tm++) {
            s8v ah = LDR(0, wr + tm * 16 + lr);
            #pragma unroll
            for (int tn = 0; tn < 4; tn++)
                acc[tm][tn] = __builtin_amdgcn_mfma_f32_16x16x32_bf16(ah, bh[tn], acc[tm][tn], 0, 0, 0);
        }
        #undef LDR
    }
    __syncthreads();   // all tile reads done before overwriting lds with h2

    // stage1 epilogue: bias+relu -> h2 bf16 (stride 132)
    #pragma unroll
    for (int tm = 0; tm < 4; tm++)
        #pragma unroll
        for (int rg = 0; rg < 4; rg++) {
            int row = wr + tm * 16 + kq * 4 + rg;
            #pragma unroll
            for (int tn = 0; tn < 4; tn++) {
                int col = wc + tn * 16 + lr;
                lds[row * 132 + col] = f2b(fmaxf(acc[tm][tn][rg] + b1[col], 0.f));
            }
        }
    __syncthreads();

    // stage2: rows w*32..w*32+31, cols 0..31, K=128
    f4v a2[2][2] = {};
    #pragma unroll
    for (int ks = 0; ks < 4; ks++) {
        #pragma unroll
        for (int rf = 0; rf < 2; rf++) {
            int ar = w * 32 + rf * 16 + lr;
            s8v av = *(const s8v*)&lds[ar * 132 + ks * 32 + kq * 8];
            #pragma unroll
            for (int cf = 0; cf < 2; cf++) {
                s8v bhv = *(const s8v*)&w2lds[0][(cf * 16 + lr) * 132 + ks * 32 + kq * 8];
                s8v blv = *(const s8v*)&w2lds[1][(cf * 16 + lr) * 132 + ks * 32 + kq * 8];
                a2[rf][cf] = __builtin_amdgcn_mfma_f32_16x16x32_bf16(av, bhv, a2[rf][cf], 0, 0, 0);
                a2[rf][cf] = __builtin_amdgcn_mfma_f32_16x16x32_bf16(av, blv, a2[rf][cf], 0, 0, 0);
            }
        }
    }
    #pragma unroll
    for (int rf = 0; rf < 2; rf++) {
        #pragma unroll
        for (int rg = 0; rg < 4; rg++) {
            int grow = brow + w * 32 + rf * 16 + kq * 4 + rg;
            float v0 = a2[rf][0][rg] + b2[lr];
            float v1 = a2[rf][1][rg] + b2[16 + lr];
            if (grow < Nn) {
                outp[(size_t)grow * 32 + lr] = v0;
                outp[(size_t)grow * 32 + 16 + lr] = v1;
            }
            if (DOSM) {
                float m = fmaxf(v0, v1);
                m = fmaxf(m, __shfl_xor(m, 1));
                m = fmaxf(m, __shfl_xor(m, 2));
                m = fmaxf(m, __shfl_xor(m, 4));
                m = fmaxf(m, __shfl_xor(m, 8));
                float e0 = __expf(v0 - m), e1 = __expf(v1 - m);
                float s = e0 + e1;
                s += __shfl_xor(s, 1); s += __shfl_xor(s, 2);
                s += __shfl_xor(s, 4); s += __shfl_xor(s, 8);
                if (grow < Nn) {
                    float rs = 1.f / s;
                    prior[(size_t)grow * 33 + lr] = e0 * rs;
                    prior[(size_t)grow * 33 + 16 + lr] = e1 * rs;
                    if (lr == 0) prior[(size_t)grow * 33 + 32] = rs;
                }
            }
        }
    }
}

// ---------------- projh GEMM: QIK[Nn,48] = HS(bf16) @ W2T[48,384]^T (2-term B split) ----
__global__ __launch_bounds__(256) void projh_k(const u16* __restrict__ hs,
    const u16* __restrict__ w2hi, const u16* __restrict__ w2lo, float* __restrict__ qik)
{
    __shared__ u16 a_lds[128 * 32];
    __shared__ u16 b_lds[2][48 * 392];
    int t = threadIdx.x;
    int brow = blockIdx.x * 128;

    for (int i = t; i < 2304; i += 256) {
        int col = i / 48, c8 = (i - col * 48) * 8;
        *(s8v*)&b_lds[0][col * 392 + c8] = *(const s8v*)(w2hi + col * 384 + c8);
        *(s8v*)&b_lds[1][col * 392 + c8] = *(const s8v*)(w2lo + col * 384 + c8);
    }

    int ar = t >> 1, sl0 = (t & 1) * 2;
    int grow = min(brow + ar, Nn - 1);
    const u16* asrc = hs + (size_t)grow * FD;
    int adst0 = ar * 32 + ((sl0 ^ (ar & 3)) << 3);
    int adst1 = ar * 32 + (((sl0 + 1) ^ (ar & 3)) << 3);

    int l = t & 63, w = t >> 6;
    int lr = l & 15, kq = l >> 4;
    f4v acc[2][3] = {};

    s8v stg0 = *(const s8v*)(asrc + sl0 * 8);
    s8v stg1 = *(const s8v*)(asrc + sl0 * 8 + 8);
    for (int kc = 0; kc < 12; kc++) {
        if (kc) __syncthreads();
        *(s8v*)&a_lds[adst0] = stg0;
        *(s8v*)&a_lds[adst1] = stg1;
        __syncthreads();
        if (kc + 1 < 12) {
            int ko = (kc + 1) * 32 + sl0 * 8;
            stg0 = *(const s8v*)(asrc + ko);
            stg1 = *(const s8v*)(asrc + ko + 8);
        }
        s8v bh[3], bl[3];
        #pragma unroll
        for (int cf = 0; cf < 3; cf++) {
            bh[cf] = *(const s8v*)&b_lds[0][(cf * 16 + lr) * 392 + kc * 32 + kq * 8];
            bl[cf] = *(const s8v*)&b_lds[1][(cf * 16 + lr) * 392 + kc * 32 + kq * 8];
        }
        #pragma unroll
        for (int rf = 0; rf < 2; rf++) {
            int rr = w * 32 + rf * 16 + lr;
            s8v a = *(const s8v*)&a_lds[rr * 32 + ((kq ^ (rr & 3)) << 3)];
            #pragma unroll
            for (int cf = 0; cf < 3; cf++) {
                acc[rf][cf] = __builtin_amdgcn_mfma_f32_16x16x32_bf16(a, bh[cf], acc[rf][cf], 0, 0, 0);
                acc[rf][cf] = __builtin_amdgcn_mfma_f32_16x16x32_bf16(a, bl[cf], acc[rf][cf], 0, 0, 0);
            }
        }
    }
    #pragma unroll
    for (int rf = 0; rf < 2; rf++)
        #pragma unroll
        for (int cf = 0; cf < 3; cf++)
            #pragma unroll
            for (int rg = 0; rg < 4; rg++) {
                int row = brow + w * 32 + rf * 16 + kq * 4 + rg;
                if (row < Nn) qik[(size_t)row * 48 + cf * 16 + lr] = acc[rf][cf][rg];
            }
}

// scalar-LN of a 128-col block (bf16 pre-norm, pre-offset) from RAW sums -> bf16 hi
__global__ __launch_bounds__(256) void enc_norm_k(const u16* __restrict__ H,
                           const float* __restrict__ w, const float* __restrict__ b,
                           const float* __restrict__ stats, float cntinv, u16* __restrict__ hi)
{
    int i = blockIdx.x * 256 + threadIdx.x;
    if (i >= Nn * 32) return;
    int n = i >> 5, c4 = i & 31;
    float m = stats[0] * cntinv;
    float var = stats[1] * cntinv - m * m;
    float s = 1.f / (sqrtf(fmaxf(var, 0.f)) + EPS);
    float4 wv = ((const float4*)w)[c4];
    float4 bv = ((const float4*)b)[c4];
    uint2 yv = ((const uint2*)(H + (size_t)n * FD))[c4];
    ushort4 hh;
    hh.x = f2b((b2f((u16)(yv.x & 0xffffu)) - m) * s * wv.x + bv.x);
    hh.y = f2b((b2f((u16)(yv.x >> 16))     - m) * s * wv.y + bv.y);
    hh.z = f2b((b2f((u16)(yv.y & 0xffffu)) - m) * s * wv.z + bv.z);
    hh.w = f2b((b2f((u16)(yv.y >> 16))     - m) * s * wv.w + bv.w);
    ((ushort4*)(hi + (size_t)n * FD))[c4] = hh;
}

__global__ void edge_count_k(const int* __restrict__ e0, const int* __restrict__ e1,
                             const int* __restrict__ e2, int* __restrict__ cnt)
{
    int e = blockIdx.x * 256 + threadIdx.x;
    if (e >= ETOT) return;
    int r = e / EREL, i = e - r * EREL;
    const int* ei = (r == 0) ? e0 : (r == 1) ? e1 : e2;
    atomicAdd(&cnt[ei[EREL + i]], 1);
}

__global__ void edge_fill_k(const int* __restrict__ e0, const int* __restrict__ e1,
                            const int* __restrict__ e2, int* __restrict__ cursor,
                            int* __restrict__ eidx)
{
    int e = blockIdx.x * 256 + threadIdx.x;
    if (e >= ETOT) return;
    int r = e / EREL, i = e - r * EREL;
    const int* ei = (r == 0) ? e0 : (r == 1) ? e1 : e2;
    int src = ei[i], dst = ei[EREL + i];
    int pos = atomicAdd(&cursor[dst], 1);
    eidx[pos] = src | (r << 24);
}

// exclusive scan via per-wave shuffle scan + 16-wave LDS combine
__global__ __launch_bounds__(1024) void scan_k(const int* __restrict__ cnt,
                                               int* __restrict__ rowptr, int* __restrict__ cursor)
{
    __shared__ int wsum[16], wpre[16];
    __shared__ int carry, tot;
    int t = threadIdx.x, lane = t & 63, wid = t >> 6;
    if (t == 0) carry = 0;
    __syncthreads();
    for (int base = 0; base < Nn; base += 1024) {
        int i = base + t;
        int v = (i < Nn) ? cnt[i] : 0;
        int s = v;
        #pragma unroll
        for (int o = 1; o < 64; o <<= 1) {
            int x = __shfl_up(s, o);
            if (lane >= o) s += x;
        }
        if (lane == 63) wsum[wid] = s;
        __syncthreads();
        if (t < 16) {
            int wv = wsum[t];
            int ws = wv;
            #pragma unroll
            for (int o = 1; o < 16; o <<= 1) {
                int x = __shfl_up(ws, o);
                if (t >= o) ws += x;
            }
            wpre[t] = ws - wv;
            if (t == 15) tot = ws;
        }
        __syncthreads();
        if (i < Nn) {
            int ex = carry + wpre[wid] + s - v;
            rowptr[i] = ex; cursor[i] = ex;
        }
        __syncthreads();
        if (t == 0) carry += tot;
    }
    __syncthreads();
    if (t == 0) rowptr[Nn] = carry;
}

// per-graph node counts via LDS histogram
__global__ __launch_bounds__(256) void gcount_k(const int* __restrict__ batch, int* __restrict__ gcnt)
{
    __shared__ int bins[NG];
    int t = threadIdx.x;
    if (t < NG) bins[t] = 0;
    __syncthreads();
    int n = blockIdx.x * 256 + t;
    if (n < Nn) atomicAdd(&bins[batch[n]], 1);
    __syncthreads();
    if (t < NG && bins[t]) atomicAdd(&gcnt[t], bins[t]);
}

// RGAT aggregation, softmax fused (QIK[n][48]: q=r*16+h, k=r*16+8+h). One wave per node,
// 4x edge unroll, dwordx3 row gather, fused elu/residual/stats.
__global__ __launch_bounds__(256) void aggr_k(const u16* __restrict__ xr,
    const float* __restrict__ qik, const int* __restrict__ rowptr, const int* __restrict__ eidx,
    const float* __restrict__ bias, const u16* __restrict__ hinb,
    const int* __restrict__ batch, u16* __restrict__ outb,
    float* __restrict__ gsum, float* __restrict__ gsq)
{
    __shared__ float ls[NG], lq[NG];
    int t = threadIdx.x;
    if (t < NG) { ls[t] = 0.f; lq[t] = 0.f; }
    __syncthreads();
    int node = blockIdx.x * 4 + (t >> 6);
    int lane = t & 63;
    int e0 = rowptr[node], e1 = rowptr[node + 1];
    int hd = lane >> 3;
    float qv = (lane < 48) ? qik[(size_t)node * 48 + lane] : 0.f;
    float den = 0.f;
    float acc[6] = {};

    int e = e0;
    while (e + 4 <= e1) {
        int p0 = eidx[e], p1 = eidx[e + 1], p2 = eidx[e + 2], p3 = eidx[e + 3];
        int n0 = p0 & 0xFFFFFF, et0 = p0 >> 24;
        int n1 = p1 & 0xFFFFFF, et1 = p1 >> 24;
        int n2 = p2 & 0xFFFFFF, et2 = p2 >> 24;
        int n3 = p3 & 0xFFFFFF, et3 = p3 >> 24;
        float kv0 = (lane < 8) ? qik[(size_t)n0 * 48 + et0 * 16 + 8 + lane] : 0.f;
        float kv1 = (lane < 8) ? qik[(size_t)n1 * 48 + et1 * 16 + 8 + lane] : 0.f;
        float kv2 = (lane < 8) ? qik[(size_t)n2 * 48 + et2 * 16 + 8 + lane] : 0.f;
        float kv3 = (lane < 8) ? qik[(size_t)n3 * 48 + et3 * 16 + 8 + lane] : 0.f;
        const u32* r0 = (const u32*)(xr + ((size_t)et0 * Nn + n0) * FD);
        const u32* r1 = (const u32*)(xr + ((size_t)et1 * Nn + n1) * FD);
        const u32* r2 = (const u32*)(xr + ((size_t)et2 * Nn + n2) * FD);
        const u32* r3 = (const u32*)(xr + ((size_t)et3 * Nn + n3) * FD);
        u32 u0[3], u1[3], u2[3], u3[3];
        #pragma unroll
        for (int j = 0; j < 3; j++) u0[j] = r0[lane * 3 + j];
        #pragma unroll
        for (int j = 0; j < 3; j++) u1[j] = r1[lane * 3 + j];
        #pragma unroll
        for (int j = 0; j < 3; j++) u2[j] = r2[lane * 3 + j];
        #pragma unroll
        for (int j = 0; j < 3; j++) u3[j] = r3[lane * 3 + j];
        float qq0 = __shfl(qv, et0 * 16 + (lane & 7));
        float qq1 = __shfl(qv, et1 * 16 + (lane & 7));
        float qq2 = __shfl(qv, et2 * 16 + (lane & 7));
        float qq3 = __shfl(qv, et3 * 16 + (lane & 7));
        float ex0 = 0.f, ex1 = 0.f, ex2 = 0.f, ex3 = 0.f;
        if (lane < 8) {
            float a0 = qq0 + kv0; a0 = (a0 > 0.f) ? a0 : 0.2f * a0; ex0 = __expf(a0);
            float a1 = qq1 + kv1; a1 = (a1 > 0.f) ? a1 : 0.2f * a1; ex1 = __expf(a1);
            float a2 = qq2 + kv2; a2 = (a2 > 0.f) ? a2 : 0.2f * a2; ex2 = __expf(a2);
            float a3 = qq3 + kv3; a3 = (a3 > 0.f) ? a3 : 0.2f * a3; ex3 = __expf(a3);
        }
        den += ex0 + ex1 + ex2 + ex3;
        float w0 = __shfl(ex0, hd), w1 = __shfl(ex1, hd);
        float w2 = __shfl(ex2, hd), w3 = __shfl(ex3, hd);
        #pragma unroll
        for (int j = 0; j < 3; j++) {
            acc[2*j]   = fmaf(w0, __uint_as_float(u0[j] << 16), acc[2*j]);
            acc[2*j+1] = fmaf(w0, __uint_as_float(u0[j] & 0xffff0000u), acc[2*j+1]);
            acc[2*j]   = fmaf(w1, __uint_as_float(u1[j] << 16), acc[2*j]);
            acc[2*j+1] = fmaf(w1, __uint_as_float(u1[j] & 0xffff0000u), acc[2*j+1]);
            acc[2*j]   = fmaf(w2, __uint_as_float(u2[j] << 16), acc[2*j]);
            acc[2*j+1] = fmaf(w2, __uint_as_float(u2[j] & 0xffff0000u), acc[2*j+1]);
            acc[2*j]   = fmaf(w3, __uint_as_float(u3[j] << 16), acc[2*j]);
            acc[2*j+1] = fmaf(w3, __uint_as_float(u3[j] & 0xffff0000u), acc[2*j+1]);
        }
        e += 4;
    }
    for (; e < e1; e++) {
        int p = eidx[e];
        int sn = p & 0xFFFFFF, et = p >> 24;
        float kv = (lane < 8) ? qik[(size_t)sn * 48 + et * 16 + 8 + lane] : 0.f;
        const u32* rr = (const u32*)(xr + ((size_t)et * Nn + sn) * FD);
        u32 u[3];
        #pragma unroll
        for (int j = 0; j < 3; j++) u[j] = rr[lane * 3 + j];
        float qq = __shfl(qv, et * 16 + (lane & 7));
        float ex = 0.f;
        if (lane < 8) { float a = qq + kv; a = (a > 0.f) ? a : 0.2f * a; ex = __expf(a); }
        den += ex;
        float wv_ = __shfl(ex, hd);
        #pragma unroll
        for (int j = 0; j < 3; j++) {
            acc[2*j]   = fmaf(wv_, __uint_as_float(u[j] << 16), acc[2*j]);
            acc[2*j+1] = fmaf(wv_, __uint_as_float(u[j] & 0xffff0000u), acc[2*j+1]);
        }
    }

    float dh = __shfl(den, hd);
    float rcp = 1.f / (dh + 1e-16f);
    const u32* hp = (const u32*)(hinb + (size_t)node * FD);
    u32* op = (u32*)(outb + (size_t)node * FD);
    float s1 = 0.f, s2 = 0.f;
    #pragma unroll
    for (int j = 0; j < 3; j++) {
        int c = lane * 6 + 2 * j;
        float2 bv = *(const float2*)(bias + c);
        u32 hb = hp[lane * 3 + j];
        float vx = acc[2*j] * rcp + bv.x;
        float vy = acc[2*j+1] * rcp + bv.y;
        vx = (vx > 0.f) ? vx : expm1f(vx);
        vy = (vy > 0.f) ? vy : expm1f(vy);
        vx += b2f((u16)(hb & 0xffffu));
        vy += b2f((u16)(hb >> 16));
        op[lane * 3 + j] = (u32)f2b(vx) | ((u32)f2b(vy) << 16);
        s1 += vx + vy; s2 += vx * vx + vy * vy;
    }
    #pragma unroll
    for (int o = 32; o; o >>= 1) { s1 += __shfl_down(s1, o); s2 += __shfl_down(s2, o); }
    int g = batch[node];
    if (lane == 0) { atomicAdd(&ls[g], s1); atomicAdd(&lq[g], s2); }
    __syncthreads();
    if (t < NG && (ls[t] != 0.f || lq[t] != 0.f)) {
        atomicAdd(&gsum[t], ls[t]);
        atomicAdd(&gsq[t], lq[t]);
    }
}

// graph-LN from raw sums, bf16 input -> bf16 hi (lo no longer needed anywhere)
__global__ __launch_bounds__(256) void gnorm_split_k(const u16* __restrict__ yb,
    const int* __restrict__ batch, const float* __restrict__ gsum, const float* __restrict__ gsq,
    const int* __restrict__ gcnt, const float* __restrict__ w, const float* __restrict__ b,
    u16* __restrict__ hi)
{
    int i = blockIdx.x * 256 + threadIdx.x;
    if (i >= Nn * (FD / 4)) return;
    int n = i / 96;
    int c4 = i - n * 96;
    int g = batch[n];
    float norm = fmaxf((float)gcnt[g], 1.f) * (float)FD;
    float m = gsum[g] / norm;
    float var = gsq[g] / norm - m * m;
    float rstd = rsqrtf(var + EPS);
    float4 wv = ((const float4*)w)[c4];
    float4 bv = ((const float4*)b)[c4];
    uint2 yv = ((const uint2*)yb)[i];
    ushort4 hh;
    hh.x = f2b((b2f((u16)(yv.x & 0xffffu)) - m) * rstd * wv.x + bv.x);
    hh.y = f2b((b2f((u16)(yv.x >> 16))     - m) * rstd * wv.y + bv.y);
    hh.z = f2b((b2f((u16)(yv.y & 0xffffu)) - m) * rstd * wv.z + bv.z);
    hh.w = f2b((b2f((u16)(yv.y >> 16))     - m) * rstd * wv.w + bv.w);
    ((ushort4*)hi)[i] = hh;
}

extern "C" void kernel_launch(void* const* d_in, const int* in_sizes, int n_in,
                              void* d_out, int out_size, void* d_ws, size_t ws_size,
                              hipStream_t stream)
{
    const float* x_visual = (const float*)d_in[0];
    const float* x_geom   = (const float*)d_in[1];
    const float* x_prior  = (const float*)d_in[2];
    const int* ei0   = (const int*)d_in[3];
    const int* ei1   = (const int*)d_in[4];
    const int* ei2   = (const int*)d_in[5];
    const int* batch = (const int*)d_in[6];
    const float* vis_W = (const float*)d_in[7];  const float* vis_b = (const float*)d_in[8];
    const float* vis_lnw = (const float*)d_in[9]; const float* vis_lnb = (const float*)d_in[10];
    const float* geo_W = (const float*)d_in[11]; const float* geo_b = (const float*)d_in[12];
    const float* geo_lnw = (const float*)d_in[13]; const float* geo_lnb = (const float*)d_in[14];
    const float* pri_W = (const float*)d_in[15]; const float* pri_b = (const float*)d_in[16];
    const float* pri_lnw = (const float*)d_in[17]; const float* pri_lnb = (const float*)d_in[18];
    const float* rgat_W[2]    = { (const float*)d_in[19], (const float*)d_in[25] };
    const float* rgat_q[2]    = { (const float*)d_in[20], (const float*)d_in[26] };
    const float* rgat_kk[2]   = { (const float*)d_in[21], (const float*)d_in[27] };
    const float* rgat_bias[2] = { (const float*)d_in[22], (const float*)d_in[28] };
    const float* ln_w[2]      = { (const float*)d_in[23], (const float*)d_in[29] };
    const float* ln_b[2]      = { (const float*)d_in[24], (const float*)d_in[30] };
    const float* cls_W1 = (const float*)d_in[31]; const float* cls_b1 = (const float*)d_in[32];
    const float* cls_W2 = (const float*)d_in[33]; const float* cls_b2 = (const float*)d_in[34];
    float* OUT = (float*)d_out;

    // ---------------- workspace layout ----------------
    float* ws = (float*)d_ws;
    float* XRreg = ws;                         // 3*Nn*FD floats reserved (92.2 MB region)
    u16*   XR16  = (u16*)XRreg;                // XR stored bf16 (46 MB)
    float* HCAT  = XRreg + (size_t)3 * Nn * FD;
    u16*   HENC  = (u16*)HCAT;                 // [Nn][384] bf16 pre-norm encoder out
    float* HA    = HCAT + (size_t)Nn * FD;
    float* HB    = HA + (size_t)Nn * FD;
    float* PRIOR = HB + (size_t)Nn * FD;       // Nn*33
    float* QIK   = PRIOR + (size_t)Nn * 33;    // Nn*48
    u16* HS0_HI  = (u16*)(QIK + (size_t)Nn * 48);      // normalized HCAT (bf16)
    u16* HS0_LO  = HS0_HI + (size_t)Nn * FD;           // (dead)
    u16* HS1_HI  = HS0_LO + (size_t)Nn * FD;           // normalized layer-0 out (bf16)
    u16* HS1_LO  = HS1_HI + (size_t)Nn * FD;           // (dead)
    u16* RW_HI   = HS1_LO + (size_t)Nn * FD;   // 2*3*384*384
    u16* RW_LO   = RW_HI + (size_t)2 * 3 * 384 * 384;  // (dead, unwritten)
    u16* VW_HI   = RW_LO + (size_t)2 * 3 * 384 * 384; // 128*1024
    u16* VW_LO   = VW_HI + (size_t)128 * 1024;        // (dead)
    u16* CW_HI   = VW_LO + (size_t)128 * 1024;        // cls_W1: 128 cols x 384
    u16* W2T_HI  = CW_HI + (size_t)128 * 384;         // cls_W2^T: 32 x 128
    u16* W2T_LO  = W2T_HI + (size_t)32 * 128;
    u16* W2_HI   = W2T_LO + (size_t)32 * 128;         // attn W2: 2 layers * 48*384
    u16* W2_LO   = W2_HI + (size_t)2 * 48 * 384;
    float* GS    = (float*)(W2_LO + (size_t)2 * 48 * 384); // 4 slots * 128 (sum|sq)
    float* STATS = GS + 512;                   // 4 slots * 2
    int* CNT    = (int*)(STATS + 8);
    int* ROWPTR = CNT + Nn;
    int* CURSOR = ROWPTR + Nn + 1;
    int* EIDX   = CURSOR + Nn;
    int* GCNT   = EIDX + ETOT;
    // aliases (temporally dead sub-ranges):
    u16* HS2_HI = (u16*)(XRreg + (size_t)12 * 1000 * 1000); // HB split [48MB,63.4MB)
    u16* YB0 = (u16*)HA;                       // aggr L=0 out (bf16 pre-norm)
    u16* YB1 = (u16*)HB;                       // aggr L=1 out (bf16 pre-norm)

    // ---------------- CSR build (reused by all 4 RGAT calls) ----------------
    hipMemsetAsync(CNT, 0, Nn * sizeof(int), stream);
    edge_count_k<<<cdiv(ETOT, 256), 256, 0, stream>>>(ei0, ei1, ei2, CNT);
    scan_k<<<1, 1024, 0, stream>>>(CNT, ROWPTR, CURSOR);
    edge_fill_k<<<cdiv(ETOT, 256), 256, 0, stream>>>(ei0, ei1, ei2, CURSOR, EIDX);
    hipMemsetAsync(GCNT, 0, 64 * sizeof(int), stream);
    gcount_k<<<cdiv(Nn, 256), 256, 0, stream>>>(batch, GCNT);
    hipMemsetAsync(GS, 0, 520 * sizeof(float), stream);   // GS (4x128) + STATS (4x2)

    // ---------------- weight conversions ----------------
    tsplit_k<false><<<cdiv(3 * 384 * 384, 256), 256, 0, stream>>>(rgat_W[0], RW_HI, RW_LO, 384, 384, 3 * 384 * 384);
    tsplit_k<false><<<cdiv(3 * 384 * 384, 256), 256, 0, stream>>>(rgat_W[1], RW_HI + 3 * 384 * 384, RW_LO, 384, 384, 3 * 384 * 384);
    tsplit_k<false><<<cdiv(1024 * 128, 256), 256, 0, stream>>>(vis_W, VW_HI, VW_LO, 1024, 128, 1024 * 128);
    tsplit_k<false><<<cdiv(384 * 128, 256), 256, 0, stream>>>(cls_W1, CW_HI, nullptr, 384, 128, 384 * 128);
    tsplit_k<true><<<cdiv(128 * 32, 256), 256, 0, stream>>>(cls_W2, W2T_HI, W2T_LO, 128, 32, 128 * 32);
    w2_k<<<576, 256, 0, stream>>>(rgat_W[0], rgat_q[0], rgat_kk[0],
                                  rgat_W[1], rgat_q[1], rgat_kk[1], W2_HI, W2_LO);

    const int MB = cdiv(Nn, 128);   // 157
    const int XRBLK = 160 * 9;      // padded rows * (3 cols x 3 rels), XCD-swizzled
    const float cinv = 1.f / ((float)Nn * 128.f);

    // ---------------- vis encoder (MFMA TERMS=1, fp32 A staged in-kernel) -> HENC[:,0:128) ----
    mgemm_k<true, true, true, true, 1, false, true><<<dim3(MB, 1, 1), 256, 0, stream>>>(
        nullptr, nullptr, x_visual, VW_HI, VW_LO, vis_b, HENC, Nn, 1024, FD, 0, STATS + 0);
    enc_norm_k<<<cdiv(Nn * 32, 256), 256, 0, stream>>>(HENC, vis_lnw, vis_lnb, STATS + 0, cinv, HS0_HI);

    // ---------------- geo encoder (small-K) -> HENC[:,128:256) ----------------
    enc_gemm_k<<<cdiv(Nn, 32), 256, 0, stream>>>(x_geom, 6, geo_W, geo_b, HENC + 128, STATS + 2);
    enc_norm_k<<<cdiv(Nn * 32, 256), 256, 0, stream>>>(HENC + 128, geo_lnw, geo_lnb, STATS + 2, cinv, HS0_HI + 128);

    for (int t = 0; t < 2; t++) {
        // prior encoder (small-K) -> HENC[:,256:384)
        const float* pin = t ? PRIOR : x_prior;
        enc_gemm_k<<<cdiv(Nn, 32), 256, 0, stream>>>(pin, 33, pri_W, pri_b, HENC + 256, STATS + 4 + 2 * t);
        enc_norm_k<<<cdiv(Nn * 32, 256), 256, 0, stream>>>(HENC + 256, pri_lnw, pri_lnb, STATS + 4 + 2 * t, cinv, HS0_HI + 256);

        for (int L = 0; L < 2; L++) {
            const u16* ahi = L ? HS1_HI : HS0_HI;     // normalized input (bf16)
            u16* yout = L ? YB1 : YB0;                // aggr out (bf16 pre-norm)
            u16* snorm = L ? HS2_HI : HS1_HI;         // normalized out
            float* gsum = GS + (t * 2 + L) * 128;     // pre-zeroed slot
            mgemm_k<false, false, false, true, 1, true, false><<<dim3(XRBLK, 1, 1), 256, 0, stream>>>(
                ahi, ahi, nullptr, RW_HI + (size_t)L * 3 * 384 * 384, RW_LO,
                nullptr, XR16, Nn, 384, FD, 384 * 384, nullptr);
            projh_k<<<MB, 256, 0, stream>>>(ahi,
                W2_HI + (size_t)L * 48 * 384, W2_LO + (size_t)L * 48 * 384, QIK);
            aggr_k<<<cdiv(Nn, 4), 256, 0, stream>>>(XR16, QIK, ROWPTR, EIDX, rgat_bias[L],
                                                    ahi, batch, yout, gsum, gsum + 64);
            gnorm_split_k<<<cdiv(Nn * 96, 256), 256, 0, stream>>>(
                yout, batch, gsum, gsum + 64, GCNT, ln_w[L], ln_b[L], snorm);
        }

        // fused classifier (cls1 + relu + cls2 + bias, softmax->prior at t=0)
        if (t == 0)
            mcls_k<true><<<dim3(MB, 1, 1), 256, 0, stream>>>(
                HS2_HI, CW_HI, cls_b1, W2T_HI, W2T_LO, cls_b2, OUT, PRIOR);
        else
            mcls_k<false><<<dim3(MB, 1, 1), 256, 0, stream>>>(
                HS2_HI, CW_HI, cls_b1, W2T_HI, W2T_LO, cls_b2, OUT, nullptr);
    }
}